// Round 1
// baseline (693.096 us; speedup 1.0000x reference)
//
#include <hip/hip_runtime.h>

// ---------------------------------------------------------------------------
// MemoryOptimizedMLA on gfx950 — absorbed-MLA formulation.
//
//   c_kv = h@W_dkv+b ; c_q = h@W_dq+b ; k_rot = rope(h@W_kr+b)
//   W_qk[h] = W_uq_h @ W_uk_h^T (128x128), b_qabs[h] = b_uq_h @ W_uk_h^T
//   q_abs = (c_q@W_qk + b_qabs)/sqrt(640) ; q_rot = rope(c_q@W_qr + b_qr)/sqrt(640)
//   scores = q_abs . c_kv + q_rot . k_rot          (b_uk is softmax-inv.)
//   ctx = softmax(scores) @ c_kv      (128 dims, flash/online-softmax)
//   out = ctx @ W_combT^T + (b_uv@W_o + b_o),  W_comb[h] = W_uv_h @ W_o_h
//
// R2: gemm1 rebuilt as split-K (grid 64x2x4, fp32 partials) + k_reduce
//     epilogue (bias + rope). part ws aliases qabs/wcombT/ctx (stream-ordered).
// R3: (a) k_bvec_acc folded into k_comb (saves a full 105 MB W_o HBM pass);
//     (b) attention softmax diet: exact defer-rescale (alpha path only when
//         row-max grows), deferred l-reduction (one shfl reduce at the end),
//         q pre-scaled by 1/sqrt(640) at the producers;
//     (c) LDS conflict fixes: XOR-swizzled transpose scatter stores
//         (gemm1 Bs, comb As, attn Vt: 4-way -> conflict-free) and
//         Qs/Ks stride 160->168 (staging writes 2x -> optimal).
// ---------------------------------------------------------------------------

typedef unsigned short ushort_t;
typedef __attribute__((ext_vector_type(8)))  short          short8;
typedef __attribute__((ext_vector_type(8)))  unsigned short us8;
typedef __attribute__((ext_vector_type(4)))  float          f32x4;

#define SCALE_ATT 0.0395284707521047f  /* 1/sqrt(640) */

static __device__ inline unsigned short f2bf(float f) {
  union { float f; unsigned u; } v; v.f = f;
  unsigned r = (v.u + 0x7fffu + ((v.u >> 16) & 1u)) >> 16;
  return (unsigned short)r;
}
static __device__ inline float bf2f(unsigned short u) {
  union { unsigned u; float f; } v; v.u = ((unsigned)u) << 16;
  return v.f;
}
static __device__ inline f32x4 MFMA(short8 a, short8 b, f32x4 c) {
  return __builtin_amdgcn_mfma_f32_16x16x32_bf16(a, b, c, 0, 0, 0);
}

// ---------------------------------------------------------------------------
// bvec init: bvec[n] = bo[n].  grid 20, block 256. (accumulated in k_comb)
__global__ __launch_bounds__(256) void k_bvec_init(const float* __restrict__ bo,
                                                   float* __restrict__ bvec) {
  int n = blockIdx.x * 256 + threadIdx.x;
  bvec[n] = bo[n];
}

// ---------------------------------------------------------------------------
// bqabs[h][j] = sum_d b_uq[h*624+d] * W_uk[j][h*624+d]   grid 8, block 128
__global__ __launch_bounds__(128) void k_bqabs(const float* __restrict__ buq,
                                               const float* __restrict__ Wuk,
                                               float* __restrict__ bqabs) {
  int h = blockIdx.x, j = threadIdx.x;
  float acc = 0.f;
  const float* bq = buq + h * 624;
  const float* wk = Wuk + (size_t)j * 4992 + h * 624;
  for (int d = 0; d < 624; ++d) acc += bq[d] * wk[d];
  bqabs[h * 128 + j] = acc;
}

// ---------------------------------------------------------------------------
// wqkT[h][j][i] = sum_d W_uq[i][h*624+d]*W_uk[j][h*624+d]  (fp32, then bf16)
__global__ __launch_bounds__(256) void k_wqk(const float* __restrict__ Wuq,
                                             const float* __restrict__ Wuk,
                                             ushort_t* __restrict__ wqkT) {
  __shared__ float Aq[16 * 132];
  __shared__ float Ak[16 * 132];
  int jt = blockIdx.x, it = blockIdx.y, h = blockIdx.z;
  int i0 = it * 16, j0 = jt * 16;
  int t = threadIdx.x;
  int srow = t >> 4, sc0 = (t & 15) * 8;
  int ti = t & 15, tj = t >> 4;
  float acc = 0.f;
  for (int dc = 0; dc < 624; dc += 128) {
#pragma unroll
    for (int i = 0; i < 8; ++i) {
      int d = dc + sc0 + i;
      Aq[srow * 132 + sc0 + i] = (d < 624) ? Wuq[(size_t)(i0 + srow) * 4992 + h * 624 + d] : 0.f;
      Ak[srow * 132 + sc0 + i] = (d < 624) ? Wuk[(size_t)(j0 + srow) * 4992 + h * 624 + d] : 0.f;
    }
    __syncthreads();
    int cs = (624 - dc) < 128 ? (624 - dc) : 128;
    for (int d = 0; d < cs; d += 4) {
      const f32x4 a4 = *(const f32x4*)&Aq[ti * 132 + d];
      const f32x4 b4 = *(const f32x4*)&Ak[tj * 132 + d];
      acc += a4[0] * b4[0] + a4[1] * b4[1] + a4[2] * b4[2] + a4[3] * b4[3];
    }
    __syncthreads();
  }
  wqkT[(size_t)h * 16384 + (size_t)(j0 + tj) * 128 + (i0 + ti)] = f2bf(acc);
}

// ---------------------------------------------------------------------------
// GEMM1 split-K: partials of h @ [W_dkv|W_dq|W_kr].
// grid (64 mtiles, 2 nhalves, 4 ksplits), block 256 (4 waves, each 64x48).
// BM=64, BN=192, BK=64, KC=1280. fp32 partials -> part[ks][4096][384].
// Bs scatter stores XOR-swizzled: k-index ^= (colgroup&3)<<4  (was 4-way).
__global__ __launch_bounds__(256) void k_gemm1_sk(
    const float* __restrict__ H, const float* __restrict__ Wdkv,
    const float* __restrict__ Wdq, const float* __restrict__ Wkr,
    float* __restrict__ part) {
  __shared__ __align__(16) ushort_t As[64 * 72];
  __shared__ __align__(16) ushort_t Bs[192 * 72];
  const int tid = threadIdx.x;
  const int m0 = blockIdx.x * 64;
  const int n0 = blockIdx.y * 192;
  const int kc0 = blockIdx.z * 1280;
  const int lane = tid & 63, wid = tid >> 6;
  const int quad = lane >> 4, l15 = lane & 15;
  f32x4 acc[4][3];
#pragma unroll
  for (int a = 0; a < 4; ++a)
#pragma unroll
    for (int b = 0; b < 3; ++b) acc[a][b] = (f32x4){0.f, 0.f, 0.f, 0.f};
  const int ar = tid >> 2, ak0 = (tid & 3) * 16;
  const int br = tid >> 2, bsg = tid & 3;
  const int bkidx = br ^ (bsg << 4);   // swizzled k-slot for Bs scatter
  const float* harow = H + (size_t)(m0 + ar) * 5120 + ak0;
  for (int kb = kc0; kb < kc0 + 1280; kb += 64) {
    const float* ap = harow + kb;
    us8 av0, av1;
#pragma unroll
    for (int i = 0; i < 8; ++i) { av0[i] = f2bf(ap[i]); av1[i] = f2bf(ap[8 + i]); }
    *(us8*)&As[ar * 72 + ak0] = av0;
    *(us8*)&As[ar * 72 + ak0 + 8] = av1;
#pragma unroll
    for (int g16 = 0; g16 < 3; ++g16) {
      const int lcol = g16 * 64 + bsg * 16;      // local col group, 16-aligned
      const int col = n0 + lcol;
      const float* base = (col < 128 ? Wdkv + col
                         : col < 256 ? Wdq + (col - 128)
                                     : Wkr + (col - 256)) + (size_t)(kb + br) * 128;
#pragma unroll
      for (int i = 0; i < 16; ++i)
        Bs[(lcol + i) * 72 + bkidx] = f2bf(base[i]);
    }
    __syncthreads();
#pragma unroll
    for (int ks = 0; ks < 2; ++ks) {
      short8 a[4], b[3];
#pragma unroll
      for (int mt = 0; mt < 4; ++mt)
        a[mt] = *(const short8*)&As[(mt * 16 + l15) * 72 + ks * 32 + quad * 8];
#pragma unroll
      for (int nt = 0; nt < 3; ++nt)
        b[nt] = *(const short8*)&Bs[(wid * 48 + nt * 16 + l15) * 72 +
                                    ((ks * 32 + quad * 8) ^ (((wid * 3 + nt) & 3) << 4))];
#pragma unroll
      for (int mt = 0; mt < 4; ++mt)
#pragma unroll
        for (int nt = 0; nt < 3; ++nt) acc[mt][nt] = MFMA(a[mt], b[nt], acc[mt][nt]);
    }
    __syncthreads();
  }
  const size_t pb = (size_t)blockIdx.z * 4096 * 384;
#pragma unroll
  for (int mt = 0; mt < 4; ++mt)
#pragma unroll
    for (int nt = 0; nt < 3; ++nt) {
      const int col = n0 + wid * 48 + nt * 16 + l15;
#pragma unroll
      for (int r = 0; r < 4; ++r) {
        const int row = m0 + mt * 16 + quad * 4 + r;
        part[pb + (size_t)row * 384 + col] = acc[mt][nt][r];
      }
    }
}

// ---------------------------------------------------------------------------
// reduce 4 partials + bias; rope for the k_rot slice. grid 4096, block 384.
__global__ __launch_bounds__(384) void k_reduce(
    const float* __restrict__ part, const float* __restrict__ bdkv,
    const float* __restrict__ bdq, const float* __restrict__ bkr,
    ushort_t* __restrict__ ckv, ushort_t* __restrict__ cq,
    ushort_t* __restrict__ krot) {
  const int row = blockIdx.x;
  const int c = threadIdx.x;
  float v = 0.f;
#pragma unroll
  for (int ks = 0; ks < 4; ++ks)
    v += part[((size_t)ks * 4096 + row) * 384 + c];
  if (c < 128) {
    v += bdkv[c];
    ckv[(size_t)row * 128 + c] = f2bf(v);
  } else if (c < 256) {
    v += bdq[c - 128];
    cq[(size_t)row * 128 + (c - 128)] = f2bf(v);
  } else {
    v += bkr[c - 256];
    float partner = __shfl_xor(v, 4);
    const int j = (c - 256) & 15;
    const int head = (c - 256) >> 4;
    const int s = row & 2047, bb = row >> 11;
    const int j4 = j & 3;
    const float fr = (j4 == 0) ? 1.f : (j4 == 1) ? 0.1f : (j4 == 2) ? 0.01f : 0.001f;
    float sth, cth;
    __sincosf(s * 0.025f * fr, &sth, &cth);
    const float y = (j < 4) ? (v * cth - partner * sth)
                  : (j < 8) ? (v * cth + partner * sth) : v;
    krot[((size_t)((bb << 3) + head) * 2048 + s) * 16 + j] = f2bf(y);
  }
}

// ---------------------------------------------------------------------------
// q_rot = rope(c_q @ W_qr + b_qr) * SCALE_ATT.  grid 128, block 256.
__global__ __launch_bounds__(256) void k_qrot(const ushort_t* __restrict__ cq,
                                              const float* __restrict__ Wqr,
                                              const float* __restrict__ bqr,
                                              ushort_t* __restrict__ qrot) {
  int gidx = blockIdx.x * 256 + threadIdx.x;  // 0..32767
  int s = gidx & 2047, bh = gidx >> 11;
  int hh = bh & 7, bb = bh >> 3;
  const ushort_t* crow = cq + ((size_t)bb * 2048 + s) * 128;
  float acc[16];
#pragma unroll
  for (int j = 0; j < 16; ++j) acc[j] = bqr[hh * 16 + j];
  for (int k0 = 0; k0 < 128; k0 += 8) {
    us8 cv8 = *(const us8*)(crow + k0);
#pragma unroll
    for (int i = 0; i < 8; ++i) {
      float cv = bf2f(cv8[i]);
      const float* wr = Wqr + (size_t)(k0 + i) * 128 + hh * 16;
#pragma unroll
      for (int j = 0; j < 16; ++j) acc[j] += cv * wr[j];
    }
  }
  float y[16];
#pragma unroll
  for (int j4 = 0; j4 < 4; ++j4) {
    float fr = (j4 == 0) ? 1.f : (j4 == 1) ? 0.1f : (j4 == 2) ? 0.01f : 0.001f;
    float sth, cth;
    __sincosf(s * 0.025f * fr, &sth, &cth);
    y[j4] = acc[j4] * cth - acc[j4 + 4] * sth;
    y[j4 + 4] = acc[j4 + 4] * cth + acc[j4] * sth;
  }
#pragma unroll
  for (int j = 8; j < 16; ++j) y[j] = acc[j];
  us8 o0, o1;
#pragma unroll
  for (int j = 0; j < 8; ++j) {
    o0[j] = f2bf(y[j] * SCALE_ATT);
    o1[j] = f2bf(y[8 + j] * SCALE_ATT);
  }
  *(us8*)(qrot + (size_t)gidx * 16) = o0;
  *(us8*)(qrot + (size_t)gidx * 16 + 8) = o1;
}

// ---------------------------------------------------------------------------
// q_abs = (c_q @ W_qk[h] + b_qabs[h]) * SCALE_ATT.  BM=128,BN=128,BK=64. grid (32, 8).
__global__ __launch_bounds__(256) void k_qabs(const ushort_t* __restrict__ cq,
                                              const ushort_t* __restrict__ wqkT,
                                              const float* __restrict__ bqabs,
                                              ushort_t* __restrict__ qabs) {
  __shared__ __align__(16) ushort_t As[128 * 72];
  __shared__ __align__(16) ushort_t Bs[128 * 72];
  const int tid = threadIdx.x;
  const int m0 = blockIdx.x * 128, hh = blockIdx.y;
  const int lane = tid & 63, wid = tid >> 6;
  const int quad = lane >> 4, l15 = lane & 15;
  const int wm = wid & 1, wn = wid >> 1;
  f32x4 acc[4][4];
#pragma unroll
  for (int a = 0; a < 4; ++a)
#pragma unroll
    for (int b = 0; b < 4; ++b) acc[a][b] = (f32x4){0.f, 0.f, 0.f, 0.f};
  const int ar = tid >> 1, as0 = (tid & 1) * 32;
  for (int kb = 0; kb < 128; kb += 64) {
    const ushort_t* ap = cq + (size_t)(m0 + ar) * 128 + kb + as0;
    const ushort_t* bp = wqkT + (size_t)hh * 16384 + (size_t)ar * 128 + kb + as0;
#pragma unroll
    for (int w = 0; w < 4; ++w) {
      *(us8*)&As[ar * 72 + as0 + w * 8] = *(const us8*)(ap + w * 8);
      *(us8*)&Bs[ar * 72 + as0 + w * 8] = *(const us8*)(bp + w * 8);
    }
    __syncthreads();
#pragma unroll
    for (int ks = 0; ks < 2; ++ks) {
      short8 a[4], b[4];
#pragma unroll
      for (int mt = 0; mt < 4; ++mt)
        a[mt] = *(const short8*)&As[(wm * 64 + mt * 16 + l15) * 72 + ks * 32 + quad * 8];
#pragma unroll
      for (int nt = 0; nt < 4; ++nt)
        b[nt] = *(const short8*)&Bs[(wn * 64 + nt * 16 + l15) * 72 + ks * 32 + quad * 8];
#pragma unroll
      for (int mt = 0; mt < 4; ++mt)
#pragma unroll
        for (int nt = 0; nt < 4; ++nt) acc[mt][nt] = MFMA(a[mt], b[nt], acc[mt][nt]);
    }
    __syncthreads();
  }
#pragma unroll
  for (int mt = 0; mt < 4; ++mt)
#pragma unroll
    for (int nt = 0; nt < 4; ++nt) {
      int col = wn * 64 + nt * 16 + l15;
      float bias = bqabs[hh * 128 + col];
#pragma unroll
      for (int r = 0; r < 4; ++r) {
        int m = m0 + wm * 64 + mt * 16 + quad * 4 + r;
        int bb = m >> 11, s = m & 2047;
        qabs[((size_t)((bb << 3) + hh) * 2048 + s) * 128 + col] =
            f2bf((acc[mt][nt][r] + bias) * SCALE_ATT);
      }
    }
}

// ---------------------------------------------------------------------------
// wcombT[n][h*128+c] = sum_d W_o[h*640+d][n] * W_uv[c][h*640+d]
// + fused bvec accumulation: bvec[n] += sum_d buv[h*640+d]*W_o[h*640+d][n]
// As scatter stores XOR-swizzled: k-index ^= (col>>5 & 3)<<4  (was 4-way).
__global__ __launch_bounds__(256) void k_comb(const float* __restrict__ Wo,
                                              const float* __restrict__ Wuv,
                                              const float* __restrict__ buv,
                                              ushort_t* __restrict__ wcombT,
                                              float* __restrict__ bvec) {
  __shared__ __align__(16) ushort_t As[128 * 72];
  __shared__ __align__(16) ushort_t Bs[128 * 72];
  const int tid = threadIdx.x;
  const int n0 = blockIdx.x * 128, hh = blockIdx.y;
  const int lane = tid & 63, wid = tid >> 6;
  const int quad = lane >> 4, l15 = lane & 15;
  const int wm = wid & 1, wn = wid >> 1;
  f32x4 acc[4][4];
#pragma unroll
  for (int a = 0; a < 4; ++a)
#pragma unroll
    for (int b = 0; b < 4; ++b) acc[a][b] = (f32x4){0.f, 0.f, 0.f, 0.f};
  const int ad = tid >> 2, asg = tid & 3;     // asg = col>>5 of staged group
  const int an0 = asg * 32;
  const int akidx = ad ^ (asg << 4);          // swizzled k-slot for As scatter
  const int bc = tid >> 1, bd0 = (tid & 1) * 32;
  // fused bvec partial: thread owns col bvc, half bvh of the k-range
  const int bvc = tid >> 1, bvh = tid & 1;
  const int bsgr = (bvc >> 5) & 3;            // read-side swizzle group
  const float* buvh = buv + hh * 640;
  float bacc = 0.f;
  for (int kb = 0; kb < 640; kb += 64) {
    const float* ap = Wo + (size_t)(hh * 640 + kb + ad) * 5120 + n0 + an0;
#pragma unroll
    for (int i = 0; i < 32; ++i) As[(an0 + i) * 72 + akidx] = f2bf(ap[i]);
    const float* bp = Wuv + (size_t)bc * 5120 + hh * 640 + kb + bd0;
    us8 bv0, bv1, bv2, bv3;
#pragma unroll
    for (int i = 0; i < 8; ++i) {
      bv0[i] = f2bf(bp[i]); bv1[i] = f2bf(bp[8 + i]);
      bv2[i] = f2bf(bp[16 + i]); bv3[i] = f2bf(bp[24 + i]);
    }
    *(us8*)&Bs[bc * 72 + bd0] = bv0;
    *(us8*)&Bs[bc * 72 + bd0 + 8] = bv1;
    *(us8*)&Bs[bc * 72 + bd0 + 16] = bv2;
    *(us8*)&Bs[bc * 72 + bd0 + 24] = bv3;
    __syncthreads();
    // bvec partial from the staged W_o tile (exact col/k mapping via swizzle)
#pragma unroll
    for (int d8 = 0; d8 < 4; ++d8) {
      const int k0 = bvh * 32 + d8 * 8;       // logical k base (8-aligned)
      const us8 a8 = *(const us8*)&As[bvc * 72 + (k0 ^ (bsgr << 4))];
      const f32x4 b4a = *(const f32x4*)&buvh[kb + k0];
      const f32x4 b4b = *(const f32x4*)&buvh[kb + k0 + 4];
      bacc += b4a[0] * bf2f(a8[0]) + b4a[1] * bf2f(a8[1]) +
              b4a[2] * bf2f(a8[2]) + b4a[3] * bf2f(a8[3]) +
              b4b[0] * bf2f(a8[4]) + b4b[1] * bf2f(a8[5]) +
              b4b[2] * bf2f(a8[6]) + b4b[3] * bf2f(a8[7]);
    }
#pragma unroll
    for (int ks = 0; ks < 2; ++ks) {
      short8 a[4], b[4];
#pragma unroll
      for (int mt = 0; mt < 4; ++mt)
        a[mt] = *(const short8*)&As[(wm * 64 + mt * 16 + l15) * 72 +
                                    ((ks * 32 + quad * 8) ^ (((wm * 2 + (mt >> 1)) & 3) << 4))];
#pragma unroll
      for (int nt = 0; nt < 4; ++nt)
        b[nt] = *(const short8*)&Bs[(wn * 64 + nt * 16 + l15) * 72 + ks * 32 + quad * 8];
#pragma unroll
      for (int mt = 0; mt < 4; ++mt)
#pragma unroll
        for (int nt = 0; nt < 4; ++nt) acc[mt][nt] = MFMA(a[mt], b[nt], acc[mt][nt]);
    }
    __syncthreads();
  }
#pragma unroll
  for (int mt = 0; mt < 4; ++mt)
#pragma unroll
    for (int nt = 0; nt < 4; ++nt) {
      int col = wn * 64 + nt * 16 + l15;
#pragma unroll
      for (int r = 0; r < 4; ++r) {
        int n = n0 + wm * 64 + mt * 16 + quad * 4 + r;
        wcombT[(size_t)n * 1024 + hh * 128 + col] = f2bf(acc[mt][nt][r]);
      }
    }
  atomicAdd(&bvec[n0 + bvc], bacc);
}

// ---------------------------------------------------------------------------
// Flash attention over absorbed dims. grid (32 q-tiles, 16 bh), block 256.
// q pre-scaled by producers; defer-rescale + deferred l-reduction (exact);
// Vt scatter XOR-swizzled (key ^= (d>>5)<<4); Qs/Ks stride 168.
__global__ __launch_bounds__(256) void k_attn(const ushort_t* __restrict__ qabs,
                                              const ushort_t* __restrict__ qrot,
                                              const ushort_t* __restrict__ ckv,
                                              const ushort_t* __restrict__ krot,
                                              ushort_t* __restrict__ ctx) {
  __shared__ __align__(16) ushort_t Qs[64 * 168];
  __shared__ __align__(16) ushort_t Ks[64 * 168];
  __shared__ __align__(16) ushort_t Vt[128 * 72];
  __shared__ __align__(16) ushort_t Ps[64 * 72];
  const int tid = threadIdx.x;
  const int bh = blockIdx.y, bb = bh >> 3, hh = bh & 7;
  const int q0 = blockIdx.x * 64;
  const int lane = tid & 63, wid = tid >> 6;
  const int quad = lane >> 4, l15 = lane & 15;
  const int sr = tid >> 2, sseg = tid & 3;
  (void)hh;
  {
    const ushort_t* qa = qabs + ((size_t)bh * 2048 + q0 + sr) * 128 + sseg * 32;
#pragma unroll
    for (int w = 0; w < 4; ++w)
      *(us8*)&Qs[sr * 168 + sseg * 32 + w * 8] = *(const us8*)(qa + w * 8);
    if (sseg == 0) {
      const ushort_t* qr = qrot + ((size_t)bh * 2048 + q0 + sr) * 16;
      *(us8*)&Qs[sr * 168 + 128] = *(const us8*)qr;
      *(us8*)&Qs[sr * 168 + 136] = *(const us8*)(qr + 8);
    }
    if (sseg == 1) {
      us8 z = (us8)0;
      *(us8*)&Qs[sr * 168 + 144] = z;
      *(us8*)&Qs[sr * 168 + 152] = z;
    }
  }
  f32x4 oacc[8];
#pragma unroll
  for (int i = 0; i < 8; ++i) oacc[i] = (f32x4){0.f, 0.f, 0.f, 0.f};
  float mrow[4] = {-1e30f, -1e30f, -1e30f, -1e30f};
  float lrow[4] = {0.f, 0.f, 0.f, 0.f};

  for (int kt = 0; kt < 32; ++kt) {
    int key0 = kt * 64;
    {
      const ushort_t* kp = ckv + ((size_t)bb * 2048 + key0 + sr) * 128 + sseg * 32;
      us8 v[4];
#pragma unroll
      for (int w = 0; w < 4; ++w) v[w] = *(const us8*)(kp + w * 8);
#pragma unroll
      for (int w = 0; w < 4; ++w)
        *(us8*)&Ks[sr * 168 + sseg * 32 + w * 8] = v[w];
      const int vc = sr ^ (sseg << 4);   // swizzled key-slot (d>>5 == sseg)
#pragma unroll
      for (int w = 0; w < 4; ++w)
#pragma unroll
        for (int i = 0; i < 8; ++i)
          Vt[(sseg * 32 + w * 8 + i) * 72 + vc] = v[w][i];
      if (sseg == 0) {
        const ushort_t* kr = krot + ((size_t)bh * 2048 + key0 + sr) * 16;
        *(us8*)&Ks[sr * 168 + 128] = *(const us8*)kr;
        *(us8*)&Ks[sr * 168 + 136] = *(const us8*)(kr + 8);
      }
      if (sseg == 1) {
        us8 z = (us8)0;
        *(us8*)&Ks[sr * 168 + 144] = z;
        *(us8*)&Ks[sr * 168 + 152] = z;
      }
    }
    __syncthreads();
    f32x4 sacc[4];
#pragma unroll
    for (int nt = 0; nt < 4; ++nt) sacc[nt] = (f32x4){0.f, 0.f, 0.f, 0.f};
#pragma unroll
    for (int ks = 0; ks < 5; ++ks) {
      short8 aq = *(const short8*)&Qs[(wid * 16 + l15) * 168 + ks * 32 + quad * 8];
#pragma unroll
      for (int nt = 0; nt < 4; ++nt) {
        short8 bk = *(const short8*)&Ks[(nt * 16 + l15) * 168 + ks * 32 + quad * 8];
        sacc[nt] = MFMA(aq, bk, sacc[nt]);
      }
    }
    float p[4][4];
#pragma unroll
    for (int r = 0; r < 4; ++r) {
      float mx = fmaxf(fmaxf(sacc[0][r], sacc[1][r]), fmaxf(sacc[2][r], sacc[3][r]));
#pragma unroll
      for (int off = 1; off < 16; off <<= 1) mx = fmaxf(mx, __shfl_xor(mx, off));
      if (mx > mrow[r]) {                 // exact: skipped path has alpha==1
        float alpha = __expf(mrow[r] - mx);
        mrow[r] = mx;
        lrow[r] *= alpha;
#pragma unroll
        for (int t8 = 0; t8 < 8; ++t8) oacc[t8][r] *= alpha;
      }
      float rs = 0.f;
#pragma unroll
      for (int nt = 0; nt < 4; ++nt) {
        float pv = __expf(sacc[nt][r] - mrow[r]);
        p[nt][r] = pv;
        rs += pv;
      }
      lrow[r] += rs;                      // per-lane partial; reduced at end
    }
#pragma unroll
    for (int nt = 0; nt < 4; ++nt)
#pragma unroll
      for (int r = 0; r < 4; ++r)
        Ps[(wid * 16 + quad * 4 + r) * 72 + nt * 16 + l15] = f2bf(p[nt][r]);
    __syncthreads();
#pragma unroll
    for (int kk = 0; kk < 2; ++kk) {
      short8 pa = *(const short8*)&Ps[(wid * 16 + l15) * 72 + kk * 32 + quad * 8];
#pragma unroll
      for (int nt = 0; nt < 8; ++nt) {
        short8 vb = *(const short8*)&Vt[(nt * 16 + l15) * 72 +
                                        ((kk * 32 + quad * 8) ^ ((nt >> 1) << 4))];
        oacc[nt] = MFMA(pa, vb, oacc[nt]);
      }
    }
    __syncthreads();
  }
#pragma unroll
  for (int r = 0; r < 4; ++r) {
#pragma unroll
    for (int off = 1; off < 16; off <<= 1) lrow[r] += __shfl_xor(lrow[r], off);
    float rl = 1.f / lrow[r];
    int row = q0 + wid * 16 + quad * 4 + r;
    size_t base = ((size_t)bb * 2048 + row) * 1024 + hh * 128;
#pragma unroll
    for (int nt = 0; nt < 8; ++nt)
      ctx[base + nt * 16 + l15] = f2bf(oacc[nt][r] * rl);
  }
}

// ---------------------------------------------------------------------------
// out = ctx(4096x1024) @ wcombT^T + bvec.  BM=BN=128, BK=64, K=1024. grid (32,40)
__global__ __launch_bounds__(256) void k_final(const ushort_t* __restrict__ ctx,
                                               const ushort_t* __restrict__ wcombT,
                                               const float* __restrict__ bvec,
                                               float* __restrict__ out) {
  __shared__ __align__(16) ushort_t As[128 * 72];
  __shared__ __align__(16) ushort_t Bs[128 * 72];
  const int tid = threadIdx.x;
  const int m0 = blockIdx.x * 128, n0 = blockIdx.y * 128;
  const int lane = tid & 63, wid = tid >> 6;
  const int quad = lane >> 4, l15 = lane & 15;
  const int wm = wid & 1, wn = wid >> 1;
  f32x4 acc[4][4];
#pragma unroll
  for (int a = 0; a < 4; ++a)
#pragma unroll
    for (int b = 0; b < 4; ++b) acc[a][b] = (f32x4){0.f, 0.f, 0.f, 0.f};
  const int ar = tid >> 1, as0 = (tid & 1) * 32;
  for (int kb = 0; kb < 1024; kb += 64) {
    const ushort_t* ap = ctx + (size_t)(m0 + ar) * 1024 + kb + as0;
    const ushort_t* bp = wcombT + (size_t)(n0 + ar) * 1024 + kb + as0;
#pragma unroll
    for (int w = 0; w < 4; ++w) {
      *(us8*)&As[ar * 72 + as0 + w * 8] = *(const us8*)(ap + w * 8);
      *(us8*)&Bs[ar * 72 + as0 + w * 8] = *(const us8*)(bp + w * 8);
    }
    __syncthreads();
#pragma unroll
    for (int ks = 0; ks < 2; ++ks) {
      short8 a[4], b[4];
#pragma unroll
      for (int mt = 0; mt < 4; ++mt)
        a[mt] = *(const short8*)&As[(wm * 64 + mt * 16 + l15) * 72 + ks * 32 + quad * 8];
#pragma unroll
      for (int nt = 0; nt < 4; ++nt)
        b[nt] = *(const short8*)&Bs[(wn * 64 + nt * 16 + l15) * 72 + ks * 32 + quad * 8];
#pragma unroll
      for (int mt = 0; mt < 4; ++mt)
#pragma unroll
        for (int nt = 0; nt < 4; ++nt) acc[mt][nt] = MFMA(a[mt], b[nt], acc[mt][nt]);
    }
    __syncthreads();
  }
#pragma unroll
  for (int mt = 0; mt < 4; ++mt)
#pragma unroll
    for (int nt = 0; nt < 4; ++nt) {
      int col = wn * 64 + nt * 16 + l15;
      float bias = bvec[n0 + col];
#pragma unroll
      for (int r = 0; r < 4; ++r) {
        int row = m0 + wm * 64 + mt * 16 + quad * 4 + r;
        out[(size_t)row * 5120 + n0 + col] = acc[mt][nt][r] + bias;
      }
    }
}

// ---------------------------------------------------------------------------
extern "C" void kernel_launch(void* const* d_in, const int* in_sizes, int n_in,
                              void* d_out, int out_size, void* d_ws, size_t ws_size,
                              hipStream_t stream) {
  const float* H    = (const float*)d_in[0];
  const float* Wdkv = (const float*)d_in[1];
  const float* bdkv = (const float*)d_in[2];
  const float* Wdq  = (const float*)d_in[3];
  const float* bdq  = (const float*)d_in[4];
  const float* Wuk  = (const float*)d_in[5];
  // d_in[6] = b_uk : softmax-invariant -> unused
  const float* Wuv  = (const float*)d_in[7];
  const float* buv  = (const float*)d_in[8];
  const float* Wuq  = (const float*)d_in[9];
  const float* buq  = (const float*)d_in[10];
  const float* Wqr  = (const float*)d_in[11];
  const float* bqr  = (const float*)d_in[12];
  const float* Wkr  = (const float*)d_in[13];
  const float* bkr  = (const float*)d_in[14];
  const float* Wo   = (const float*)d_in[15];
  const float* bo   = (const float*)d_in[16];
  float* out = (float*)d_out;

  char* ws = (char*)d_ws;
  size_t off = 0;
  auto alloc = [&](size_t bytes) -> void* {
    void* p = ws + off;
    off += (bytes + 255) & ~(size_t)255;
    return p;
  };
  // --- region A (persistent) ~4.5 MB
  ushort_t* ckv    = (ushort_t*)alloc((size_t)4096 * 128 * 2);
  ushort_t* cq     = (ushort_t*)alloc((size_t)4096 * 128 * 2);
  ushort_t* krot   = (ushort_t*)alloc((size_t)16 * 2048 * 16 * 2);
  ushort_t* qrot   = (ushort_t*)alloc((size_t)16 * 2048 * 16 * 2);
  ushort_t* wqkT   = (ushort_t*)alloc((size_t)8 * 128 * 128 * 2);
  float*    bqabs  = (float*)alloc((size_t)8 * 128 * 4);
  float*    bvec   = (float*)alloc((size_t)5120 * 4);
  // --- region B: split-K partials (25.2 MB), lifetime: gemm1_sk -> reduce
  size_t mark = off;
  float*    part   = (float*)alloc((size_t)4 * 4096 * 384 * 4);
  size_t endB = off;
  // --- region C aliases B (stream-ordered: all uses launch after k_reduce)
  off = mark;
  ushort_t* qabs   = (ushort_t*)alloc((size_t)16 * 2048 * 128 * 2);
  ushort_t* wcombT = (ushort_t*)alloc((size_t)5120 * 1024 * 2);
  ushort_t* ctx    = (ushort_t*)alloc((size_t)4096 * 1024 * 2);
  if (off < endB) off = endB;
  (void)ws_size; (void)in_sizes; (void)n_in; (void)out_size;

  hipLaunchKernelGGL(k_bvec_init, dim3(20), dim3(256), 0, stream, bo, bvec);
  hipLaunchKernelGGL(k_bqabs, dim3(8), dim3(128), 0, stream, buq, Wuk, bqabs);
  hipLaunchKernelGGL(k_wqk, dim3(8, 8, 8), dim3(256), 0, stream, Wuq, Wuk, wqkT);
  hipLaunchKernelGGL(k_gemm1_sk, dim3(64, 2, 4), dim3(256), 0, stream,
                     H, Wdkv, Wdq, Wkr, part);
  hipLaunchKernelGGL(k_reduce, dim3(4096), dim3(384), 0, stream,
                     part, bdkv, bdq, bkr, ckv, cq, krot);
  hipLaunchKernelGGL(k_comb, dim3(40, 8), dim3(256), 0, stream, Wo, Wuv, buv, wcombT, bvec);
  hipLaunchKernelGGL(k_qrot, dim3(128), dim3(256), 0, stream, cq, Wqr, bqr, qrot);
  hipLaunchKernelGGL(k_qabs, dim3(32, 8), dim3(256), 0, stream, cq, wqkT, bqabs, qabs);
  hipLaunchKernelGGL(k_attn, dim3(32, 16), dim3(256), 0, stream, qabs, qrot, ckv, krot, ctx);
  hipLaunchKernelGGL(k_final, dim3(32, 40), dim3(256), 0, stream, ctx, wcombT, bvec, out);
}

// Round 2
// 679.657 us; speedup vs baseline: 1.0198x; 1.0198x over previous
//
#include <hip/hip_runtime.h>

// ---------------------------------------------------------------------------
// MemoryOptimizedMLA on gfx950 — absorbed-MLA formulation.
//
//   c_kv = h@W_dkv+b ; c_q = h@W_dq+b ; k_rot = rope(h@W_kr+b)
//   W_qk[h] = W_uq_h @ W_uk_h^T (128x128), b_qabs[h] = b_uq_h @ W_uk_h^T
//   q_abs = (c_q@W_qk + b_qabs)/sqrt(640) ; q_rot = rope(c_q@W_qr + b_qr)/sqrt(640)
//   scores = q_abs . c_kv + q_rot . k_rot          (b_uk is softmax-inv.)
//   ctx = softmax(scores) @ c_kv      (128 dims, flash/online-softmax)
//   out = ctx @ W_combT^T + (b_uv@W_o + b_o),  W_comb[h] = W_uv_h @ W_o_h
//
// R2: gemm1 split-K + k_reduce epilogue; ws aliasing.
// R3: bvec fused into k_comb; softmax diet (defer-rescale, deferred l-reduce,
//     pre-scaled q); LDS swizzles (gemm1 Bs, comb As); Qs/Ks stride 168.
// R4: k_attn was VALU/latency-bound (MfmaUtil 12%, VALUBusy 35%, occ 21%):
//     (a) NEW k_ckvt: transpose ckv once -> ckvT; k_attn stages Vt with
//         vectorized us8 copies (kills 32x b16 scatter + extraction per
//         thread per kt = the big VALU+LDS cost);
//     (b) reg-prefetch software pipeline: kt+1 K/V/krot loads issue right
//         after QK MFMA, LDS-write after the post-PV barrier (T14);
//     (c) Ps conversion via v_cvt_pk_bf16_f32 (8 ops vs 64);
//     (d) k_final: same reg-prefetch 2-phase pipeline (loads fly under MFMA).
// ---------------------------------------------------------------------------

typedef unsigned short ushort_t;
typedef __attribute__((ext_vector_type(8)))  short          short8;
typedef __attribute__((ext_vector_type(8)))  unsigned short us8;
typedef __attribute__((ext_vector_type(4)))  float          f32x4;

#define SCALE_ATT 0.0395284707521047f  /* 1/sqrt(640) */

static __device__ inline unsigned short f2bf(float f) {
  union { float f; unsigned u; } v; v.f = f;
  unsigned r = (v.u + 0x7fffu + ((v.u >> 16) & 1u)) >> 16;
  return (unsigned short)r;
}
static __device__ inline float bf2f(unsigned short u) {
  union { unsigned u; float f; } v; v.u = ((unsigned)u) << 16;
  return v.f;
}
static __device__ inline unsigned cvt_pk_bf16(float a, float b) {
  unsigned r;
  asm("v_cvt_pk_bf16_f32 %0, %1, %2" : "=v"(r) : "v"(a), "v"(b));
  return r;  // low16 = bf16(a), high16 = bf16(b), RNE
}
static __device__ inline f32x4 MFMA(short8 a, short8 b, f32x4 c) {
  return __builtin_amdgcn_mfma_f32_16x16x32_bf16(a, b, c, 0, 0, 0);
}

// ---------------------------------------------------------------------------
// bvec init: bvec[n] = bo[n].  grid 20, block 256. (accumulated in k_comb)
__global__ __launch_bounds__(256) void k_bvec_init(const float* __restrict__ bo,
                                                   float* __restrict__ bvec) {
  int n = blockIdx.x * 256 + threadIdx.x;
  bvec[n] = bo[n];
}

// ---------------------------------------------------------------------------
// bqabs[h][j] = sum_d b_uq[h*624+d] * W_uk[j][h*624+d]   grid 8, block 128
__global__ __launch_bounds__(128) void k_bqabs(const float* __restrict__ buq,
                                               const float* __restrict__ Wuk,
                                               float* __restrict__ bqabs) {
  int h = blockIdx.x, j = threadIdx.x;
  float acc = 0.f;
  const float* bq = buq + h * 624;
  const float* wk = Wuk + (size_t)j * 4992 + h * 624;
  for (int d = 0; d < 624; ++d) acc += bq[d] * wk[d];
  bqabs[h * 128 + j] = acc;
}

// ---------------------------------------------------------------------------
// wqkT[h][j][i] = sum_d W_uq[i][h*624+d]*W_uk[j][h*624+d]  (fp32, then bf16)
__global__ __launch_bounds__(256) void k_wqk(const float* __restrict__ Wuq,
                                             const float* __restrict__ Wuk,
                                             ushort_t* __restrict__ wqkT) {
  __shared__ float Aq[16 * 132];
  __shared__ float Ak[16 * 132];
  int jt = blockIdx.x, it = blockIdx.y, h = blockIdx.z;
  int i0 = it * 16, j0 = jt * 16;
  int t = threadIdx.x;
  int srow = t >> 4, sc0 = (t & 15) * 8;
  int ti = t & 15, tj = t >> 4;
  float acc = 0.f;
  for (int dc = 0; dc < 624; dc += 128) {
#pragma unroll
    for (int i = 0; i < 8; ++i) {
      int d = dc + sc0 + i;
      Aq[srow * 132 + sc0 + i] = (d < 624) ? Wuq[(size_t)(i0 + srow) * 4992 + h * 624 + d] : 0.f;
      Ak[srow * 132 + sc0 + i] = (d < 624) ? Wuk[(size_t)(j0 + srow) * 4992 + h * 624 + d] : 0.f;
    }
    __syncthreads();
    int cs = (624 - dc) < 128 ? (624 - dc) : 128;
    for (int d = 0; d < cs; d += 4) {
      const f32x4 a4 = *(const f32x4*)&Aq[ti * 132 + d];
      const f32x4 b4 = *(const f32x4*)&Ak[tj * 132 + d];
      acc += a4[0] * b4[0] + a4[1] * b4[1] + a4[2] * b4[2] + a4[3] * b4[3];
    }
    __syncthreads();
  }
  wqkT[(size_t)h * 16384 + (size_t)(j0 + tj) * 128 + (i0 + ti)] = f2bf(acc);
}

// ---------------------------------------------------------------------------
// GEMM1 split-K: partials of h @ [W_dkv|W_dq|W_kr].
// grid (64 mtiles, 2 nhalves, 4 ksplits), block 256 (4 waves, each 64x48).
__global__ __launch_bounds__(256) void k_gemm1_sk(
    const float* __restrict__ H, const float* __restrict__ Wdkv,
    const float* __restrict__ Wdq, const float* __restrict__ Wkr,
    float* __restrict__ part) {
  __shared__ __align__(16) ushort_t As[64 * 72];
  __shared__ __align__(16) ushort_t Bs[192 * 72];
  const int tid = threadIdx.x;
  const int m0 = blockIdx.x * 64;
  const int n0 = blockIdx.y * 192;
  const int kc0 = blockIdx.z * 1280;
  const int lane = tid & 63, wid = tid >> 6;
  const int quad = lane >> 4, l15 = lane & 15;
  f32x4 acc[4][3];
#pragma unroll
  for (int a = 0; a < 4; ++a)
#pragma unroll
    for (int b = 0; b < 3; ++b) acc[a][b] = (f32x4){0.f, 0.f, 0.f, 0.f};
  const int ar = tid >> 2, ak0 = (tid & 3) * 16;
  const int br = tid >> 2, bsg = tid & 3;
  const int bkidx = br ^ (bsg << 4);   // swizzled k-slot for Bs scatter
  const float* harow = H + (size_t)(m0 + ar) * 5120 + ak0;
  for (int kb = kc0; kb < kc0 + 1280; kb += 64) {
    const float* ap = harow + kb;
    us8 av0, av1;
#pragma unroll
    for (int i = 0; i < 8; ++i) { av0[i] = f2bf(ap[i]); av1[i] = f2bf(ap[8 + i]); }
    *(us8*)&As[ar * 72 + ak0] = av0;
    *(us8*)&As[ar * 72 + ak0 + 8] = av1;
#pragma unroll
    for (int g16 = 0; g16 < 3; ++g16) {
      const int lcol = g16 * 64 + bsg * 16;      // local col group, 16-aligned
      const int col = n0 + lcol;
      const float* base = (col < 128 ? Wdkv + col
                         : col < 256 ? Wdq + (col - 128)
                                     : Wkr + (col - 256)) + (size_t)(kb + br) * 128;
#pragma unroll
      for (int i = 0; i < 16; ++i)
        Bs[(lcol + i) * 72 + bkidx] = f2bf(base[i]);
    }
    __syncthreads();
#pragma unroll
    for (int ks = 0; ks < 2; ++ks) {
      short8 a[4], b[3];
#pragma unroll
      for (int mt = 0; mt < 4; ++mt)
        a[mt] = *(const short8*)&As[(mt * 16 + l15) * 72 + ks * 32 + quad * 8];
#pragma unroll
      for (int nt = 0; nt < 3; ++nt)
        b[nt] = *(const short8*)&Bs[(wid * 48 + nt * 16 + l15) * 72 +
                                    ((ks * 32 + quad * 8) ^ (((wid * 3 + nt) & 3) << 4))];
#pragma unroll
      for (int mt = 0; mt < 4; ++mt)
#pragma unroll
        for (int nt = 0; nt < 3; ++nt) acc[mt][nt] = MFMA(a[mt], b[nt], acc[mt][nt]);
    }
    __syncthreads();
  }
  const size_t pb = (size_t)blockIdx.z * 4096 * 384;
#pragma unroll
  for (int mt = 0; mt < 4; ++mt)
#pragma unroll
    for (int nt = 0; nt < 3; ++nt) {
      const int col = n0 + wid * 48 + nt * 16 + l15;
#pragma unroll
      for (int r = 0; r < 4; ++r) {
        const int row = m0 + mt * 16 + quad * 4 + r;
        part[pb + (size_t)row * 384 + col] = acc[mt][nt][r];
      }
    }
}

// ---------------------------------------------------------------------------
// reduce 4 partials + bias; rope for the k_rot slice. grid 4096, block 384.
__global__ __launch_bounds__(384) void k_reduce(
    const float* __restrict__ part, const float* __restrict__ bdkv,
    const float* __restrict__ bdq, const float* __restrict__ bkr,
    ushort_t* __restrict__ ckv, ushort_t* __restrict__ cq,
    ushort_t* __restrict__ krot) {
  const int row = blockIdx.x;
  const int c = threadIdx.x;
  float v = 0.f;
#pragma unroll
  for (int ks = 0; ks < 4; ++ks)
    v += part[((size_t)ks * 4096 + row) * 384 + c];
  if (c < 128) {
    v += bdkv[c];
    ckv[(size_t)row * 128 + c] = f2bf(v);
  } else if (c < 256) {
    v += bdq[c - 128];
    cq[(size_t)row * 128 + (c - 128)] = f2bf(v);
  } else {
    v += bkr[c - 256];
    float partner = __shfl_xor(v, 4);
    const int j = (c - 256) & 15;
    const int head = (c - 256) >> 4;
    const int s = row & 2047, bb = row >> 11;
    const int j4 = j & 3;
    const float fr = (j4 == 0) ? 1.f : (j4 == 1) ? 0.1f : (j4 == 2) ? 0.01f : 0.001f;
    float sth, cth;
    __sincosf(s * 0.025f * fr, &sth, &cth);
    const float y = (j < 4) ? (v * cth - partner * sth)
                  : (j < 8) ? (v * cth + partner * sth) : v;
    krot[((size_t)((bb << 3) + head) * 2048 + s) * 16 + j] = f2bf(y);
  }
}

// ---------------------------------------------------------------------------
// ckvT[b][d][s] = ckv[b*2048+s][d].  64 blocks x 256 thr, 64 s x 128 d tiles.
__global__ __launch_bounds__(256) void k_ckvt(const ushort_t* __restrict__ ckv,
                                              ushort_t* __restrict__ ckvT) {
  __shared__ __align__(16) ushort_t T[128 * 72];
  const int tid = threadIdx.x;
  const int s0 = blockIdx.x * 64;
  const int bb = s0 >> 11, sl = s0 & 2047;
  const int sr = tid >> 2, sseg = tid & 3;
  {
    const ushort_t* kp = ckv + ((size_t)s0 + sr) * 128 + sseg * 32;
    us8 v[4];
#pragma unroll
    for (int w = 0; w < 4; ++w) v[w] = *(const us8*)(kp + w * 8);
#pragma unroll
    for (int w = 0; w < 4; ++w)
#pragma unroll
      for (int i = 0; i < 8; ++i)
        T[(sseg * 32 + w * 8 + i) * 72 + sr] = v[w][i];
  }
  __syncthreads();
  const int vrow = tid >> 1, vk0 = (tid & 1) * 32;
#pragma unroll
  for (int w = 0; w < 4; ++w) {
    us8 t = *(const us8*)&T[vrow * 72 + vk0 + w * 8];
    *(us8*)(ckvT + ((size_t)bb * 128 + vrow) * 2048 + sl + vk0 + w * 8) = t;
  }
}

// ---------------------------------------------------------------------------
// q_rot = rope(c_q @ W_qr + b_qr) * SCALE_ATT.  grid 128, block 256.
__global__ __launch_bounds__(256) void k_qrot(const ushort_t* __restrict__ cq,
                                              const float* __restrict__ Wqr,
                                              const float* __restrict__ bqr,
                                              ushort_t* __restrict__ qrot) {
  int gidx = blockIdx.x * 256 + threadIdx.x;  // 0..32767
  int s = gidx & 2047, bh = gidx >> 11;
  int hh = bh & 7, bb = bh >> 3;
  const ushort_t* crow = cq + ((size_t)bb * 2048 + s) * 128;
  float acc[16];
#pragma unroll
  for (int j = 0; j < 16; ++j) acc[j] = bqr[hh * 16 + j];
  for (int k0 = 0; k0 < 128; k0 += 8) {
    us8 cv8 = *(const us8*)(crow + k0);
#pragma unroll
    for (int i = 0; i < 8; ++i) {
      float cv = bf2f(cv8[i]);
      const float* wr = Wqr + (size_t)(k0 + i) * 128 + hh * 16;
#pragma unroll
      for (int j = 0; j < 16; ++j) acc[j] += cv * wr[j];
    }
  }
  float y[16];
#pragma unroll
  for (int j4 = 0; j4 < 4; ++j4) {
    float fr = (j4 == 0) ? 1.f : (j4 == 1) ? 0.1f : (j4 == 2) ? 0.01f : 0.001f;
    float sth, cth;
    __sincosf(s * 0.025f * fr, &sth, &cth);
    y[j4] = acc[j4] * cth - acc[j4 + 4] * sth;
    y[j4 + 4] = acc[j4 + 4] * cth + acc[j4] * sth;
  }
#pragma unroll
  for (int j = 8; j < 16; ++j) y[j] = acc[j];
  us8 o0, o1;
#pragma unroll
  for (int j = 0; j < 8; ++j) {
    o0[j] = f2bf(y[j] * SCALE_ATT);
    o1[j] = f2bf(y[8 + j] * SCALE_ATT);
  }
  *(us8*)(qrot + (size_t)gidx * 16) = o0;
  *(us8*)(qrot + (size_t)gidx * 16 + 8) = o1;
}

// ---------------------------------------------------------------------------
// q_abs = (c_q @ W_qk[h] + b_qabs[h]) * SCALE_ATT.  BM=128,BN=128,BK=64. grid (32, 8).
__global__ __launch_bounds__(256) void k_qabs(const ushort_t* __restrict__ cq,
                                              const ushort_t* __restrict__ wqkT,
                                              const float* __restrict__ bqabs,
                                              ushort_t* __restrict__ qabs) {
  __shared__ __align__(16) ushort_t As[128 * 72];
  __shared__ __align__(16) ushort_t Bs[128 * 72];
  const int tid = threadIdx.x;
  const int m0 = blockIdx.x * 128, hh = blockIdx.y;
  const int lane = tid & 63, wid = tid >> 6;
  const int quad = lane >> 4, l15 = lane & 15;
  const int wm = wid & 1, wn = wid >> 1;
  f32x4 acc[4][4];
#pragma unroll
  for (int a = 0; a < 4; ++a)
#pragma unroll
    for (int b = 0; b < 4; ++b) acc[a][b] = (f32x4){0.f, 0.f, 0.f, 0.f};
  const int ar = tid >> 1, as0 = (tid & 1) * 32;
  for (int kb = 0; kb < 128; kb += 64) {
    const ushort_t* ap = cq + (size_t)(m0 + ar) * 128 + kb + as0;
    const ushort_t* bp = wqkT + (size_t)hh * 16384 + (size_t)ar * 128 + kb + as0;
#pragma unroll
    for (int w = 0; w < 4; ++w) {
      *(us8*)&As[ar * 72 + as0 + w * 8] = *(const us8*)(ap + w * 8);
      *(us8*)&Bs[ar * 72 + as0 + w * 8] = *(const us8*)(bp + w * 8);
    }
    __syncthreads();
#pragma unroll
    for (int ks = 0; ks < 2; ++ks) {
      short8 a[4], b[4];
#pragma unroll
      for (int mt = 0; mt < 4; ++mt)
        a[mt] = *(const short8*)&As[(wm * 64 + mt * 16 + l15) * 72 + ks * 32 + quad * 8];
#pragma unroll
      for (int nt = 0; nt < 4; ++nt)
        b[nt] = *(const short8*)&Bs[(wn * 64 + nt * 16 + l15) * 72 + ks * 32 + quad * 8];
#pragma unroll
      for (int mt = 0; mt < 4; ++mt)
#pragma unroll
        for (int nt = 0; nt < 4; ++nt) acc[mt][nt] = MFMA(a[mt], b[nt], acc[mt][nt]);
    }
    __syncthreads();
  }
#pragma unroll
  for (int mt = 0; mt < 4; ++mt)
#pragma unroll
    for (int nt = 0; nt < 4; ++nt) {
      int col = wn * 64 + nt * 16 + l15;
      float bias = bqabs[hh * 128 + col];
#pragma unroll
      for (int r = 0; r < 4; ++r) {
        int m = m0 + wm * 64 + mt * 16 + quad * 4 + r;
        int bb = m >> 11, s = m & 2047;
        qabs[((size_t)((bb << 3) + hh) * 2048 + s) * 128 + col] =
            f2bf((acc[mt][nt][r] + bias) * SCALE_ATT);
      }
    }
}

// ---------------------------------------------------------------------------
// wcombT[n][h*128+c] = sum_d W_o[h*640+d][n] * W_uv[c][h*640+d]
// + fused bvec accumulation: bvec[n] += sum_d buv[h*640+d]*W_o[h*640+d][n]
__global__ __launch_bounds__(256) void k_comb(const float* __restrict__ Wo,
                                              const float* __restrict__ Wuv,
                                              const float* __restrict__ buv,
                                              ushort_t* __restrict__ wcombT,
                                              float* __restrict__ bvec) {
  __shared__ __align__(16) ushort_t As[128 * 72];
  __shared__ __align__(16) ushort_t Bs[128 * 72];
  const int tid = threadIdx.x;
  const int n0 = blockIdx.x * 128, hh = blockIdx.y;
  const int lane = tid & 63, wid = tid >> 6;
  const int quad = lane >> 4, l15 = lane & 15;
  const int wm = wid & 1, wn = wid >> 1;
  f32x4 acc[4][4];
#pragma unroll
  for (int a = 0; a < 4; ++a)
#pragma unroll
    for (int b = 0; b < 4; ++b) acc[a][b] = (f32x4){0.f, 0.f, 0.f, 0.f};
  const int ad = tid >> 2, asg = tid & 3;     // asg = col>>5 of staged group
  const int an0 = asg * 32;
  const int akidx = ad ^ (asg << 4);          // swizzled k-slot for As scatter
  const int bc = tid >> 1, bd0 = (tid & 1) * 32;
  const int bvc = tid >> 1, bvh = tid & 1;
  const int bsgr = (bvc >> 5) & 3;            // read-side swizzle group
  const float* buvh = buv + hh * 640;
  float bacc = 0.f;
  for (int kb = 0; kb < 640; kb += 64) {
    const float* ap = Wo + (size_t)(hh * 640 + kb + ad) * 5120 + n0 + an0;
#pragma unroll
    for (int i = 0; i < 32; ++i) As[(an0 + i) * 72 + akidx] = f2bf(ap[i]);
    const float* bp = Wuv + (size_t)bc * 5120 + hh * 640 + kb + bd0;
    us8 bv0, bv1, bv2, bv3;
#pragma unroll
    for (int i = 0; i < 8; ++i) {
      bv0[i] = f2bf(bp[i]); bv1[i] = f2bf(bp[8 + i]);
      bv2[i] = f2bf(bp[16 + i]); bv3[i] = f2bf(bp[24 + i]);
    }
    *(us8*)&Bs[bc * 72 + bd0] = bv0;
    *(us8*)&Bs[bc * 72 + bd0 + 8] = bv1;
    *(us8*)&Bs[bc * 72 + bd0 + 16] = bv2;
    *(us8*)&Bs[bc * 72 + bd0 + 24] = bv3;
    __syncthreads();
#pragma unroll
    for (int d8 = 0; d8 < 4; ++d8) {
      const int k0 = bvh * 32 + d8 * 8;       // logical k base (8-aligned)
      const us8 a8 = *(const us8*)&As[bvc * 72 + (k0 ^ (bsgr << 4))];
      const f32x4 b4a = *(const f32x4*)&buvh[kb + k0];
      const f32x4 b4b = *(const f32x4*)&buvh[kb + k0 + 4];
      bacc += b4a[0] * bf2f(a8[0]) + b4a[1] * bf2f(a8[1]) +
              b4a[2] * bf2f(a8[2]) + b4a[3] * bf2f(a8[3]) +
              b4b[0] * bf2f(a8[4]) + b4b[1] * bf2f(a8[5]) +
              b4b[2] * bf2f(a8[6]) + b4b[3] * bf2f(a8[7]);
    }
#pragma unroll
    for (int ks = 0; ks < 2; ++ks) {
      short8 a[4], b[4];
#pragma unroll
      for (int mt = 0; mt < 4; ++mt)
        a[mt] = *(const short8*)&As[(wm * 64 + mt * 16 + l15) * 72 +
                                    ((ks * 32 + quad * 8) ^ (((wm * 2 + (mt >> 1)) & 3) << 4))];
#pragma unroll
      for (int nt = 0; nt < 4; ++nt)
        b[nt] = *(const short8*)&Bs[(wn * 64 + nt * 16 + l15) * 72 + ks * 32 + quad * 8];
#pragma unroll
      for (int mt = 0; mt < 4; ++mt)
#pragma unroll
        for (int nt = 0; nt < 4; ++nt) acc[mt][nt] = MFMA(a[mt], b[nt], acc[mt][nt]);
    }
    __syncthreads();
  }
#pragma unroll
  for (int mt = 0; mt < 4; ++mt)
#pragma unroll
    for (int nt = 0; nt < 4; ++nt) {
      int col = wn * 64 + nt * 16 + l15;
#pragma unroll
      for (int r = 0; r < 4; ++r) {
        int n = n0 + wm * 64 + mt * 16 + quad * 4 + r;
        wcombT[(size_t)n * 1024 + hh * 128 + col] = f2bf(acc[mt][nt][r]);
      }
    }
  atomicAdd(&bvec[n0 + bvc], bacc);
}

// ---------------------------------------------------------------------------
// Flash attention over absorbed dims. grid (32 q-tiles, 16 bh), block 256.
// R4: Vt staged from ckvT (vectorized, no scatter); reg-prefetch pipeline;
//     Ps via v_cvt_pk_bf16_f32; defer-rescale + deferred l-reduction (exact).
__global__ __launch_bounds__(256) void k_attn(const ushort_t* __restrict__ qabs,
                                              const ushort_t* __restrict__ qrot,
                                              const ushort_t* __restrict__ ckv,
                                              const ushort_t* __restrict__ krot,
                                              const ushort_t* __restrict__ ckvT,
                                              ushort_t* __restrict__ ctx) {
  __shared__ __align__(16) ushort_t Qs[64 * 168];
  __shared__ __align__(16) ushort_t Ks[64 * 168];
  __shared__ __align__(16) ushort_t Vt[128 * 72];
  __shared__ __align__(16) ushort_t Ps[64 * 72];
  const int tid = threadIdx.x;
  const int bh = blockIdx.y, bb = bh >> 3, hh = bh & 7;
  const int q0 = blockIdx.x * 64;
  const int lane = tid & 63, wid = tid >> 6;
  const int quad = lane >> 4, l15 = lane & 15;
  const int sr = tid >> 2, sseg = tid & 3;
  const int vrow = tid >> 1, vk0 = (tid & 1) * 32;
  (void)hh;
  {  // Q staging (once) + static zero tails for Qs AND Ks (cols 144..159)
    const ushort_t* qa = qabs + ((size_t)bh * 2048 + q0 + sr) * 128 + sseg * 32;
#pragma unroll
    for (int w = 0; w < 4; ++w)
      *(us8*)&Qs[sr * 168 + sseg * 32 + w * 8] = *(const us8*)(qa + w * 8);
    if (sseg == 0) {
      const ushort_t* qr = qrot + ((size_t)bh * 2048 + q0 + sr) * 16;
      *(us8*)&Qs[sr * 168 + 128] = *(const us8*)qr;
      *(us8*)&Qs[sr * 168 + 136] = *(const us8*)(qr + 8);
    }
    if (sseg == 1) {
      us8 z = (us8)0;
      *(us8*)&Qs[sr * 168 + 144] = z;
      *(us8*)&Qs[sr * 168 + 152] = z;
      *(us8*)&Ks[sr * 168 + 144] = z;
      *(us8*)&Ks[sr * 168 + 152] = z;
    }
  }
  us8 kreg[4], vreg[4], krr0, krr1;
  auto loadKV = [&](int key0) {
    const ushort_t* kp = ckv + ((size_t)bb * 2048 + key0 + sr) * 128 + sseg * 32;
#pragma unroll
    for (int w = 0; w < 4; ++w) kreg[w] = *(const us8*)(kp + w * 8);
    const ushort_t* vp = ckvT + ((size_t)bb * 128 + vrow) * 2048 + key0 + vk0;
#pragma unroll
    for (int w = 0; w < 4; ++w) vreg[w] = *(const us8*)(vp + w * 8);
    if (sseg == 0) {
      const ushort_t* kr = krot + ((size_t)bh * 2048 + key0 + sr) * 16;
      krr0 = *(const us8*)kr;
      krr1 = *(const us8*)(kr + 8);
    }
  };
  loadKV(0);
  f32x4 oacc[8];
#pragma unroll
  for (int i = 0; i < 8; ++i) oacc[i] = (f32x4){0.f, 0.f, 0.f, 0.f};
  float mrow[4] = {-1e30f, -1e30f, -1e30f, -1e30f};
  float lrow[4] = {0.f, 0.f, 0.f, 0.f};

  for (int kt = 0; kt < 32; ++kt) {
    // write prefetched regs -> LDS
#pragma unroll
    for (int w = 0; w < 4; ++w)
      *(us8*)&Ks[sr * 168 + sseg * 32 + w * 8] = kreg[w];
    if (sseg == 0) {
      *(us8*)&Ks[sr * 168 + 128] = krr0;
      *(us8*)&Ks[sr * 168 + 136] = krr1;
    }
#pragma unroll
    for (int w = 0; w < 4; ++w)
      *(us8*)&Vt[vrow * 72 + vk0 + w * 8] = vreg[w];
    __syncthreads();
    f32x4 sacc[4];
#pragma unroll
    for (int nt = 0; nt < 4; ++nt) sacc[nt] = (f32x4){0.f, 0.f, 0.f, 0.f};
#pragma unroll
    for (int ks = 0; ks < 5; ++ks) {
      short8 aq = *(const short8*)&Qs[(wid * 16 + l15) * 168 + ks * 32 + quad * 8];
#pragma unroll
      for (int nt = 0; nt < 4; ++nt) {
        short8 bk = *(const short8*)&Ks[(nt * 16 + l15) * 168 + ks * 32 + quad * 8];
        sacc[nt] = MFMA(aq, bk, sacc[nt]);
      }
    }
    if (kt < 31) loadKV((kt + 1) * 64);   // VMEM in flight during softmax+PV
    float p[4][4];
#pragma unroll
    for (int r = 0; r < 4; ++r) {
      float mx = fmaxf(fmaxf(sacc[0][r], sacc[1][r]), fmaxf(sacc[2][r], sacc[3][r]));
#pragma unroll
      for (int off = 1; off < 16; off <<= 1) mx = fmaxf(mx, __shfl_xor(mx, off));
      if (mx > mrow[r]) {                 // exact: skipped path has alpha==1
        float alpha = __expf(mrow[r] - mx);
        mrow[r] = mx;
        lrow[r] *= alpha;
#pragma unroll
        for (int t8 = 0; t8 < 8; ++t8) oacc[t8][r] *= alpha;
      }
      float rs = 0.f;
#pragma unroll
      for (int nt = 0; nt < 4; ++nt) {
        float pv = __expf(sacc[nt][r] - mrow[r]);
        p[nt][r] = pv;
        rs += pv;
      }
      lrow[r] += rs;                      // per-lane partial; reduced at end
    }
#pragma unroll
    for (int nt = 0; nt < 4; ++nt)
#pragma unroll
      for (int rp = 0; rp < 2; ++rp) {
        unsigned pk = cvt_pk_bf16(p[nt][2 * rp], p[nt][2 * rp + 1]);
        int ad = (wid * 16 + quad * 4 + 2 * rp) * 72 + nt * 16 + l15;
        Ps[ad] = (ushort_t)pk;
        Ps[ad + 72] = (ushort_t)(pk >> 16);
      }
    __syncthreads();
#pragma unroll
    for (int kk = 0; kk < 2; ++kk) {
      short8 pa = *(const short8*)&Ps[(wid * 16 + l15) * 72 + kk * 32 + quad * 8];
#pragma unroll
      for (int nt = 0; nt < 8; ++nt) {
        short8 vb = *(const short8*)&Vt[(nt * 16 + l15) * 72 + kk * 32 + quad * 8];
        oacc[nt] = MFMA(pa, vb, oacc[nt]);
      }
    }
    __syncthreads();
  }
#pragma unroll
  for (int r = 0; r < 4; ++r) {
#pragma unroll
    for (int off = 1; off < 16; off <<= 1) lrow[r] += __shfl_xor(lrow[r], off);
    float rl = 1.f / lrow[r];
    int row = q0 + wid * 16 + quad * 4 + r;
    size_t base = ((size_t)bb * 2048 + row) * 1024 + hh * 128;
#pragma unroll
    for (int nt = 0; nt < 8; ++nt)
      ctx[base + nt * 16 + l15] = f2bf(oacc[nt][r] * rl);
  }
}

// ---------------------------------------------------------------------------
// out = ctx(4096x1024) @ wcombT^T + bvec.  BM=BN=128, BK=64, K=1024. grid (32,40)
// R4: reg-prefetch 2-phase pipeline (loads for kb+64 fly under MFMA on kb).
__global__ __launch_bounds__(256) void k_final(const ushort_t* __restrict__ ctx,
                                               const ushort_t* __restrict__ wcombT,
                                               const float* __restrict__ bvec,
                                               float* __restrict__ out) {
  __shared__ __align__(16) ushort_t As[128 * 72];
  __shared__ __align__(16) ushort_t Bs[128 * 72];
  const int tid = threadIdx.x;
  const int m0 = blockIdx.x * 128, n0 = blockIdx.y * 128;
  const int lane = tid & 63, wid = tid >> 6;
  const int quad = lane >> 4, l15 = lane & 15;
  const int wm = wid & 1, wn = wid >> 1;
  f32x4 acc[4][4];
#pragma unroll
  for (int a = 0; a < 4; ++a)
#pragma unroll
    for (int b = 0; b < 4; ++b) acc[a][b] = (f32x4){0.f, 0.f, 0.f, 0.f};
  const int ar = tid >> 1, as0 = (tid & 1) * 32;
  const ushort_t* ap = ctx + (size_t)(m0 + ar) * 1024 + as0;
  const ushort_t* bp = wcombT + (size_t)(n0 + ar) * 1024 + as0;
  us8 ra[4], rb[4];
#pragma unroll
  for (int w = 0; w < 4; ++w) {
    ra[w] = *(const us8*)(ap + w * 8);
    rb[w] = *(const us8*)(bp + w * 8);
  }
  for (int kb = 0; kb < 1024; kb += 64) {
#pragma unroll
    for (int w = 0; w < 4; ++w) {
      *(us8*)&As[ar * 72 + as0 + w * 8] = ra[w];
      *(us8*)&Bs[ar * 72 + as0 + w * 8] = rb[w];
    }
    __syncthreads();
    if (kb < 960) {
      const ushort_t* ap2 = ap + kb + 64;
      const ushort_t* bp2 = bp + kb + 64;
#pragma unroll
      for (int w = 0; w < 4; ++w) {
        ra[w] = *(const us8*)(ap2 + w * 8);
        rb[w] = *(const us8*)(bp2 + w * 8);
      }
    }
#pragma unroll
    for (int ks = 0; ks < 2; ++ks) {
      short8 a[4], b[4];
#pragma unroll
      for (int mt = 0; mt < 4; ++mt)
        a[mt] = *(const short8*)&As[(wm * 64 + mt * 16 + l15) * 72 + ks * 32 + quad * 8];
#pragma unroll
      for (int nt = 0; nt < 4; ++nt)
        b[nt] = *(const short8*)&Bs[(wn * 64 + nt * 16 + l15) * 72 + ks * 32 + quad * 8];
#pragma unroll
      for (int mt = 0; mt < 4; ++mt)
#pragma unroll
        for (int nt = 0; nt < 4; ++nt) acc[mt][nt] = MFMA(a[mt], b[nt], acc[mt][nt]);
    }
    __syncthreads();
  }
#pragma unroll
  for (int mt = 0; mt < 4; ++mt)
#pragma unroll
    for (int nt = 0; nt < 4; ++nt) {
      int col = wn * 64 + nt * 16 + l15;
      float bias = bvec[n0 + col];
#pragma unroll
      for (int r = 0; r < 4; ++r) {
        int row = m0 + wm * 64 + mt * 16 + quad * 4 + r;
        out[(size_t)row * 5120 + n0 + col] = acc[mt][nt][r] + bias;
      }
    }
}

// ---------------------------------------------------------------------------
extern "C" void kernel_launch(void* const* d_in, const int* in_sizes, int n_in,
                              void* d_out, int out_size, void* d_ws, size_t ws_size,
                              hipStream_t stream) {
  const float* H    = (const float*)d_in[0];
  const float* Wdkv = (const float*)d_in[1];
  const float* bdkv = (const float*)d_in[2];
  const float* Wdq  = (const float*)d_in[3];
  const float* bdq  = (const float*)d_in[4];
  const float* Wuk  = (const float*)d_in[5];
  // d_in[6] = b_uk : softmax-invariant -> unused
  const float* Wuv  = (const float*)d_in[7];
  const float* buv  = (const float*)d_in[8];
  const float* Wuq  = (const float*)d_in[9];
  const float* buq  = (const float*)d_in[10];
  const float* Wqr  = (const float*)d_in[11];
  const float* bqr  = (const float*)d_in[12];
  const float* Wkr  = (const float*)d_in[13];
  const float* bkr  = (const float*)d_in[14];
  const float* Wo   = (const float*)d_in[15];
  const float* bo   = (const float*)d_in[16];
  float* out = (float*)d_out;

  char* ws = (char*)d_ws;
  size_t off = 0;
  auto alloc = [&](size_t bytes) -> void* {
    void* p = ws + off;
    off += (bytes + 255) & ~(size_t)255;
    return p;
  };
  // --- region A (persistent) ~5.5 MB
  ushort_t* ckv    = (ushort_t*)alloc((size_t)4096 * 128 * 2);
  ushort_t* cq     = (ushort_t*)alloc((size_t)4096 * 128 * 2);
  ushort_t* ckvT   = (ushort_t*)alloc((size_t)2 * 128 * 2048 * 2);
  ushort_t* krot   = (ushort_t*)alloc((size_t)16 * 2048 * 16 * 2);
  ushort_t* qrot   = (ushort_t*)alloc((size_t)16 * 2048 * 16 * 2);
  ushort_t* wqkT   = (ushort_t*)alloc((size_t)8 * 128 * 128 * 2);
  float*    bqabs  = (float*)alloc((size_t)8 * 128 * 4);
  float*    bvec   = (float*)alloc((size_t)5120 * 4);
  // --- region B: split-K partials (25.2 MB), lifetime: gemm1_sk -> reduce
  size_t mark = off;
  float*    part   = (float*)alloc((size_t)4 * 4096 * 384 * 4);
  size_t endB = off;
  // --- region C aliases B (stream-ordered: all uses launch after k_reduce)
  off = mark;
  ushort_t* qabs   = (ushort_t*)alloc((size_t)16 * 2048 * 128 * 2);
  ushort_t* wcombT = (ushort_t*)alloc((size_t)5120 * 1024 * 2);
  ushort_t* ctx    = (ushort_t*)alloc((size_t)4096 * 1024 * 2);
  if (off < endB) off = endB;
  (void)ws_size; (void)in_sizes; (void)n_in; (void)out_size;

  hipLaunchKernelGGL(k_bvec_init, dim3(20), dim3(256), 0, stream, bo, bvec);
  hipLaunchKernelGGL(k_bqabs, dim3(8), dim3(128), 0, stream, buq, Wuk, bqabs);
  hipLaunchKernelGGL(k_wqk, dim3(8, 8, 8), dim3(256), 0, stream, Wuq, Wuk, wqkT);
  hipLaunchKernelGGL(k_gemm1_sk, dim3(64, 2, 4), dim3(256), 0, stream,
                     H, Wdkv, Wdq, Wkr, part);
  hipLaunchKernelGGL(k_reduce, dim3(4096), dim3(384), 0, stream,
                     part, bdkv, bdq, bkr, ckv, cq, krot);
  hipLaunchKernelGGL(k_ckvt, dim3(64), dim3(256), 0, stream, ckv, ckvT);
  hipLaunchKernelGGL(k_comb, dim3(40, 8), dim3(256), 0, stream, Wo, Wuv, buv, wcombT, bvec);
  hipLaunchKernelGGL(k_qrot, dim3(128), dim3(256), 0, stream, cq, Wqr, bqr, qrot);
  hipLaunchKernelGGL(k_qabs, dim3(32, 8), dim3(256), 0, stream, cq, wqkT, bqabs, qabs);
  hipLaunchKernelGGL(k_attn, dim3(32, 16), dim3(256), 0, stream,
                     qabs, qrot, ckv, krot, ckvT, ctx);
  hipLaunchKernelGGL(k_final, dim3(32, 40), dim3(256), 0, stream, ctx, wcombT, bvec, out);
}

// Round 4
// 652.579 us; speedup vs baseline: 1.0621x; 1.0415x over previous
//
#include <hip/hip_runtime.h>

// ---------------------------------------------------------------------------
// MemoryOptimizedMLA on gfx950 — absorbed-MLA formulation.
//
//   c_kv = h@W_dkv+b ; c_q = h@W_dq+b ; k_rot = rope(h@W_kr+b)
//   W_qk[h] = W_uq_h @ W_uk_h^T (128x128), b_qabs[h] = b_uq_h @ W_uk_h^T
//   q_abs = (c_q@W_qk + b_qabs)/sqrt(640) ; q_rot = rope(c_q@W_qr + b_qr)/sqrt(640)
//   scores = q_abs . c_kv + q_rot . k_rot          (b_uk is softmax-inv.)
//   ctx = softmax(scores) @ c_kv      (128 dims, flash/online-softmax)
//   out = ctx @ W_combT^T + (b_uv@W_o + b_o),  W_comb[h] = W_uv_h @ W_o_h
//
// R2: gemm1 split-K + k_reduce epilogue; ws aliasing.
// R3: bvec fused into k_comb; softmax diet; first LDS swizzles.
// R4: k_ckvt (Vt staged vectorized); reg-prefetch pipelines; cvt_pk Ps.
// R5: k_attn swapped-QK softmax: MFMA(K,Q) makes score rows lane-local ->
//     15 in-lane fmax + 2 shuffles (was 16 shuffles); ballot-gated rescale;
//     Ps as 8 packed b32 writes; mid-loop barrier removed (Ps wave-private).
//     gemm1/comb staging: k-pair-packed b32 LDS scatters via cvt_pk_bf16
//     (half the DS ops, 1/4 the conversion VALU) with XOR bank swizzle on
//     k-bits>=3, compensated at both read sites.
// R6: identical to R5 (previous round's bench never ran — GPU timeout).
// ---------------------------------------------------------------------------

typedef unsigned short ushort_t;
typedef __attribute__((ext_vector_type(8)))  short          short8;
typedef __attribute__((ext_vector_type(8)))  unsigned short us8;
typedef __attribute__((ext_vector_type(4)))  float          f32x4;
typedef __attribute__((ext_vector_type(4)))  unsigned int   u32x4;

#define SCALE_ATT 0.0395284707521047f  /* 1/sqrt(640) */

static __device__ inline unsigned short f2bf(float f) {
  union { float f; unsigned u; } v; v.f = f;
  unsigned r = (v.u + 0x7fffu + ((v.u >> 16) & 1u)) >> 16;
  return (unsigned short)r;
}
static __device__ inline float bf2f(unsigned short u) {
  union { unsigned u; float f; } v; v.u = ((unsigned)u) << 16;
  return v.f;
}
static __device__ inline unsigned cvt_pk_bf16(float a, float b) {
  unsigned r;
  asm("v_cvt_pk_bf16_f32 %0, %1, %2" : "=v"(r) : "v"(a), "v"(b));
  return r;  // low16 = bf16(a), high16 = bf16(b), RNE
}
static __device__ inline f32x4 MFMA(short8 a, short8 b, f32x4 c) {
  return __builtin_amdgcn_mfma_f32_16x16x32_bf16(a, b, c, 0, 0, 0);
}

// ---------------------------------------------------------------------------
// bvec init: bvec[n] = bo[n].  grid 20, block 256. (accumulated in k_comb)
__global__ __launch_bounds__(256) void k_bvec_init(const float* __restrict__ bo,
                                                   float* __restrict__ bvec) {
  int n = blockIdx.x * 256 + threadIdx.x;
  bvec[n] = bo[n];
}

// ---------------------------------------------------------------------------
// bqabs[h][j] = sum_d b_uq[h*624+d] * W_uk[j][h*624+d]   grid 8, block 128
__global__ __launch_bounds__(128) void k_bqabs(const float* __restrict__ buq,
                                               const float* __restrict__ Wuk,
                                               float* __restrict__ bqabs) {
  int h = blockIdx.x, j = threadIdx.x;
  float acc = 0.f;
  const float* bq = buq + h * 624;
  const float* wk = Wuk + (size_t)j * 4992 + h * 624;
  for (int d = 0; d < 624; ++d) acc += bq[d] * wk[d];
  bqabs[h * 128 + j] = acc;
}

// ---------------------------------------------------------------------------
// wqkT[h][j][i] = sum_d W_uq[i][h*624+d]*W_uk[j][h*624+d]  (fp32, then bf16)
__global__ __launch_bounds__(256) void k_wqk(const float* __restrict__ Wuq,
                                             const float* __restrict__ Wuk,
                                             ushort_t* __restrict__ wqkT) {
  __shared__ float Aq[16 * 132];
  __shared__ float Ak[16 * 132];
  int jt = blockIdx.x, it = blockIdx.y, h = blockIdx.z;
  int i0 = it * 16, j0 = jt * 16;
  int t = threadIdx.x;
  int srow = t >> 4, sc0 = (t & 15) * 8;
  int ti = t & 15, tj = t >> 4;
  float acc = 0.f;
  for (int dc = 0; dc < 624; dc += 128) {
#pragma unroll
    for (int i = 0; i < 8; ++i) {
      int d = dc + sc0 + i;
      Aq[srow * 132 + sc0 + i] = (d < 624) ? Wuq[(size_t)(i0 + srow) * 4992 + h * 624 + d] : 0.f;
      Ak[srow * 132 + sc0 + i] = (d < 624) ? Wuk[(size_t)(j0 + srow) * 4992 + h * 624 + d] : 0.f;
    }
    __syncthreads();
    int cs = (624 - dc) < 128 ? (624 - dc) : 128;
    for (int d = 0; d < cs; d += 4) {
      const f32x4 a4 = *(const f32x4*)&Aq[ti * 132 + d];
      const f32x4 b4 = *(const f32x4*)&Ak[tj * 132 + d];
      acc += a4[0] * b4[0] + a4[1] * b4[1] + a4[2] * b4[2] + a4[3] * b4[3];
    }
    __syncthreads();
  }
  wqkT[(size_t)h * 16384 + (size_t)(j0 + tj) * 128 + (i0 + ti)] = f2bf(acc);
}

// ---------------------------------------------------------------------------
// GEMM1 split-K: partials of h @ [W_dkv|W_dq|W_kr].
// grid (64 mtiles, 2 nhalves, 4 ksplits), block 256 (4 waves, each 64x48).
// R5: B staged as k-pair-packed b32 scatters (cvt_pk), physical k index
//     k' = k ^ (((n>>3)&7)<<3); A staged via cvt_pk u32x4.
__global__ __launch_bounds__(256) void k_gemm1_sk(
    const float* __restrict__ H, const float* __restrict__ Wdkv,
    const float* __restrict__ Wdq, const float* __restrict__ Wkr,
    float* __restrict__ part) {
  __shared__ __align__(16) ushort_t As[64 * 72];
  __shared__ __align__(16) ushort_t Bs[192 * 72];
  const int tid = threadIdx.x;
  const int m0 = blockIdx.x * 64;
  const int n0 = blockIdx.y * 192;
  const int kc0 = blockIdx.z * 1280;
  const int lane = tid & 63, wid = tid >> 6;
  const int quad = lane >> 4, l15 = lane & 15;
  f32x4 acc[4][3];
#pragma unroll
  for (int a = 0; a < 4; ++a)
#pragma unroll
    for (int b = 0; b < 3; ++b) acc[a][b] = (f32x4){0.f, 0.f, 0.f, 0.f};
  const int ar = tid >> 2, ak0 = (tid & 3) * 16;
  const int bkp = tid >> 3;   // 0..31: k-pair (k = 2*bkp, 2*bkp+1)
  const int bng = tid & 7;    // n-subgroup of 8 within each 64-col group
  const float* harow = H + (size_t)(m0 + ar) * 5120 + ak0;
  for (int kb = kc0; kb < kc0 + 1280; kb += 64) {
    const float* ap = harow + kb;
    f32x4 af0 = *(const f32x4*)ap, af1 = *(const f32x4*)(ap + 4);
    f32x4 af2 = *(const f32x4*)(ap + 8), af3 = *(const f32x4*)(ap + 12);
    u32x4 apk0 = { cvt_pk_bf16(af0[0], af0[1]), cvt_pk_bf16(af0[2], af0[3]),
                   cvt_pk_bf16(af1[0], af1[1]), cvt_pk_bf16(af1[2], af1[3]) };
    u32x4 apk1 = { cvt_pk_bf16(af2[0], af2[1]), cvt_pk_bf16(af2[2], af2[3]),
                   cvt_pk_bf16(af3[0], af3[1]), cvt_pk_bf16(af3[2], af3[3]) };
    *(u32x4*)&As[ar * 72 + ak0] = apk0;
    *(u32x4*)&As[ar * 72 + ak0 + 8] = apk1;
    const int krow = kb + 2 * bkp;
    const int kd = (2 * bkp) ^ (bng << 3);   // swizzled physical k slot
#pragma unroll
    for (int g = 0; g < 3; ++g) {
      const int lcol = g * 64 + bng * 8;
      const int col = n0 + lcol;
      const float* base = (col < 128 ? Wdkv + col
                         : col < 256 ? Wdq + (col - 128)
                                     : Wkr + (col - 256)) + (size_t)krow * 128;
      f32x4 r0a = *(const f32x4*)base, r0b = *(const f32x4*)(base + 4);
      f32x4 r1a = *(const f32x4*)(base + 128), r1b = *(const f32x4*)(base + 132);
#pragma unroll
      for (int i = 0; i < 4; ++i) {
        *(unsigned*)&Bs[(lcol + i) * 72 + kd]     = cvt_pk_bf16(r0a[i], r1a[i]);
        *(unsigned*)&Bs[(lcol + 4 + i) * 72 + kd] = cvt_pk_bf16(r0b[i], r1b[i]);
      }
    }
    __syncthreads();
#pragma unroll
    for (int ks = 0; ks < 2; ++ks) {
      short8 a[4], b[3];
#pragma unroll
      for (int mt = 0; mt < 4; ++mt)
        a[mt] = *(const short8*)&As[(mt * 16 + l15) * 72 + ks * 32 + quad * 8];
#pragma unroll
      for (int nt = 0; nt < 3; ++nt) {
        const int row = wid * 48 + nt * 16 + l15;
        const int kofs = (ks * 32 + quad * 8) ^ (((row >> 3) & 7) << 3);
        b[nt] = *(const short8*)&Bs[row * 72 + kofs];
      }
#pragma unroll
      for (int mt = 0; mt < 4; ++mt)
#pragma unroll
        for (int nt = 0; nt < 3; ++nt) acc[mt][nt] = MFMA(a[mt], b[nt], acc[mt][nt]);
    }
    __syncthreads();
  }
  const size_t pb = (size_t)blockIdx.z * 4096 * 384;
#pragma unroll
  for (int mt = 0; mt < 4; ++mt)
#pragma unroll
    for (int nt = 0; nt < 3; ++nt) {
      const int col = n0 + wid * 48 + nt * 16 + l15;
#pragma unroll
      for (int r = 0; r < 4; ++r) {
        const int row = m0 + mt * 16 + quad * 4 + r;
        part[pb + (size_t)row * 384 + col] = acc[mt][nt][r];
      }
    }
}

// ---------------------------------------------------------------------------
// reduce 4 partials + bias; rope for the k_rot slice. grid 4096, block 384.
__global__ __launch_bounds__(384) void k_reduce(
    const float* __restrict__ part, const float* __restrict__ bdkv,
    const float* __restrict__ bdq, const float* __restrict__ bkr,
    ushort_t* __restrict__ ckv, ushort_t* __restrict__ cq,
    ushort_t* __restrict__ krot) {
  const int row = blockIdx.x;
  const int c = threadIdx.x;
  float v = 0.f;
#pragma unroll
  for (int ks = 0; ks < 4; ++ks)
    v += part[((size_t)ks * 4096 + row) * 384 + c];
  if (c < 128) {
    v += bdkv[c];
    ckv[(size_t)row * 128 + c] = f2bf(v);
  } else if (c < 256) {
    v += bdq[c - 128];
    cq[(size_t)row * 128 + (c - 128)] = f2bf(v);
  } else {
    v += bkr[c - 256];
    float partner = __shfl_xor(v, 4);
    const int j = (c - 256) & 15;
    const int head = (c - 256) >> 4;
    const int s = row & 2047, bb = row >> 11;
    const int j4 = j & 3;
    const float fr = (j4 == 0) ? 1.f : (j4 == 1) ? 0.1f : (j4 == 2) ? 0.01f : 0.001f;
    float sth, cth;
    __sincosf(s * 0.025f * fr, &sth, &cth);
    const float y = (j < 4) ? (v * cth - partner * sth)
                  : (j < 8) ? (v * cth + partner * sth) : v;
    krot[((size_t)((bb << 3) + head) * 2048 + s) * 16 + j] = f2bf(y);
  }
}

// ---------------------------------------------------------------------------
// ckvT[b][d][s] = ckv[b*2048+s][d].  64 blocks x 256 thr, 64 s x 128 d tiles.
__global__ __launch_bounds__(256) void k_ckvt(const ushort_t* __restrict__ ckv,
                                              ushort_t* __restrict__ ckvT) {
  __shared__ __align__(16) ushort_t T[128 * 72];
  const int tid = threadIdx.x;
  const int s0 = blockIdx.x * 64;
  const int bb = s0 >> 11, sl = s0 & 2047;
  const int sr = tid >> 2, sseg = tid & 3;
  {
    const ushort_t* kp = ckv + ((size_t)s0 + sr) * 128 + sseg * 32;
    us8 v[4];
#pragma unroll
    for (int w = 0; w < 4; ++w) v[w] = *(const us8*)(kp + w * 8);
#pragma unroll
    for (int w = 0; w < 4; ++w)
#pragma unroll
      for (int i = 0; i < 8; ++i)
        T[(sseg * 32 + w * 8 + i) * 72 + sr] = v[w][i];
  }
  __syncthreads();
  const int vrow = tid >> 1, vk0 = (tid & 1) * 32;
#pragma unroll
  for (int w = 0; w < 4; ++w) {
    us8 t = *(const us8*)&T[vrow * 72 + vk0 + w * 8];
    *(us8*)(ckvT + ((size_t)bb * 128 + vrow) * 2048 + sl + vk0 + w * 8) = t;
  }
}

// ---------------------------------------------------------------------------
// q_rot = rope(c_q @ W_qr + b_qr) * SCALE_ATT.  grid 128, block 256.
__global__ __launch_bounds__(256) void k_qrot(const ushort_t* __restrict__ cq,
                                              const float* __restrict__ Wqr,
                                              const float* __restrict__ bqr,
                                              ushort_t* __restrict__ qrot) {
  int gidx = blockIdx.x * 256 + threadIdx.x;  // 0..32767
  int s = gidx & 2047, bh = gidx >> 11;
  int hh = bh & 7, bb = bh >> 3;
  const ushort_t* crow = cq + ((size_t)bb * 2048 + s) * 128;
  float acc[16];
#pragma unroll
  for (int j = 0; j < 16; ++j) acc[j] = bqr[hh * 16 + j];
  for (int k0 = 0; k0 < 128; k0 += 8) {
    us8 cv8 = *(const us8*)(crow + k0);
#pragma unroll
    for (int i = 0; i < 8; ++i) {
      float cv = bf2f(cv8[i]);
      const float* wr = Wqr + (size_t)(k0 + i) * 128 + hh * 16;
#pragma unroll
      for (int j = 0; j < 16; ++j) acc[j] += cv * wr[j];
    }
  }
  float y[16];
#pragma unroll
  for (int j4 = 0; j4 < 4; ++j4) {
    float fr = (j4 == 0) ? 1.f : (j4 == 1) ? 0.1f : (j4 == 2) ? 0.01f : 0.001f;
    float sth, cth;
    __sincosf(s * 0.025f * fr, &sth, &cth);
    y[j4] = acc[j4] * cth - acc[j4 + 4] * sth;
    y[j4 + 4] = acc[j4 + 4] * cth + acc[j4] * sth;
  }
#pragma unroll
  for (int j = 8; j < 16; ++j) y[j] = acc[j];
  us8 o0, o1;
#pragma unroll
  for (int j = 0; j < 8; ++j) {
    o0[j] = f2bf(y[j] * SCALE_ATT);
    o1[j] = f2bf(y[8 + j] * SCALE_ATT);
  }
  *(us8*)(qrot + (size_t)gidx * 16) = o0;
  *(us8*)(qrot + (size_t)gidx * 16 + 8) = o1;
}

// ---------------------------------------------------------------------------
// q_abs = (c_q @ W_qk[h] + b_qabs[h]) * SCALE_ATT.  BM=128,BN=128,BK=64. grid (32, 8).
__global__ __launch_bounds__(256) void k_qabs(const ushort_t* __restrict__ cq,
                                              const ushort_t* __restrict__ wqkT,
                                              const float* __restrict__ bqabs,
                                              ushort_t* __restrict__ qabs) {
  __shared__ __align__(16) ushort_t As[128 * 72];
  __shared__ __align__(16) ushort_t Bs[128 * 72];
  const int tid = threadIdx.x;
  const int m0 = blockIdx.x * 128, hh = blockIdx.y;
  const int lane = tid & 63, wid = tid >> 6;
  const int quad = lane >> 4, l15 = lane & 15;
  const int wm = wid & 1, wn = wid >> 1;
  f32x4 acc[4][4];
#pragma unroll
  for (int a = 0; a < 4; ++a)
#pragma unroll
    for (int b = 0; b < 4; ++b) acc[a][b] = (f32x4){0.f, 0.f, 0.f, 0.f};
  const int ar = tid >> 1, as0 = (tid & 1) * 32;
  for (int kb = 0; kb < 128; kb += 64) {
    const ushort_t* ap = cq + (size_t)(m0 + ar) * 128 + kb + as0;
    const ushort_t* bp = wqkT + (size_t)hh * 16384 + (size_t)ar * 128 + kb + as0;
#pragma unroll
    for (int w = 0; w < 4; ++w) {
      *(us8*)&As[ar * 72 + as0 + w * 8] = *(const us8*)(ap + w * 8);
      *(us8*)&Bs[ar * 72 + as0 + w * 8] = *(const us8*)(bp + w * 8);
    }
    __syncthreads();
#pragma unroll
    for (int ks = 0; ks < 2; ++ks) {
      short8 a[4], b[4];
#pragma unroll
      for (int mt = 0; mt < 4; ++mt)
        a[mt] = *(const short8*)&As[(wm * 64 + mt * 16 + l15) * 72 + ks * 32 + quad * 8];
#pragma unroll
      for (int nt = 0; nt < 4; ++nt)
        b[nt] = *(const short8*)&Bs[(wn * 64 + nt * 16 + l15) * 72 + ks * 32 + quad * 8];
#pragma unroll
      for (int mt = 0; mt < 4; ++mt)
#pragma unroll
        for (int nt = 0; nt < 4; ++nt) acc[mt][nt] = MFMA(a[mt], b[nt], acc[mt][nt]);
    }
    __syncthreads();
  }
#pragma unroll
  for (int mt = 0; mt < 4; ++mt)
#pragma unroll
    for (int nt = 0; nt < 4; ++nt) {
      int col = wn * 64 + nt * 16 + l15;
      float bias = bqabs[hh * 128 + col];
#pragma unroll
      for (int r = 0; r < 4; ++r) {
        int m = m0 + wm * 64 + mt * 16 + quad * 4 + r;
        int bb = m >> 11, s = m & 2047;
        qabs[((size_t)((bb << 3) + hh) * 2048 + s) * 128 + col] =
            f2bf((acc[mt][nt][r] + bias) * SCALE_ATT);
      }
    }
}

// ---------------------------------------------------------------------------
// wcombT[n][h*128+c] = sum_d W_o[h*640+d][n] * W_uv[c][h*640+d]
// + fused bvec accumulation: bvec[n] += sum_d buv[h*640+d]*W_o[h*640+d][n]
// R5: As staged as k-pair-packed b32 scatters (cvt_pk), physical
//     k' = k ^ (((n>>3)&7)<<3); Bs conversions via cvt_pk.
__global__ __launch_bounds__(256) void k_comb(const float* __restrict__ Wo,
                                              const float* __restrict__ Wuv,
                                              const float* __restrict__ buv,
                                              ushort_t* __restrict__ wcombT,
                                              float* __restrict__ bvec) {
  __shared__ __align__(16) ushort_t As[128 * 72];
  __shared__ __align__(16) ushort_t Bs[128 * 72];
  const int tid = threadIdx.x;
  const int n0 = blockIdx.x * 128, hh = blockIdx.y;
  const int lane = tid & 63, wid = tid >> 6;
  const int quad = lane >> 4, l15 = lane & 15;
  const int wm = wid & 1, wn = wid >> 1;
  f32x4 acc[4][4];
#pragma unroll
  for (int a = 0; a < 4; ++a)
#pragma unroll
    for (int b = 0; b < 4; ++b) acc[a][b] = (f32x4){0.f, 0.f, 0.f, 0.f};
  const int akp = tid >> 3;   // 0..31: k-pair
  const int ang = tid & 7;    // n-group of 16
  const int kd0 = (2 * akp) ^ (((2 * ang) & 7) << 3);
  const int kd1 = (2 * akp) ^ (((2 * ang + 1) & 7) << 3);
  const int bc = tid >> 1, bd0 = (tid & 1) * 32;
  const int bvc = tid >> 1, bvh = tid & 1;
  const int bswz = ((bvc >> 3) & 7) << 3;     // bacc read-side swizzle
  const float* buvh = buv + hh * 640;
  float bacc = 0.f;
  for (int kb = 0; kb < 640; kb += 64) {
    {
      const float* ap0 = Wo + (size_t)(hh * 640 + kb + 2 * akp) * 5120 + n0 + ang * 16;
      const float* ap1 = ap0 + 5120;
      f32x4 r0[4], r1[4];
#pragma unroll
      for (int w = 0; w < 4; ++w) {
        r0[w] = *(const f32x4*)(ap0 + w * 4);
        r1[w] = *(const f32x4*)(ap1 + w * 4);
      }
#pragma unroll
      for (int w = 0; w < 2; ++w)
#pragma unroll
        for (int i = 0; i < 4; ++i)
          *(unsigned*)&As[(ang * 16 + w * 4 + i) * 72 + kd0] =
              cvt_pk_bf16(r0[w][i], r1[w][i]);
#pragma unroll
      for (int w = 2; w < 4; ++w)
#pragma unroll
        for (int i = 0; i < 4; ++i)
          *(unsigned*)&As[(ang * 16 + w * 4 + i) * 72 + kd1] =
              cvt_pk_bf16(r0[w][i], r1[w][i]);
    }
    const float* bp = Wuv + (size_t)bc * 5120 + hh * 640 + kb + bd0;
    f32x4 b0 = *(const f32x4*)bp, b1 = *(const f32x4*)(bp + 4);
    f32x4 b2 = *(const f32x4*)(bp + 8), b3 = *(const f32x4*)(bp + 12);
    f32x4 b4 = *(const f32x4*)(bp + 16), b5 = *(const f32x4*)(bp + 20);
    f32x4 b6 = *(const f32x4*)(bp + 24), b7 = *(const f32x4*)(bp + 28);
    u32x4 q0 = { cvt_pk_bf16(b0[0], b0[1]), cvt_pk_bf16(b0[2], b0[3]),
                 cvt_pk_bf16(b1[0], b1[1]), cvt_pk_bf16(b1[2], b1[3]) };
    u32x4 q1 = { cvt_pk_bf16(b2[0], b2[1]), cvt_pk_bf16(b2[2], b2[3]),
                 cvt_pk_bf16(b3[0], b3[1]), cvt_pk_bf16(b3[2], b3[3]) };
    u32x4 q2 = { cvt_pk_bf16(b4[0], b4[1]), cvt_pk_bf16(b4[2], b4[3]),
                 cvt_pk_bf16(b5[0], b5[1]), cvt_pk_bf16(b5[2], b5[3]) };
    u32x4 q3 = { cvt_pk_bf16(b6[0], b6[1]), cvt_pk_bf16(b6[2], b6[3]),
                 cvt_pk_bf16(b7[0], b7[1]), cvt_pk_bf16(b7[2], b7[3]) };
    *(u32x4*)&Bs[bc * 72 + bd0]      = q0;
    *(u32x4*)&Bs[bc * 72 + bd0 + 8]  = q1;
    *(u32x4*)&Bs[bc * 72 + bd0 + 16] = q2;
    *(u32x4*)&Bs[bc * 72 + bd0 + 24] = q3;
    __syncthreads();
    // bvec partial from the staged W_o tile (swizzle-compensated read)
#pragma unroll
    for (int d8 = 0; d8 < 4; ++d8) {
      const int k0 = bvh * 32 + d8 * 8;       // logical k base (8-aligned)
      const us8 a8 = *(const us8*)&As[bvc * 72 + (k0 ^ bswz)];
      const f32x4 b4a = *(const f32x4*)&buvh[kb + k0];
      const f32x4 b4b = *(const f32x4*)&buvh[kb + k0 + 4];
      bacc += b4a[0] * bf2f(a8[0]) + b4a[1] * bf2f(a8[1]) +
              b4a[2] * bf2f(a8[2]) + b4a[3] * bf2f(a8[3]) +
              b4b[0] * bf2f(a8[4]) + b4b[1] * bf2f(a8[5]) +
              b4b[2] * bf2f(a8[6]) + b4b[3] * bf2f(a8[7]);
    }
#pragma unroll
    for (int ks = 0; ks < 2; ++ks) {
      short8 a[4], b[4];
#pragma unroll
      for (int mt = 0; mt < 4; ++mt) {
        const int row = wm * 64 + mt * 16 + l15;
        const int kofs = (ks * 32 + quad * 8) ^ (((row >> 3) & 7) << 3);
        a[mt] = *(const short8*)&As[row * 72 + kofs];
      }
#pragma unroll
      for (int nt = 0; nt < 4; ++nt)
        b[nt] = *(const short8*)&Bs[(wn * 64 + nt * 16 + l15) * 72 + ks * 32 + quad * 8];
#pragma unroll
      for (int mt = 0; mt < 4; ++mt)
#pragma unroll
        for (int nt = 0; nt < 4; ++nt) acc[mt][nt] = MFMA(a[mt], b[nt], acc[mt][nt]);
    }
    __syncthreads();
  }
#pragma unroll
  for (int mt = 0; mt < 4; ++mt)
#pragma unroll
    for (int nt = 0; nt < 4; ++nt) {
      int col = wn * 64 + nt * 16 + l15;
#pragma unroll
      for (int r = 0; r < 4; ++r) {
        int n = n0 + wm * 64 + mt * 16 + quad * 4 + r;
        wcombT[(size_t)n * 1024 + hh * 128 + col] = f2bf(acc[mt][nt][r]);
      }
    }
  atomicAdd(&bvec[n0 + bvc], bacc);
}

// ---------------------------------------------------------------------------
// Flash attention over absorbed dims. grid (32 q-tiles, 16 bh), block 256.
// R5: swapped-QK softmax — MFMA(K,Q) puts the 16 scores of query l15 into
//     this lane's regs: 15 in-lane fmax + 2 shuffles; ballot-gated PV
//     rescale (4 bpermutes only when a max grows); Ps = 8 packed b32
//     writes; 2 barriers/kt (mid barrier removed: Ps is wave-private).
__global__ __launch_bounds__(256) void k_attn(const ushort_t* __restrict__ qabs,
                                              const ushort_t* __restrict__ qrot,
                                              const ushort_t* __restrict__ ckv,
                                              const ushort_t* __restrict__ krot,
                                              const ushort_t* __restrict__ ckvT,
                                              ushort_t* __restrict__ ctx) {
  __shared__ __align__(16) ushort_t Qs[64 * 168];
  __shared__ __align__(16) ushort_t Ks[64 * 168];
  __shared__ __align__(16) ushort_t Vt[128 * 72];
  __shared__ __align__(16) ushort_t Ps[64 * 72];
  const int tid = threadIdx.x;
  const int bh = blockIdx.y, bb = bh >> 3, hh = bh & 7;
  const int q0 = blockIdx.x * 64;
  const int lane = tid & 63, wid = tid >> 6;
  const int quad = lane >> 4, l15 = lane & 15;
  const int sr = tid >> 2, sseg = tid & 3;
  const int vrow = tid >> 1, vk0 = (tid & 1) * 32;
  (void)hh;
  {  // Q staging (once) + static zero tails for Qs AND Ks (cols 144..159)
    const ushort_t* qa = qabs + ((size_t)bh * 2048 + q0 + sr) * 128 + sseg * 32;
#pragma unroll
    for (int w = 0; w < 4; ++w)
      *(us8*)&Qs[sr * 168 + sseg * 32 + w * 8] = *(const us8*)(qa + w * 8);
    if (sseg == 0) {
      const ushort_t* qr = qrot + ((size_t)bh * 2048 + q0 + sr) * 16;
      *(us8*)&Qs[sr * 168 + 128] = *(const us8*)qr;
      *(us8*)&Qs[sr * 168 + 136] = *(const us8*)(qr + 8);
    }
    if (sseg == 1) {
      us8 z = (us8)0;
      *(us8*)&Qs[sr * 168 + 144] = z;
      *(us8*)&Qs[sr * 168 + 152] = z;
      *(us8*)&Ks[sr * 168 + 144] = z;
      *(us8*)&Ks[sr * 168 + 152] = z;
    }
  }
  us8 kreg[4], vreg[4], krr0, krr1;
  auto loadKV = [&](int key0) {
    const ushort_t* kp = ckv + ((size_t)bb * 2048 + key0 + sr) * 128 + sseg * 32;
#pragma unroll
    for (int w = 0; w < 4; ++w) kreg[w] = *(const us8*)(kp + w * 8);
    const ushort_t* vp = ckvT + ((size_t)bb * 128 + vrow) * 2048 + key0 + vk0;
#pragma unroll
    for (int w = 0; w < 4; ++w) vreg[w] = *(const us8*)(vp + w * 8);
    if (sseg == 0) {
      const ushort_t* kr = krot + ((size_t)bh * 2048 + key0 + sr) * 16;
      krr0 = *(const us8*)kr;
      krr1 = *(const us8*)(kr + 8);
    }
  };
  loadKV(0);
  f32x4 oacc[8];
#pragma unroll
  for (int i = 0; i < 8; ++i) oacc[i] = (f32x4){0.f, 0.f, 0.f, 0.f};
  float mrow[4] = {-1e30f, -1e30f, -1e30f, -1e30f};  // PV-side (q = quad*4+r)
  float m_sm = -1e30f;                               // SM-side (q = l15)
  float lrow_l = 0.f;                                // per-lane partial sum

  for (int kt = 0; kt < 32; ++kt) {
    // write prefetched regs -> LDS
#pragma unroll
    for (int w = 0; w < 4; ++w)
      *(us8*)&Ks[sr * 168 + sseg * 32 + w * 8] = kreg[w];
    if (sseg == 0) {
      *(us8*)&Ks[sr * 168 + 128] = krr0;
      *(us8*)&Ks[sr * 168 + 136] = krr1;
    }
#pragma unroll
    for (int w = 0; w < 4; ++w)
      *(us8*)&Vt[vrow * 72 + vk0 + w * 8] = vreg[w];
    __syncthreads();
    f32x4 sacc[4];   // sacc[nt][r]: key = nt*16 + quad*4 + r, query = l15
#pragma unroll
    for (int nt = 0; nt < 4; ++nt) sacc[nt] = (f32x4){0.f, 0.f, 0.f, 0.f};
#pragma unroll
    for (int ks = 0; ks < 5; ++ks) {
      short8 aq = *(const short8*)&Qs[(wid * 16 + l15) * 168 + ks * 32 + quad * 8];
#pragma unroll
      for (int nt = 0; nt < 4; ++nt) {
        short8 bk = *(const short8*)&Ks[(nt * 16 + l15) * 168 + ks * 32 + quad * 8];
        sacc[nt] = MFMA(bk, aq, sacc[nt]);   // swapped: D[key][query]
      }
    }
    if (kt < 31) loadKV((kt + 1) * 64);   // VMEM in flight during softmax+PV
    // ---- swapped softmax: lane owns query l15, 16 keys in regs
    float mx = sacc[0][0];
#pragma unroll
    for (int nt = 0; nt < 4; ++nt)
#pragma unroll
      for (int r = 0; r < 4; ++r) mx = fmaxf(mx, sacc[nt][r]);
    mx = fmaxf(mx, __shfl_xor(mx, 16));
    mx = fmaxf(mx, __shfl_xor(mx, 32));
    const bool grew = mx > m_sm;
    if (__any(grew)) {
      if (grew) { lrow_l *= __expf(m_sm - mx); m_sm = mx; }
#pragma unroll
      for (int r = 0; r < 4; ++r) {
        float mnew = __shfl(m_sm, quad * 4 + r);
        if (mnew > mrow[r]) {
          float alpha = __expf(mrow[r] - mnew);
          mrow[r] = mnew;
#pragma unroll
          for (int t8 = 0; t8 < 8; ++t8) oacc[t8][r] *= alpha;
        }
      }
    }
    float rs = 0.f;
    const int prow = (wid * 16 + l15) * 72 + quad * 4;
#pragma unroll
    for (int nt = 0; nt < 4; ++nt) {
      float p0 = __expf(sacc[nt][0] - m_sm);
      float p1 = __expf(sacc[nt][1] - m_sm);
      float p2 = __expf(sacc[nt][2] - m_sm);
      float p3 = __expf(sacc[nt][3] - m_sm);
      rs += (p0 + p1) + (p2 + p3);
      *(unsigned*)&Ps[prow + nt * 16]     = cvt_pk_bf16(p0, p1);
      *(unsigned*)&Ps[prow + nt * 16 + 2] = cvt_pk_bf16(p2, p3);
    }
    lrow_l += rs;
    // Ps rows are wave-private: no barrier needed before PV (intra-wave
    // LDS RAW ordered by compiler-inserted lgkmcnt).
#pragma unroll
    for (int kk = 0; kk < 2; ++kk) {
      short8 pa = *(const short8*)&Ps[(wid * 16 + l15) * 72 + kk * 32 + quad * 8];
#pragma unroll
      for (int nt = 0; nt < 8; ++nt) {
        short8 vb = *(const short8*)&Vt[(nt * 16 + l15) * 72 + kk * 32 + quad * 8];
        oacc[nt] = MFMA(pa, vb, oacc[nt]);
      }
    }
    __syncthreads();
  }
  lrow_l += __shfl_xor(lrow_l, 16);
  lrow_l += __shfl_xor(lrow_l, 32);
#pragma unroll
  for (int r = 0; r < 4; ++r) {
    float rl = 1.f / __shfl(lrow_l, quad * 4 + r);
    int row = q0 + wid * 16 + quad * 4 + r;
    size_t base = ((size_t)bb * 2048 + row) * 1024 + hh * 128;
#pragma unroll
    for (int nt = 0; nt < 8; ++nt)
      ctx[base + nt * 16 + l15] = f2bf(oacc[nt][r] * rl);
  }
}

// ---------------------------------------------------------------------------
// out = ctx(4096x1024) @ wcombT^T + bvec.  BM=BN=128, BK=64, K=1024. grid (32,40)
// reg-prefetch 2-phase pipeline (loads for kb+64 fly under MFMA on kb).
__global__ __launch_bounds__(256) void k_final(const ushort_t* __restrict__ ctx,
                                               const ushort_t* __restrict__ wcombT,
                                               const float* __restrict__ bvec,
                                               float* __restrict__ out) {
  __shared__ __align__(16) ushort_t As[128 * 72];
  __shared__ __align__(16) ushort_t Bs[128 * 72];
  const int tid = threadIdx.x;
  const int m0 = blockIdx.x * 128, n0 = blockIdx.y * 128;
  const int lane = tid & 63, wid = tid >> 6;
  const int quad = lane >> 4, l15 = lane & 15;
  const int wm = wid & 1, wn = wid >> 1;
  f32x4 acc[4][4];
#pragma unroll
  for (int a = 0; a < 4; ++a)
#pragma unroll
    for (int b = 0; b < 4; ++b) acc[a][b] = (f32x4){0.f, 0.f, 0.f, 0.f};
  const int ar = tid >> 1, as0 = (tid & 1) * 32;
  const ushort_t* ap = ctx + (size_t)(m0 + ar) * 1024 + as0;
  const ushort_t* bp = wcombT + (size_t)(n0 + ar) * 1024 + as0;
  us8 ra[4], rb[4];
#pragma unroll
  for (int w = 0; w < 4; ++w) {
    ra[w] = *(const us8*)(ap + w * 8);
    rb[w] = *(const us8*)(bp + w * 8);
  }
  for (int kb = 0; kb < 1024; kb += 64) {
#pragma unroll
    for (int w = 0; w < 4; ++w) {
      *(us8*)&As[ar * 72 + as0 + w * 8] = ra[w];
      *(us8*)&Bs[ar * 72 + as0 + w * 8] = rb[w];
    }
    __syncthreads();
    if (kb < 960) {
      const ushort_t* ap2 = ap + kb + 64;
      const ushort_t* bp2 = bp + kb + 64;
#pragma unroll
      for (int w = 0; w < 4; ++w) {
        ra[w] = *(const us8*)(ap2 + w * 8);
        rb[w] = *(const us8*)(bp2 + w * 8);
      }
    }
#pragma unroll
    for (int ks = 0; ks < 2; ++ks) {
      short8 a[4], b[4];
#pragma unroll
      for (int mt = 0; mt < 4; ++mt)
        a[mt] = *(const short8*)&As[(wm * 64 + mt * 16 + l15) * 72 + ks * 32 + quad * 8];
#pragma unroll
      for (int nt = 0; nt < 4; ++nt)
        b[nt] = *(const short8*)&Bs[(wn * 64 + nt * 16 + l15) * 72 + ks * 32 + quad * 8];
#pragma unroll
      for (int mt = 0; mt < 4; ++mt)
#pragma unroll
        for (int nt = 0; nt < 4; ++nt) acc[mt][nt] = MFMA(a[mt], b[nt], acc[mt][nt]);
    }
    __syncthreads();
  }
#pragma unroll
  for (int mt = 0; mt < 4; ++mt)
#pragma unroll
    for (int nt = 0; nt < 4; ++nt) {
      int col = wn * 64 + nt * 16 + l15;
      float bias = bvec[n0 + col];
#pragma unroll
      for (int r = 0; r < 4; ++r) {
        int row = m0 + wm * 64 + mt * 16 + quad * 4 + r;
        out[(size_t)row * 5120 + n0 + col] = acc[mt][nt][r] + bias;
      }
    }
}

// ---------------------------------------------------------------------------
extern "C" void kernel_launch(void* const* d_in, const int* in_sizes, int n_in,
                              void* d_out, int out_size, void* d_ws, size_t ws_size,
                              hipStream_t stream) {
  const float* H    = (const float*)d_in[0];
  const float* Wdkv = (const float*)d_in[1];
  const float* bdkv = (const float*)d_in[2];
  const float* Wdq  = (const float*)d_in[3];
  const float* bdq  = (const float*)d_in[4];
  const float* Wuk  = (const float*)d_in[5];
  // d_in[6] = b_uk : softmax-invariant -> unused
  const float* Wuv  = (const float*)d_in[7];
  const float* buv  = (const float*)d_in[8];
  const float* Wuq  = (const float*)d_in[9];
  const float* buq  = (const float*)d_in[10];
  const float* Wqr  = (const float*)d_in[11];
  const float* bqr  = (const float*)d_in[12];
  const float* Wkr  = (const float*)d_in[13];
  const float* bkr  = (const float*)d_in[14];
  const float* Wo   = (const float*)d_in[15];
  const float* bo   = (const float*)d_in[16];
  float* out = (float*)d_out;

  char* ws = (char*)d_ws;
  size_t off = 0;
  auto alloc = [&](size_t bytes) -> void* {
    void* p = ws + off;
    off += (bytes + 255) & ~(size_t)255;
    return p;
  };
  // --- region A (persistent) ~5.5 MB
  ushort_t* ckv    = (ushort_t*)alloc((size_t)4096 * 128 * 2);
  ushort_t* cq     = (ushort_t*)alloc((size_t)4096 * 128 * 2);
  ushort_t* ckvT   = (ushort_t*)alloc((size_t)2 * 128 * 2048 * 2);
  ushort_t* krot   = (ushort_t*)alloc((size_t)16 * 2048 * 16 * 2);
  ushort_t* qrot   = (ushort_t*)alloc((size_t)16 * 2048 * 16 * 2);
  ushort_t* wqkT   = (ushort_t*)alloc((size_t)8 * 128 * 128 * 2);
  float*    bqabs  = (float*)alloc((size_t)8 * 128 * 4);
  float*    bvec   = (float*)alloc((size_t)5120 * 4);
  // --- region B: split-K partials (25.2 MB), lifetime: gemm1_sk -> reduce
  size_t mark = off;
  float*    part   = (float*)alloc((size_t)4 * 4096 * 384 * 4);
  size_t endB = off;
  // --- region C aliases B (stream-ordered: all uses launch after k_reduce)
  off = mark;
  ushort_t* qabs   = (ushort_t*)alloc((size_t)16 * 2048 * 128 * 2);
  ushort_t* wcombT = (ushort_t*)alloc((size_t)5120 * 1024 * 2);
  ushort_t* ctx    = (ushort_t*)alloc((size_t)4096 * 1024 * 2);
  if (off < endB) off = endB;
  (void)ws_size; (void)in_sizes; (void)n_in; (void)out_size;

  hipLaunchKernelGGL(k_bvec_init, dim3(20), dim3(256), 0, stream, bo, bvec);
  hipLaunchKernelGGL(k_bqabs, dim3(8), dim3(128), 0, stream, buq, Wuk, bqabs);
  hipLaunchKernelGGL(k_wqk, dim3(8, 8, 8), dim3(256), 0, stream, Wuq, Wuk, wqkT);
  hipLaunchKernelGGL(k_gemm1_sk, dim3(64, 2, 4), dim3(256), 0, stream,
                     H, Wdkv, Wdq, Wkr, part);
  hipLaunchKernelGGL(k_reduce, dim3(4096), dim3(384), 0, stream,
                     part, bdkv, bdq, bkr, ckv, cq, krot);
  hipLaunchKernelGGL(k_ckvt, dim3(64), dim3(256), 0, stream, ckv, ckvT);
  hipLaunchKernelGGL(k_comb, dim3(40, 8), dim3(256), 0, stream, Wo, Wuv, buv, wcombT, bvec);
  hipLaunchKernelGGL(k_qrot, dim3(128), dim3(256), 0, stream, cq, Wqr, bqr, qrot);
  hipLaunchKernelGGL(k_qabs, dim3(32, 8), dim3(256), 0, stream, cq, wqkT, bqabs, qabs);
  hipLaunchKernelGGL(k_attn, dim3(32, 16), dim3(256), 0, stream,
                     qabs, qrot, ckv, krot, ckvT, ctx);
  hipLaunchKernelGGL(k_final, dim3(32, 40), dim3(256), 0, stream, ctx, wcombT, bvec, out);
}

// Round 5
// 577.631 us; speedup vs baseline: 1.1999x; 1.1298x over previous
//
#include <hip/hip_runtime.h>

// ---------------------------------------------------------------------------
// MemoryOptimizedMLA on gfx950 — absorbed-MLA formulation.
//
//   c_kv = h@W_dkv+b ; c_q = h@W_dq+b ; k_rot = rope(h@W_kr+b)
//   W_qk[h] = W_uq_h @ W_uk_h^T (128x128), b_qabs[h] = b_uq_h @ W_uk_h^T
//   q_abs = (c_q@W_qk + b_qabs)/sqrt(640) ; q_rot = rope(c_q@W_qr + b_qr)/sqrt(640)
//   scores = q_abs . c_kv + q_rot . k_rot          (b_uk is softmax-inv.)
//   ctx = softmax(scores) @ c_kv      (128 dims, flash/online-softmax)
//   out = ctx @ W_combT^T + (b_uv@W_o + b_o),  W_comb[h] = W_uv_h @ W_o_h
//
// R2: gemm1 split-K + k_reduce epilogue; ws aliasing.
// R3: bvec fused into k_comb; softmax diet; first LDS swizzles.
// R4: k_ckvt (Vt staged vectorized); reg-prefetch pipelines; cvt_pk Ps.
// R5: k_attn swapped-QK lane-local softmax; packed-b32 staging swizzles.
// R7: k_wqk was a hidden 128 µs spill-bomb (VGPR=256, 272 MB scratch writes,
//     VALUBusy 2.8%) — rebuilt as the proven k_qabs MFMA skeleton: one
//     128x128 tile per head, K=624 zero-padded to 640, cvt_pk bf16 staging,
//     fp32 MFMA accum. k_bqabs folded into its staging loop (fp32 math from
//     pre-conversion values — unchanged numerics), launch removed.
// ---------------------------------------------------------------------------

typedef unsigned short ushort_t;
typedef __attribute__((ext_vector_type(8)))  short          short8;
typedef __attribute__((ext_vector_type(8)))  unsigned short us8;
typedef __attribute__((ext_vector_type(4)))  float          f32x4;
typedef __attribute__((ext_vector_type(4)))  unsigned int   u32x4;

#define SCALE_ATT 0.0395284707521047f  /* 1/sqrt(640) */

static __device__ inline unsigned short f2bf(float f) {
  union { float f; unsigned u; } v; v.f = f;
  unsigned r = (v.u + 0x7fffu + ((v.u >> 16) & 1u)) >> 16;
  return (unsigned short)r;
}
static __device__ inline float bf2f(unsigned short u) {
  union { unsigned u; float f; } v; v.u = ((unsigned)u) << 16;
  return v.f;
}
static __device__ inline unsigned cvt_pk_bf16(float a, float b) {
  unsigned r;
  asm("v_cvt_pk_bf16_f32 %0, %1, %2" : "=v"(r) : "v"(a), "v"(b));
  return r;  // low16 = bf16(a), high16 = bf16(b), RNE
}
static __device__ inline f32x4 MFMA(short8 a, short8 b, f32x4 c) {
  return __builtin_amdgcn_mfma_f32_16x16x32_bf16(a, b, c, 0, 0, 0);
}

// ---------------------------------------------------------------------------
// bvec init: bvec[n] = bo[n].  grid 20, block 256. (accumulated in k_comb)
__global__ __launch_bounds__(256) void k_bvec_init(const float* __restrict__ bo,
                                                   float* __restrict__ bvec) {
  int n = blockIdx.x * 256 + threadIdx.x;
  bvec[n] = bo[n];
}

// ---------------------------------------------------------------------------
// wqkT[h][j][i] = sum_d Wuq[i][h*624+d]*Wuk[j][h*624+d]  (bf16 MFMA, R7)
// + folded bqabs[h][j] = sum_d buq[h*624+d]*Wuk[j][h*624+d] (fp32, from
//   pre-conversion staged values).
// grid 8 (one block per head), block 256 (4 waves). BM=BN=128, BK=64,
// K=624 zero-padded to 640. As <- Wuk rows (j, output row); Bs <- Wuq rows
// (i, output col) so the b16 stores are 16-contiguous in i.
__global__ __launch_bounds__(256) void k_wqk(const float* __restrict__ Wuq,
                                             const float* __restrict__ Wuk,
                                             const float* __restrict__ buq,
                                             ushort_t* __restrict__ wqkT,
                                             float* __restrict__ bqabs) {
  __shared__ __align__(16) ushort_t As[128 * 72];
  __shared__ __align__(16) ushort_t Bs[128 * 72];
  const int tid = threadIdx.x;
  const int hh = blockIdx.x;
  const int lane = tid & 63, wid = tid >> 6;
  const int quad = lane >> 4, l15 = lane & 15;
  const int wm = wid & 1, wn = wid >> 1;
  f32x4 acc[4][4];
#pragma unroll
  for (int a = 0; a < 4; ++a)
#pragma unroll
    for (int b = 0; b < 4; ++b) acc[a][b] = (f32x4){0.f, 0.f, 0.f, 0.f};
  const int r = tid >> 1, c0 = (tid & 1) * 32;  // row 0..127, 32-float half
  float bacc = 0.f;
  for (int kb = 0; kb < 640; kb += 64) {
    const int dbase = kb + c0;
    const float* ak = Wuk + (size_t)r * 4992 + hh * 624 + dbase;
    const float* aq = Wuq + (size_t)r * 4992 + hh * 624 + dbase;
    const float* bu = buq + hh * 624 + dbase;
    float vk[32], vq[32];
    if (dbase + 32 <= 624) {       // full half (all but kb=576,c0=32)
#pragma unroll
      for (int w = 0; w < 8; ++w) {
        const f32x4 t1 = *(const f32x4*)(ak + w * 4);
        const f32x4 t2 = *(const f32x4*)(aq + w * 4);
        const f32x4 t3 = *(const f32x4*)(bu + w * 4);
#pragma unroll
        for (int e = 0; e < 4; ++e) { vk[w * 4 + e] = t1[e]; vq[w * 4 + e] = t2[e]; }
        bacc += t3[0] * t1[0] + t3[1] * t1[1] + t3[2] * t1[2] + t3[3] * t1[3];
      }
    } else {                        // guarded tail (d 608..639, 16 valid)
#pragma unroll
      for (int i2 = 0; i2 < 32; ++i2) {
        const bool ok = (dbase + i2) < 624;
        const float wkv = ok ? ak[i2] : 0.f;
        vk[i2] = wkv;
        vq[i2] = ok ? aq[i2] : 0.f;
        bacc += (ok ? bu[i2] : 0.f) * wkv;
      }
    }
    u32x4 pk0 = { cvt_pk_bf16(vk[0], vk[1]),  cvt_pk_bf16(vk[2], vk[3]),
                  cvt_pk_bf16(vk[4], vk[5]),  cvt_pk_bf16(vk[6], vk[7]) };
    u32x4 pk1 = { cvt_pk_bf16(vk[8], vk[9]),  cvt_pk_bf16(vk[10], vk[11]),
                  cvt_pk_bf16(vk[12], vk[13]), cvt_pk_bf16(vk[14], vk[15]) };
    u32x4 pk2 = { cvt_pk_bf16(vk[16], vk[17]), cvt_pk_bf16(vk[18], vk[19]),
                  cvt_pk_bf16(vk[20], vk[21]), cvt_pk_bf16(vk[22], vk[23]) };
    u32x4 pk3 = { cvt_pk_bf16(vk[24], vk[25]), cvt_pk_bf16(vk[26], vk[27]),
                  cvt_pk_bf16(vk[28], vk[29]), cvt_pk_bf16(vk[30], vk[31]) };
    *(u32x4*)&As[r * 72 + c0]      = pk0;
    *(u32x4*)&As[r * 72 + c0 + 8]  = pk1;
    *(u32x4*)&As[r * 72 + c0 + 16] = pk2;
    *(u32x4*)&As[r * 72 + c0 + 24] = pk3;
    u32x4 pq0 = { cvt_pk_bf16(vq[0], vq[1]),  cvt_pk_bf16(vq[2], vq[3]),
                  cvt_pk_bf16(vq[4], vq[5]),  cvt_pk_bf16(vq[6], vq[7]) };
    u32x4 pq1 = { cvt_pk_bf16(vq[8], vq[9]),  cvt_pk_bf16(vq[10], vq[11]),
                  cvt_pk_bf16(vq[12], vq[13]), cvt_pk_bf16(vq[14], vq[15]) };
    u32x4 pq2 = { cvt_pk_bf16(vq[16], vq[17]), cvt_pk_bf16(vq[18], vq[19]),
                  cvt_pk_bf16(vq[20], vq[21]), cvt_pk_bf16(vq[22], vq[23]) };
    u32x4 pq3 = { cvt_pk_bf16(vq[24], vq[25]), cvt_pk_bf16(vq[26], vq[27]),
                  cvt_pk_bf16(vq[28], vq[29]), cvt_pk_bf16(vq[30], vq[31]) };
    *(u32x4*)&Bs[r * 72 + c0]      = pq0;
    *(u32x4*)&Bs[r * 72 + c0 + 8]  = pq1;
    *(u32x4*)&Bs[r * 72 + c0 + 16] = pq2;
    *(u32x4*)&Bs[r * 72 + c0 + 24] = pq3;
    __syncthreads();
#pragma unroll
    for (int ks = 0; ks < 2; ++ks) {
      short8 a[4], b[4];
#pragma unroll
      for (int mt = 0; mt < 4; ++mt)
        a[mt] = *(const short8*)&As[(wm * 64 + mt * 16 + l15) * 72 + ks * 32 + quad * 8];
#pragma unroll
      for (int nt = 0; nt < 4; ++nt)
        b[nt] = *(const short8*)&Bs[(wn * 64 + nt * 16 + l15) * 72 + ks * 32 + quad * 8];
#pragma unroll
      for (int mt = 0; mt < 4; ++mt)
#pragma unroll
        for (int nt = 0; nt < 4; ++nt) acc[mt][nt] = MFMA(a[mt], b[nt], acc[mt][nt]);
    }
    __syncthreads();
  }
#pragma unroll
  for (int mt = 0; mt < 4; ++mt)
#pragma unroll
    for (int nt = 0; nt < 4; ++nt) {
      const int i = wn * 64 + nt * 16 + l15;           // Wuq index (col)
#pragma unroll
      for (int rr = 0; rr < 4; ++rr) {
        const int j = wm * 64 + mt * 16 + quad * 4 + rr;  // Wuk index (row)
        wqkT[(size_t)hh * 16384 + (size_t)j * 128 + i] = f2bf(acc[mt][nt][rr]);
      }
    }
  const float po = __shfl_xor(bacc, 1);
  if ((tid & 1) == 0) bqabs[hh * 128 + r] = bacc + po;
}

// ---------------------------------------------------------------------------
// GEMM1 split-K: partials of h @ [W_dkv|W_dq|W_kr].
// grid (64 mtiles, 2 nhalves, 4 ksplits), block 256 (4 waves, each 64x48).
// R5: B staged as k-pair-packed b32 scatters (cvt_pk), physical k index
//     k' = k ^ (((n>>3)&7)<<3); A staged via cvt_pk u32x4.
__global__ __launch_bounds__(256) void k_gemm1_sk(
    const float* __restrict__ H, const float* __restrict__ Wdkv,
    const float* __restrict__ Wdq, const float* __restrict__ Wkr,
    float* __restrict__ part) {
  __shared__ __align__(16) ushort_t As[64 * 72];
  __shared__ __align__(16) ushort_t Bs[192 * 72];
  const int tid = threadIdx.x;
  const int m0 = blockIdx.x * 64;
  const int n0 = blockIdx.y * 192;
  const int kc0 = blockIdx.z * 1280;
  const int lane = tid & 63, wid = tid >> 6;
  const int quad = lane >> 4, l15 = lane & 15;
  f32x4 acc[4][3];
#pragma unroll
  for (int a = 0; a < 4; ++a)
#pragma unroll
    for (int b = 0; b < 3; ++b) acc[a][b] = (f32x4){0.f, 0.f, 0.f, 0.f};
  const int ar = tid >> 2, ak0 = (tid & 3) * 16;
  const int bkp = tid >> 3;   // 0..31: k-pair (k = 2*bkp, 2*bkp+1)
  const int bng = tid & 7;    // n-subgroup of 8 within each 64-col group
  const float* harow = H + (size_t)(m0 + ar) * 5120 + ak0;
  for (int kb = kc0; kb < kc0 + 1280; kb += 64) {
    const float* ap = harow + kb;
    f32x4 af0 = *(const f32x4*)ap, af1 = *(const f32x4*)(ap + 4);
    f32x4 af2 = *(const f32x4*)(ap + 8), af3 = *(const f32x4*)(ap + 12);
    u32x4 apk0 = { cvt_pk_bf16(af0[0], af0[1]), cvt_pk_bf16(af0[2], af0[3]),
                   cvt_pk_bf16(af1[0], af1[1]), cvt_pk_bf16(af1[2], af1[3]) };
    u32x4 apk1 = { cvt_pk_bf16(af2[0], af2[1]), cvt_pk_bf16(af2[2], af2[3]),
                   cvt_pk_bf16(af3[0], af3[1]), cvt_pk_bf16(af3[2], af3[3]) };
    *(u32x4*)&As[ar * 72 + ak0] = apk0;
    *(u32x4*)&As[ar * 72 + ak0 + 8] = apk1;
    const int krow = kb + 2 * bkp;
    const int kd = (2 * bkp) ^ (bng << 3);   // swizzled physical k slot
#pragma unroll
    for (int g = 0; g < 3; ++g) {
      const int lcol = g * 64 + bng * 8;
      const int col = n0 + lcol;
      const float* base = (col < 128 ? Wdkv + col
                         : col < 256 ? Wdq + (col - 128)
                                     : Wkr + (col - 256)) + (size_t)krow * 128;
      f32x4 r0a = *(const f32x4*)base, r0b = *(const f32x4*)(base + 4);
      f32x4 r1a = *(const f32x4*)(base + 128), r1b = *(const f32x4*)(base + 132);
#pragma unroll
      for (int i = 0; i < 4; ++i) {
        *(unsigned*)&Bs[(lcol + i) * 72 + kd]     = cvt_pk_bf16(r0a[i], r1a[i]);
        *(unsigned*)&Bs[(lcol + 4 + i) * 72 + kd] = cvt_pk_bf16(r0b[i], r1b[i]);
      }
    }
    __syncthreads();
#pragma unroll
    for (int ks = 0; ks < 2; ++ks) {
      short8 a[4], b[3];
#pragma unroll
      for (int mt = 0; mt < 4; ++mt)
        a[mt] = *(const short8*)&As[(mt * 16 + l15) * 72 + ks * 32 + quad * 8];
#pragma unroll
      for (int nt = 0; nt < 3; ++nt) {
        const int row = wid * 48 + nt * 16 + l15;
        const int kofs = (ks * 32 + quad * 8) ^ (((row >> 3) & 7) << 3);
        b[nt] = *(const short8*)&Bs[row * 72 + kofs];
      }
#pragma unroll
      for (int mt = 0; mt < 4; ++mt)
#pragma unroll
        for (int nt = 0; nt < 3; ++nt) acc[mt][nt] = MFMA(a[mt], b[nt], acc[mt][nt]);
    }
    __syncthreads();
  }
  const size_t pb = (size_t)blockIdx.z * 4096 * 384;
#pragma unroll
  for (int mt = 0; mt < 4; ++mt)
#pragma unroll
    for (int nt = 0; nt < 3; ++nt) {
      const int col = n0 + wid * 48 + nt * 16 + l15;
#pragma unroll
      for (int r = 0; r < 4; ++r) {
        const int row = m0 + mt * 16 + quad * 4 + r;
        part[pb + (size_t)row * 384 + col] = acc[mt][nt][r];
      }
    }
}

// ---------------------------------------------------------------------------
// reduce 4 partials + bias; rope for the k_rot slice. grid 4096, block 384.
__global__ __launch_bounds__(384) void k_reduce(
    const float* __restrict__ part, const float* __restrict__ bdkv,
    const float* __restrict__ bdq, const float* __restrict__ bkr,
    ushort_t* __restrict__ ckv, ushort_t* __restrict__ cq,
    ushort_t* __restrict__ krot) {
  const int row = blockIdx.x;
  const int c = threadIdx.x;
  float v = 0.f;
#pragma unroll
  for (int ks = 0; ks < 4; ++ks)
    v += part[((size_t)ks * 4096 + row) * 384 + c];
  if (c < 128) {
    v += bdkv[c];
    ckv[(size_t)row * 128 + c] = f2bf(v);
  } else if (c < 256) {
    v += bdq[c - 128];
    cq[(size_t)row * 128 + (c - 128)] = f2bf(v);
  } else {
    v += bkr[c - 256];
    float partner = __shfl_xor(v, 4);
    const int j = (c - 256) & 15;
    const int head = (c - 256) >> 4;
    const int s = row & 2047, bb = row >> 11;
    const int j4 = j & 3;
    const float fr = (j4 == 0) ? 1.f : (j4 == 1) ? 0.1f : (j4 == 2) ? 0.01f : 0.001f;
    float sth, cth;
    __sincosf(s * 0.025f * fr, &sth, &cth);
    const float y = (j < 4) ? (v * cth - partner * sth)
                  : (j < 8) ? (v * cth + partner * sth) : v;
    krot[((size_t)((bb << 3) + head) * 2048 + s) * 16 + j] = f2bf(y);
  }
}

// ---------------------------------------------------------------------------
// ckvT[b][d][s] = ckv[b*2048+s][d].  64 blocks x 256 thr, 64 s x 128 d tiles.
__global__ __launch_bounds__(256) void k_ckvt(const ushort_t* __restrict__ ckv,
                                              ushort_t* __restrict__ ckvT) {
  __shared__ __align__(16) ushort_t T[128 * 72];
  const int tid = threadIdx.x;
  const int s0 = blockIdx.x * 64;
  const int bb = s0 >> 11, sl = s0 & 2047;
  const int sr = tid >> 2, sseg = tid & 3;
  {
    const ushort_t* kp = ckv + ((size_t)s0 + sr) * 128 + sseg * 32;
    us8 v[4];
#pragma unroll
    for (int w = 0; w < 4; ++w) v[w] = *(const us8*)(kp + w * 8);
#pragma unroll
    for (int w = 0; w < 4; ++w)
#pragma unroll
      for (int i = 0; i < 8; ++i)
        T[(sseg * 32 + w * 8 + i) * 72 + sr] = v[w][i];
  }
  __syncthreads();
  const int vrow = tid >> 1, vk0 = (tid & 1) * 32;
#pragma unroll
  for (int w = 0; w < 4; ++w) {
    us8 t = *(const us8*)&T[vrow * 72 + vk0 + w * 8];
    *(us8*)(ckvT + ((size_t)bb * 128 + vrow) * 2048 + sl + vk0 + w * 8) = t;
  }
}

// ---------------------------------------------------------------------------
// q_rot = rope(c_q @ W_qr + b_qr) * SCALE_ATT.  grid 128, block 256.
__global__ __launch_bounds__(256) void k_qrot(const ushort_t* __restrict__ cq,
                                              const float* __restrict__ Wqr,
                                              const float* __restrict__ bqr,
                                              ushort_t* __restrict__ qrot) {
  int gidx = blockIdx.x * 256 + threadIdx.x;  // 0..32767
  int s = gidx & 2047, bh = gidx >> 11;
  int hh = bh & 7, bb = bh >> 3;
  const ushort_t* crow = cq + ((size_t)bb * 2048 + s) * 128;
  float acc[16];
#pragma unroll
  for (int j = 0; j < 16; ++j) acc[j] = bqr[hh * 16 + j];
  for (int k0 = 0; k0 < 128; k0 += 8) {
    us8 cv8 = *(const us8*)(crow + k0);
#pragma unroll
    for (int i = 0; i < 8; ++i) {
      float cv = bf2f(cv8[i]);
      const float* wr = Wqr + (size_t)(k0 + i) * 128 + hh * 16;
#pragma unroll
      for (int j = 0; j < 16; ++j) acc[j] += cv * wr[j];
    }
  }
  float y[16];
#pragma unroll
  for (int j4 = 0; j4 < 4; ++j4) {
    float fr = (j4 == 0) ? 1.f : (j4 == 1) ? 0.1f : (j4 == 2) ? 0.01f : 0.001f;
    float sth, cth;
    __sincosf(s * 0.025f * fr, &sth, &cth);
    y[j4] = acc[j4] * cth - acc[j4 + 4] * sth;
    y[j4 + 4] = acc[j4 + 4] * cth + acc[j4] * sth;
  }
#pragma unroll
  for (int j = 8; j < 16; ++j) y[j] = acc[j];
  us8 o0, o1;
#pragma unroll
  for (int j = 0; j < 8; ++j) {
    o0[j] = f2bf(y[j] * SCALE_ATT);
    o1[j] = f2bf(y[8 + j] * SCALE_ATT);
  }
  *(us8*)(qrot + (size_t)gidx * 16) = o0;
  *(us8*)(qrot + (size_t)gidx * 16 + 8) = o1;
}

// ---------------------------------------------------------------------------
// q_abs = (c_q @ W_qk[h] + b_qabs[h]) * SCALE_ATT.  BM=128,BN=128,BK=64. grid (32, 8).
__global__ __launch_bounds__(256) void k_qabs(const ushort_t* __restrict__ cq,
                                              const ushort_t* __restrict__ wqkT,
                                              const float* __restrict__ bqabs,
                                              ushort_t* __restrict__ qabs) {
  __shared__ __align__(16) ushort_t As[128 * 72];
  __shared__ __align__(16) ushort_t Bs[128 * 72];
  const int tid = threadIdx.x;
  const int m0 = blockIdx.x * 128, hh = blockIdx.y;
  const int lane = tid & 63, wid = tid >> 6;
  const int quad = lane >> 4, l15 = lane & 15;
  const int wm = wid & 1, wn = wid >> 1;
  f32x4 acc[4][4];
#pragma unroll
  for (int a = 0; a < 4; ++a)
#pragma unroll
    for (int b = 0; b < 4; ++b) acc[a][b] = (f32x4){0.f, 0.f, 0.f, 0.f};
  const int ar = tid >> 1, as0 = (tid & 1) * 32;
  for (int kb = 0; kb < 128; kb += 64) {
    const ushort_t* ap = cq + (size_t)(m0 + ar) * 128 + kb + as0;
    const ushort_t* bp = wqkT + (size_t)hh * 16384 + (size_t)ar * 128 + kb + as0;
#pragma unroll
    for (int w = 0; w < 4; ++w) {
      *(us8*)&As[ar * 72 + as0 + w * 8] = *(const us8*)(ap + w * 8);
      *(us8*)&Bs[ar * 72 + as0 + w * 8] = *(const us8*)(bp + w * 8);
    }
    __syncthreads();
#pragma unroll
    for (int ks = 0; ks < 2; ++ks) {
      short8 a[4], b[4];
#pragma unroll
      for (int mt = 0; mt < 4; ++mt)
        a[mt] = *(const short8*)&As[(wm * 64 + mt * 16 + l15) * 72 + ks * 32 + quad * 8];
#pragma unroll
      for (int nt = 0; nt < 4; ++nt)
        b[nt] = *(const short8*)&Bs[(wn * 64 + nt * 16 + l15) * 72 + ks * 32 + quad * 8];
#pragma unroll
      for (int mt = 0; mt < 4; ++mt)
#pragma unroll
        for (int nt = 0; nt < 4; ++nt) acc[mt][nt] = MFMA(a[mt], b[nt], acc[mt][nt]);
    }
    __syncthreads();
  }
#pragma unroll
  for (int mt = 0; mt < 4; ++mt)
#pragma unroll
    for (int nt = 0; nt < 4; ++nt) {
      int col = wn * 64 + nt * 16 + l15;
      float bias = bqabs[hh * 128 + col];
#pragma unroll
      for (int r = 0; r < 4; ++r) {
        int m = m0 + wm * 64 + mt * 16 + quad * 4 + r;
        int bb = m >> 11, s = m & 2047;
        qabs[((size_t)((bb << 3) + hh) * 2048 + s) * 128 + col] =
            f2bf((acc[mt][nt][r] + bias) * SCALE_ATT);
      }
    }
}

// ---------------------------------------------------------------------------
// wcombT[n][h*128+c] = sum_d W_o[h*640+d][n] * W_uv[c][h*640+d]
// + fused bvec accumulation: bvec[n] += sum_d buv[h*640+d]*W_o[h*640+d][n]
// R5: As staged as k-pair-packed b32 scatters (cvt_pk), physical
//     k' = k ^ (((n>>3)&7)<<3); Bs conversions via cvt_pk.
__global__ __launch_bounds__(256) void k_comb(const float* __restrict__ Wo,
                                              const float* __restrict__ Wuv,
                                              const float* __restrict__ buv,
                                              ushort_t* __restrict__ wcombT,
                                              float* __restrict__ bvec) {
  __shared__ __align__(16) ushort_t As[128 * 72];
  __shared__ __align__(16) ushort_t Bs[128 * 72];
  const int tid = threadIdx.x;
  const int n0 = blockIdx.x * 128, hh = blockIdx.y;
  const int lane = tid & 63, wid = tid >> 6;
  const int quad = lane >> 4, l15 = lane & 15;
  const int wm = wid & 1, wn = wid >> 1;
  f32x4 acc[4][4];
#pragma unroll
  for (int a = 0; a < 4; ++a)
#pragma unroll
    for (int b = 0; b < 4; ++b) acc[a][b] = (f32x4){0.f, 0.f, 0.f, 0.f};
  const int akp = tid >> 3;   // 0..31: k-pair
  const int ang = tid & 7;    // n-group of 16
  const int kd0 = (2 * akp) ^ (((2 * ang) & 7) << 3);
  const int kd1 = (2 * akp) ^ (((2 * ang + 1) & 7) << 3);
  const int bc = tid >> 1, bd0 = (tid & 1) * 32;
  const int bvc = tid >> 1, bvh = tid & 1;
  const int bswz = ((bvc >> 3) & 7) << 3;     // bacc read-side swizzle
  const float* buvh = buv + hh * 640;
  float bacc = 0.f;
  for (int kb = 0; kb < 640; kb += 64) {
    {
      const float* ap0 = Wo + (size_t)(hh * 640 + kb + 2 * akp) * 5120 + n0 + ang * 16;
      const float* ap1 = ap0 + 5120;
      f32x4 r0[4], r1[4];
#pragma unroll
      for (int w = 0; w < 4; ++w) {
        r0[w] = *(const f32x4*)(ap0 + w * 4);
        r1[w] = *(const f32x4*)(ap1 + w * 4);
      }
#pragma unroll
      for (int w = 0; w < 2; ++w)
#pragma unroll
        for (int i = 0; i < 4; ++i)
          *(unsigned*)&As[(ang * 16 + w * 4 + i) * 72 + kd0] =
              cvt_pk_bf16(r0[w][i], r1[w][i]);
#pragma unroll
      for (int w = 2; w < 4; ++w)
#pragma unroll
        for (int i = 0; i < 4; ++i)
          *(unsigned*)&As[(ang * 16 + w * 4 + i) * 72 + kd1] =
              cvt_pk_bf16(r0[w][i], r1[w][i]);
    }
    const float* bp = Wuv + (size_t)bc * 5120 + hh * 640 + kb + bd0;
    f32x4 b0 = *(const f32x4*)bp, b1 = *(const f32x4*)(bp + 4);
    f32x4 b2 = *(const f32x4*)(bp + 8), b3 = *(const f32x4*)(bp + 12);
    f32x4 b4 = *(const f32x4*)(bp + 16), b5 = *(const f32x4*)(bp + 20);
    f32x4 b6 = *(const f32x4*)(bp + 24), b7 = *(const f32x4*)(bp + 28);
    u32x4 q0 = { cvt_pk_bf16(b0[0], b0[1]), cvt_pk_bf16(b0[2], b0[3]),
                 cvt_pk_bf16(b1[0], b1[1]), cvt_pk_bf16(b1[2], b1[3]) };
    u32x4 q1 = { cvt_pk_bf16(b2[0], b2[1]), cvt_pk_bf16(b2[2], b2[3]),
                 cvt_pk_bf16(b3[0], b3[1]), cvt_pk_bf16(b3[2], b3[3]) };
    u32x4 q2 = { cvt_pk_bf16(b4[0], b4[1]), cvt_pk_bf16(b4[2], b4[3]),
                 cvt_pk_bf16(b5[0], b5[1]), cvt_pk_bf16(b5[2], b5[3]) };
    u32x4 q3 = { cvt_pk_bf16(b6[0], b6[1]), cvt_pk_bf16(b6[2], b6[3]),
                 cvt_pk_bf16(b7[0], b7[1]), cvt_pk_bf16(b7[2], b7[3]) };
    *(u32x4*)&Bs[bc * 72 + bd0]      = q0;
    *(u32x4*)&Bs[bc * 72 + bd0 + 8]  = q1;
    *(u32x4*)&Bs[bc * 72 + bd0 + 16] = q2;
    *(u32x4*)&Bs[bc * 72 + bd0 + 24] = q3;
    __syncthreads();
    // bvec partial from the staged W_o tile (swizzle-compensated read)
#pragma unroll
    for (int d8 = 0; d8 < 4; ++d8) {
      const int k0 = bvh * 32 + d8 * 8;       // logical k base (8-aligned)
      const us8 a8 = *(const us8*)&As[bvc * 72 + (k0 ^ bswz)];
      const f32x4 b4a = *(const f32x4*)&buvh[kb + k0];
      const f32x4 b4b = *(const f32x4*)&buvh[kb + k0 + 4];
      bacc += b4a[0] * bf2f(a8[0]) + b4a[1] * bf2f(a8[1]) +
              b4a[2] * bf2f(a8[2]) + b4a[3] * bf2f(a8[3]) +
              b4b[0] * bf2f(a8[4]) + b4b[1] * bf2f(a8[5]) +
              b4b[2] * bf2f(a8[6]) + b4b[3] * bf2f(a8[7]);
    }
#pragma unroll
    for (int ks = 0; ks < 2; ++ks) {
      short8 a[4], b[4];
#pragma unroll
      for (int mt = 0; mt < 4; ++mt) {
        const int row = wm * 64 + mt * 16 + l15;
        const int kofs = (ks * 32 + quad * 8) ^ (((row >> 3) & 7) << 3);
        a[mt] = *(const short8*)&As[row * 72 + kofs];
      }
#pragma unroll
      for (int nt = 0; nt < 4; ++nt)
        b[nt] = *(const short8*)&Bs[(wn * 64 + nt * 16 + l15) * 72 + ks * 32 + quad * 8];
#pragma unroll
      for (int mt = 0; mt < 4; ++mt)
#pragma unroll
        for (int nt = 0; nt < 4; ++nt) acc[mt][nt] = MFMA(a[mt], b[nt], acc[mt][nt]);
    }
    __syncthreads();
  }
#pragma unroll
  for (int mt = 0; mt < 4; ++mt)
#pragma unroll
    for (int nt = 0; nt < 4; ++nt) {
      int col = wn * 64 + nt * 16 + l15;
#pragma unroll
      for (int r = 0; r < 4; ++r) {
        int n = n0 + wm * 64 + mt * 16 + quad * 4 + r;
        wcombT[(size_t)n * 1024 + hh * 128 + col] = f2bf(acc[mt][nt][r]);
      }
    }
  atomicAdd(&bvec[n0 + bvc], bacc);
}

// ---------------------------------------------------------------------------
// Flash attention over absorbed dims. grid (32 q-tiles, 16 bh), block 256.
// R5: swapped-QK softmax — MFMA(K,Q) puts the 16 scores of query l15 into
//     this lane's regs: 15 in-lane fmax + 2 shuffles; ballot-gated PV
//     rescale; Ps = 8 packed b32 writes; 2 barriers/kt.
__global__ __launch_bounds__(256) void k_attn(const ushort_t* __restrict__ qabs,
                                              const ushort_t* __restrict__ qrot,
                                              const ushort_t* __restrict__ ckv,
                                              const ushort_t* __restrict__ krot,
                                              const ushort_t* __restrict__ ckvT,
                                              ushort_t* __restrict__ ctx) {
  __shared__ __align__(16) ushort_t Qs[64 * 168];
  __shared__ __align__(16) ushort_t Ks[64 * 168];
  __shared__ __align__(16) ushort_t Vt[128 * 72];
  __shared__ __align__(16) ushort_t Ps[64 * 72];
  const int tid = threadIdx.x;
  const int bh = blockIdx.y, bb = bh >> 3, hh = bh & 7;
  const int q0 = blockIdx.x * 64;
  const int lane = tid & 63, wid = tid >> 6;
  const int quad = lane >> 4, l15 = lane & 15;
  const int sr = tid >> 2, sseg = tid & 3;
  const int vrow = tid >> 1, vk0 = (tid & 1) * 32;
  (void)hh;
  {  // Q staging (once) + static zero tails for Qs AND Ks (cols 144..159)
    const ushort_t* qa = qabs + ((size_t)bh * 2048 + q0 + sr) * 128 + sseg * 32;
#pragma unroll
    for (int w = 0; w < 4; ++w)
      *(us8*)&Qs[sr * 168 + sseg * 32 + w * 8] = *(const us8*)(qa + w * 8);
    if (sseg == 0) {
      const ushort_t* qr = qrot + ((size_t)bh * 2048 + q0 + sr) * 16;
      *(us8*)&Qs[sr * 168 + 128] = *(const us8*)qr;
      *(us8*)&Qs[sr * 168 + 136] = *(const us8*)(qr + 8);
    }
    if (sseg == 1) {
      us8 z = (us8)0;
      *(us8*)&Qs[sr * 168 + 144] = z;
      *(us8*)&Qs[sr * 168 + 152] = z;
      *(us8*)&Ks[sr * 168 + 144] = z;
      *(us8*)&Ks[sr * 168 + 152] = z;
    }
  }
  us8 kreg[4], vreg[4], krr0, krr1;
  auto loadKV = [&](int key0) {
    const ushort_t* kp = ckv + ((size_t)bb * 2048 + key0 + sr) * 128 + sseg * 32;
#pragma unroll
    for (int w = 0; w < 4; ++w) kreg[w] = *(const us8*)(kp + w * 8);
    const ushort_t* vp = ckvT + ((size_t)bb * 128 + vrow) * 2048 + key0 + vk0;
#pragma unroll
    for (int w = 0; w < 4; ++w) vreg[w] = *(const us8*)(vp + w * 8);
    if (sseg == 0) {
      const ushort_t* kr = krot + ((size_t)bh * 2048 + key0 + sr) * 16;
      krr0 = *(const us8*)kr;
      krr1 = *(const us8*)(kr + 8);
    }
  };
  loadKV(0);
  f32x4 oacc[8];
#pragma unroll
  for (int i = 0; i < 8; ++i) oacc[i] = (f32x4){0.f, 0.f, 0.f, 0.f};
  float mrow[4] = {-1e30f, -1e30f, -1e30f, -1e30f};  // PV-side (q = quad*4+r)
  float m_sm = -1e30f;                               // SM-side (q = l15)
  float lrow_l = 0.f;                                // per-lane partial sum

  for (int kt = 0; kt < 32; ++kt) {
    // write prefetched regs -> LDS
#pragma unroll
    for (int w = 0; w < 4; ++w)
      *(us8*)&Ks[sr * 168 + sseg * 32 + w * 8] = kreg[w];
    if (sseg == 0) {
      *(us8*)&Ks[sr * 168 + 128] = krr0;
      *(us8*)&Ks[sr * 168 + 136] = krr1;
    }
#pragma unroll
    for (int w = 0; w < 4; ++w)
      *(us8*)&Vt[vrow * 72 + vk0 + w * 8] = vreg[w];
    __syncthreads();
    f32x4 sacc[4];   // sacc[nt][r]: key = nt*16 + quad*4 + r, query = l15
#pragma unroll
    for (int nt = 0; nt < 4; ++nt) sacc[nt] = (f32x4){0.f, 0.f, 0.f, 0.f};
#pragma unroll
    for (int ks = 0; ks < 5; ++ks) {
      short8 aq = *(const short8*)&Qs[(wid * 16 + l15) * 168 + ks * 32 + quad * 8];
#pragma unroll
      for (int nt = 0; nt < 4; ++nt) {
        short8 bk = *(const short8*)&Ks[(nt * 16 + l15) * 168 + ks * 32 + quad * 8];
        sacc[nt] = MFMA(bk, aq, sacc[nt]);   // swapped: D[key][query]
      }
    }
    if (kt < 31) loadKV((kt + 1) * 64);   // VMEM in flight during softmax+PV
    // ---- swapped softmax: lane owns query l15, 16 keys in regs
    float mx = sacc[0][0];
#pragma unroll
    for (int nt = 0; nt < 4; ++nt)
#pragma unroll
      for (int r = 0; r < 4; ++r) mx = fmaxf(mx, sacc[nt][r]);
    mx = fmaxf(mx, __shfl_xor(mx, 16));
    mx = fmaxf(mx, __shfl_xor(mx, 32));
    const bool grew = mx > m_sm;
    if (__any(grew)) {
      if (grew) { lrow_l *= __expf(m_sm - mx); m_sm = mx; }
#pragma unroll
      for (int r = 0; r < 4; ++r) {
        float mnew = __shfl(m_sm, quad * 4 + r);
        if (mnew > mrow[r]) {
          float alpha = __expf(mrow[r] - mnew);
          mrow[r] = mnew;
#pragma unroll
          for (int t8 = 0; t8 < 8; ++t8) oacc[t8][r] *= alpha;
        }
      }
    }
    float rs = 0.f;
    const int prow = (wid * 16 + l15) * 72 + quad * 4;
#pragma unroll
    for (int nt = 0; nt < 4; ++nt) {
      float p0 = __expf(sacc[nt][0] - m_sm);
      float p1 = __expf(sacc[nt][1] - m_sm);
      float p2 = __expf(sacc[nt][2] - m_sm);
      float p3 = __expf(sacc[nt][3] - m_sm);
      rs += (p0 + p1) + (p2 + p3);
      *(unsigned*)&Ps[prow + nt * 16]     = cvt_pk_bf16(p0, p1);
      *(unsigned*)&Ps[prow + nt * 16 + 2] = cvt_pk_bf16(p2, p3);
    }
    lrow_l += rs;
    // Ps rows are wave-private: no barrier needed before PV (intra-wave
    // LDS RAW ordered by compiler-inserted lgkmcnt).
#pragma unroll
    for (int kk = 0; kk < 2; ++kk) {
      short8 pa = *(const short8*)&Ps[(wid * 16 + l15) * 72 + kk * 32 + quad * 8];
#pragma unroll
      for (int nt = 0; nt < 8; ++nt) {
        short8 vb = *(const short8*)&Vt[(nt * 16 + l15) * 72 + kk * 32 + quad * 8];
        oacc[nt] = MFMA(pa, vb, oacc[nt]);
      }
    }
    __syncthreads();
  }
  lrow_l += __shfl_xor(lrow_l, 16);
  lrow_l += __shfl_xor(lrow_l, 32);
#pragma unroll
  for (int r = 0; r < 4; ++r) {
    float rl = 1.f / __shfl(lrow_l, quad * 4 + r);
    int row = q0 + wid * 16 + quad * 4 + r;
    size_t base = ((size_t)bb * 2048 + row) * 1024 + hh * 128;
#pragma unroll
    for (int nt = 0; nt < 8; ++nt)
      ctx[base + nt * 16 + l15] = f2bf(oacc[nt][r] * rl);
  }
}

// ---------------------------------------------------------------------------
// out = ctx(4096x1024) @ wcombT^T + bvec.  BM=BN=128, BK=64, K=1024. grid (32,40)
// reg-prefetch 2-phase pipeline (loads for kb+64 fly under MFMA on kb).
__global__ __launch_bounds__(256) void k_final(const ushort_t* __restrict__ ctx,
                                               const ushort_t* __restrict__ wcombT,
                                               const float* __restrict__ bvec,
                                               float* __restrict__ out) {
  __shared__ __align__(16) ushort_t As[128 * 72];
  __shared__ __align__(16) ushort_t Bs[128 * 72];
  const int tid = threadIdx.x;
  const int m0 = blockIdx.x * 128, n0 = blockIdx.y * 128;
  const int lane = tid & 63, wid = tid >> 6;
  const int quad = lane >> 4, l15 = lane & 15;
  const int wm = wid & 1, wn = wid >> 1;
  f32x4 acc[4][4];
#pragma unroll
  for (int a = 0; a < 4; ++a)
#pragma unroll
    for (int b = 0; b < 4; ++b) acc[a][b] = (f32x4){0.f, 0.f, 0.f, 0.f};
  const int ar = tid >> 1, as0 = (tid & 1) * 32;
  const ushort_t* ap = ctx + (size_t)(m0 + ar) * 1024 + as0;
  const ushort_t* bp = wcombT + (size_t)(n0 + ar) * 1024 + as0;
  us8 ra[4], rb[4];
#pragma unroll
  for (int w = 0; w < 4; ++w) {
    ra[w] = *(const us8*)(ap + w * 8);
    rb[w] = *(const us8*)(bp + w * 8);
  }
  for (int kb = 0; kb < 1024; kb += 64) {
#pragma unroll
    for (int w = 0; w < 4; ++w) {
      *(us8*)&As[ar * 72 + as0 + w * 8] = ra[w];
      *(us8*)&Bs[ar * 72 + as0 + w * 8] = rb[w];
    }
    __syncthreads();
    if (kb < 960) {
      const ushort_t* ap2 = ap + kb + 64;
      const ushort_t* bp2 = bp + kb + 64;
#pragma unroll
      for (int w = 0; w < 4; ++w) {
        ra[w] = *(const us8*)(ap2 + w * 8);
        rb[w] = *(const us8*)(bp2 + w * 8);
      }
    }
#pragma unroll
    for (int ks = 0; ks < 2; ++ks) {
      short8 a[4], b[4];
#pragma unroll
      for (int mt = 0; mt < 4; ++mt)
        a[mt] = *(const short8*)&As[(wm * 64 + mt * 16 + l15) * 72 + ks * 32 + quad * 8];
#pragma unroll
      for (int nt = 0; nt < 4; ++nt)
        b[nt] = *(const short8*)&Bs[(wn * 64 + nt * 16 + l15) * 72 + ks * 32 + quad * 8];
#pragma unroll
      for (int mt = 0; mt < 4; ++mt)
#pragma unroll
        for (int nt = 0; nt < 4; ++nt) acc[mt][nt] = MFMA(a[mt], b[nt], acc[mt][nt]);
    }
    __syncthreads();
  }
#pragma unroll
  for (int mt = 0; mt < 4; ++mt)
#pragma unroll
    for (int nt = 0; nt < 4; ++nt) {
      int col = wn * 64 + nt * 16 + l15;
      float bias = bvec[n0 + col];
#pragma unroll
      for (int r = 0; r < 4; ++r) {
        int row = m0 + wm * 64 + mt * 16 + quad * 4 + r;
        out[(size_t)row * 5120 + n0 + col] = acc[mt][nt][r] + bias;
      }
    }
}

// ---------------------------------------------------------------------------
extern "C" void kernel_launch(void* const* d_in, const int* in_sizes, int n_in,
                              void* d_out, int out_size, void* d_ws, size_t ws_size,
                              hipStream_t stream) {
  const float* H    = (const float*)d_in[0];
  const float* Wdkv = (const float*)d_in[1];
  const float* bdkv = (const float*)d_in[2];
  const float* Wdq  = (const float*)d_in[3];
  const float* bdq  = (const float*)d_in[4];
  const float* Wuk  = (const float*)d_in[5];
  // d_in[6] = b_uk : softmax-invariant -> unused
  const float* Wuv  = (const float*)d_in[7];
  const float* buv  = (const float*)d_in[8];
  const float* Wuq  = (const float*)d_in[9];
  const float* buq  = (const float*)d_in[10];
  const float* Wqr  = (const float*)d_in[11];
  const float* bqr  = (const float*)d_in[12];
  const float* Wkr  = (const float*)d_in[13];
  const float* bkr  = (const float*)d_in[14];
  const float* Wo   = (const float*)d_in[15];
  const float* bo   = (const float*)d_in[16];
  float* out = (float*)d_out;

  char* ws = (char*)d_ws;
  size_t off = 0;
  auto alloc = [&](size_t bytes) -> void* {
    void* p = ws + off;
    off += (bytes + 255) & ~(size_t)255;
    return p;
  };
  // --- region A (persistent) ~5.5 MB
  ushort_t* ckv    = (ushort_t*)alloc((size_t)4096 * 128 * 2);
  ushort_t* cq     = (ushort_t*)alloc((size_t)4096 * 128 * 2);
  ushort_t* ckvT   = (ushort_t*)alloc((size_t)2 * 128 * 2048 * 2);
  ushort_t* krot   = (ushort_t*)alloc((size_t)16 * 2048 * 16 * 2);
  ushort_t* qrot   = (ushort_t*)alloc((size_t)16 * 2048 * 16 * 2);
  ushort_t* wqkT   = (ushort_t*)alloc((size_t)8 * 128 * 128 * 2);
  float*    bqabs  = (float*)alloc((size_t)8 * 128 * 4);
  float*    bvec   = (float*)alloc((size_t)5120 * 4);
  // --- region B: split-K partials (25.2 MB), lifetime: gemm1_sk -> reduce
  size_t mark = off;
  float*    part   = (float*)alloc((size_t)4 * 4096 * 384 * 4);
  size_t endB = off;
  // --- region C aliases B (stream-ordered: all uses launch after k_reduce)
  off = mark;
  ushort_t* qabs   = (ushort_t*)alloc((size_t)16 * 2048 * 128 * 2);
  ushort_t* wcombT = (ushort_t*)alloc((size_t)5120 * 1024 * 2);
  ushort_t* ctx    = (ushort_t*)alloc((size_t)4096 * 1024 * 2);
  if (off < endB) off = endB;
  (void)ws_size; (void)in_sizes; (void)n_in; (void)out_size;

  hipLaunchKernelGGL(k_bvec_init, dim3(20), dim3(256), 0, stream, bo, bvec);
  hipLaunchKernelGGL(k_wqk, dim3(8), dim3(256), 0, stream, Wuq, Wuk, buq, wqkT, bqabs);
  hipLaunchKernelGGL(k_gemm1_sk, dim3(64, 2, 4), dim3(256), 0, stream,
                     H, Wdkv, Wdq, Wkr, part);
  hipLaunchKernelGGL(k_reduce, dim3(4096), dim3(384), 0, stream,
                     part, bdkv, bdq, bkr, ckv, cq, krot);
  hipLaunchKernelGGL(k_ckvt, dim3(64), dim3(256), 0, stream, ckv, ckvT);
  hipLaunchKernelGGL(k_comb, dim3(40, 8), dim3(256), 0, stream, Wo, Wuv, buv, wcombT, bvec);
  hipLaunchKernelGGL(k_qrot, dim3(128), dim3(256), 0, stream, cq, Wqr, bqr, qrot);
  hipLaunchKernelGGL(k_qabs, dim3(32, 8), dim3(256), 0, stream, cq, wqkT, bqabs, qabs);
  hipLaunchKernelGGL(k_attn, dim3(32, 16), dim3(256), 0, stream,
                     qabs, qrot, ckv, krot, ckvT, ctx);
  hipLaunchKernelGGL(k_final, dim3(32, 40), dim3(256), 0, stream, ctx, wcombT, bvec, out);
}

// Round 8
// 559.334 us; speedup vs baseline: 1.2391x; 1.0327x over previous
//
#include <hip/hip_runtime.h>

// ---------------------------------------------------------------------------
// MemoryOptimizedMLA on gfx950 — absorbed-MLA formulation.
//
//   c_kv = h@W_dkv+b ; c_q = h@W_dq+b ; k_rot = rope(h@W_kr+b)
//   W_qk[h] = W_uq_h @ W_uk_h^T (128x128), b_qabs[h] = b_uq_h @ W_uk_h^T
//   q_abs = (c_q@W_qk + b_qabs)/sqrt(640) ; q_rot = rope(c_q@W_qr + b_qr)/sqrt(640)
//   scores = q_abs . c_kv + q_rot . k_rot          (b_uk is softmax-inv.)
//   ctx = softmax(scores) @ c_kv      (128 dims, flash/online-softmax)
//   out = ctx @ W_combT^T + (b_uv@W_o + b_o),  W_comb[h] = W_uv_h @ W_o_h
//
// R2: gemm1 split-K + k_reduce epilogue; ws aliasing.
// R3: bvec fused into k_comb; softmax diet; first LDS swizzles.
// R4: k_ckvt (Vt staged vectorized); reg-prefetch pipelines; cvt_pk Ps.
// R5: k_attn swapped-QK lane-local softmax; packed-b32 staging swizzles.
// R7: k_wqk spill-bomb rebuilt as MFMA.  [577.6 us, PASS]
// R8: Q-hoist + launch_bounds(256,3) + k_qrot LDS staging  [FAIL 3.7e-2]
// R10: BISECTION — k_attn reverted to R7 exactly (known-pass); k_qrot keeps
//      the LDS staging (low-surface half of R8). If this passes, the Q-hoist/
//      launch-bounds combo was the bug; if it fails, k_qrot staging is.
// ---------------------------------------------------------------------------

typedef unsigned short ushort_t;
typedef __attribute__((ext_vector_type(8)))  short          short8;
typedef __attribute__((ext_vector_type(8)))  unsigned short us8;
typedef __attribute__((ext_vector_type(4)))  float          f32x4;
typedef __attribute__((ext_vector_type(4)))  unsigned int   u32x4;

#define SCALE_ATT 0.0395284707521047f  /* 1/sqrt(640) */

static __device__ inline unsigned short f2bf(float f) {
  union { float f; unsigned u; } v; v.f = f;
  unsigned r = (v.u + 0x7fffu + ((v.u >> 16) & 1u)) >> 16;
  return (unsigned short)r;
}
static __device__ inline float bf2f(unsigned short u) {
  union { unsigned u; float f; } v; v.u = ((unsigned)u) << 16;
  return v.f;
}
static __device__ inline unsigned cvt_pk_bf16(float a, float b) {
  unsigned r;
  asm("v_cvt_pk_bf16_f32 %0, %1, %2" : "=v"(r) : "v"(a), "v"(b));
  return r;  // low16 = bf16(a), high16 = bf16(b), RNE
}
static __device__ inline f32x4 MFMA(short8 a, short8 b, f32x4 c) {
  return __builtin_amdgcn_mfma_f32_16x16x32_bf16(a, b, c, 0, 0, 0);
}

// ---------------------------------------------------------------------------
// bvec init: bvec[n] = bo[n].  grid 20, block 256. (accumulated in k_comb)
__global__ __launch_bounds__(256) void k_bvec_init(const float* __restrict__ bo,
                                                   float* __restrict__ bvec) {
  int n = blockIdx.x * 256 + threadIdx.x;
  bvec[n] = bo[n];
}

// ---------------------------------------------------------------------------
// wqkT[h][j][i] = sum_d Wuq[i][h*624+d]*Wuk[j][h*624+d]  (bf16 MFMA, R7)
// + folded bqabs[h][j] = sum_d buq[h*624+d]*Wuk[j][h*624+d] (fp32).
// grid 8, block 256. BM=BN=128, BK=64, K=624 zero-padded to 640.
__global__ __launch_bounds__(256) void k_wqk(const float* __restrict__ Wuq,
                                             const float* __restrict__ Wuk,
                                             const float* __restrict__ buq,
                                             ushort_t* __restrict__ wqkT,
                                             float* __restrict__ bqabs) {
  __shared__ __align__(16) ushort_t As[128 * 72];
  __shared__ __align__(16) ushort_t Bs[128 * 72];
  const int tid = threadIdx.x;
  const int hh = blockIdx.x;
  const int lane = tid & 63, wid = tid >> 6;
  const int quad = lane >> 4, l15 = lane & 15;
  const int wm = wid & 1, wn = wid >> 1;
  f32x4 acc[4][4];
#pragma unroll
  for (int a = 0; a < 4; ++a)
#pragma unroll
    for (int b = 0; b < 4; ++b) acc[a][b] = (f32x4){0.f, 0.f, 0.f, 0.f};
  const int r = tid >> 1, c0 = (tid & 1) * 32;  // row 0..127, 32-float half
  float bacc = 0.f;
  for (int kb = 0; kb < 640; kb += 64) {
    const int dbase = kb + c0;
    const float* ak = Wuk + (size_t)r * 4992 + hh * 624 + dbase;
    const float* aq = Wuq + (size_t)r * 4992 + hh * 624 + dbase;
    const float* bu = buq + hh * 624 + dbase;
    float vk[32], vq[32];
    if (dbase + 32 <= 624) {       // full half (all but kb=576,c0=32)
#pragma unroll
      for (int w = 0; w < 8; ++w) {
        const f32x4 t1 = *(const f32x4*)(ak + w * 4);
        const f32x4 t2 = *(const f32x4*)(aq + w * 4);
        const f32x4 t3 = *(const f32x4*)(bu + w * 4);
#pragma unroll
        for (int e = 0; e < 4; ++e) { vk[w * 4 + e] = t1[e]; vq[w * 4 + e] = t2[e]; }
        bacc += t3[0] * t1[0] + t3[1] * t1[1] + t3[2] * t1[2] + t3[3] * t1[3];
      }
    } else {                        // guarded tail (d 608..639, 16 valid)
#pragma unroll
      for (int i2 = 0; i2 < 32; ++i2) {
        const bool ok = (dbase + i2) < 624;
        const float wkv = ok ? ak[i2] : 0.f;
        vk[i2] = wkv;
        vq[i2] = ok ? aq[i2] : 0.f;
        bacc += (ok ? bu[i2] : 0.f) * wkv;
      }
    }
    u32x4 pk0 = { cvt_pk_bf16(vk[0], vk[1]),  cvt_pk_bf16(vk[2], vk[3]),
                  cvt_pk_bf16(vk[4], vk[5]),  cvt_pk_bf16(vk[6], vk[7]) };
    u32x4 pk1 = { cvt_pk_bf16(vk[8], vk[9]),  cvt_pk_bf16(vk[10], vk[11]),
                  cvt_pk_bf16(vk[12], vk[13]), cvt_pk_bf16(vk[14], vk[15]) };
    u32x4 pk2 = { cvt_pk_bf16(vk[16], vk[17]), cvt_pk_bf16(vk[18], vk[19]),
                  cvt_pk_bf16(vk[20], vk[21]), cvt_pk_bf16(vk[22], vk[23]) };
    u32x4 pk3 = { cvt_pk_bf16(vk[24], vk[25]), cvt_pk_bf16(vk[26], vk[27]),
                  cvt_pk_bf16(vk[28], vk[29]), cvt_pk_bf16(vk[30], vk[31]) };
    *(u32x4*)&As[r * 72 + c0]      = pk0;
    *(u32x4*)&As[r * 72 + c0 + 8]  = pk1;
    *(u32x4*)&As[r * 72 + c0 + 16] = pk2;
    *(u32x4*)&As[r * 72 + c0 + 24] = pk3;
    u32x4 pq0 = { cvt_pk_bf16(vq[0], vq[1]),  cvt_pk_bf16(vq[2], vq[3]),
                  cvt_pk_bf16(vq[4], vq[5]),  cvt_pk_bf16(vq[6], vq[7]) };
    u32x4 pq1 = { cvt_pk_bf16(vq[8], vq[9]),  cvt_pk_bf16(vq[10], vq[11]),
                  cvt_pk_bf16(vq[12], vq[13]), cvt_pk_bf16(vq[14], vq[15]) };
    u32x4 pq2 = { cvt_pk_bf16(vq[16], vq[17]), cvt_pk_bf16(vq[18], vq[19]),
                  cvt_pk_bf16(vq[20], vq[21]), cvt_pk_bf16(vq[22], vq[23]) };
    u32x4 pq3 = { cvt_pk_bf16(vq[24], vq[25]), cvt_pk_bf16(vq[26], vq[27]),
                  cvt_pk_bf16(vq[28], vq[29]), cvt_pk_bf16(vq[30], vq[31]) };
    *(u32x4*)&Bs[r * 72 + c0]      = pq0;
    *(u32x4*)&Bs[r * 72 + c0 + 8]  = pq1;
    *(u32x4*)&Bs[r * 72 + c0 + 16] = pq2;
    *(u32x4*)&Bs[r * 72 + c0 + 24] = pq3;
    __syncthreads();
#pragma unroll
    for (int ks = 0; ks < 2; ++ks) {
      short8 a[4], b[4];
#pragma unroll
      for (int mt = 0; mt < 4; ++mt)
        a[mt] = *(const short8*)&As[(wm * 64 + mt * 16 + l15) * 72 + ks * 32 + quad * 8];
#pragma unroll
      for (int nt = 0; nt < 4; ++nt)
        b[nt] = *(const short8*)&Bs[(wn * 64 + nt * 16 + l15) * 72 + ks * 32 + quad * 8];
#pragma unroll
      for (int mt = 0; mt < 4; ++mt)
#pragma unroll
        for (int nt = 0; nt < 4; ++nt) acc[mt][nt] = MFMA(a[mt], b[nt], acc[mt][nt]);
    }
    __syncthreads();
  }
#pragma unroll
  for (int mt = 0; mt < 4; ++mt)
#pragma unroll
    for (int nt = 0; nt < 4; ++nt) {
      const int i = wn * 64 + nt * 16 + l15;           // Wuq index (col)
#pragma unroll
      for (int rr = 0; rr < 4; ++rr) {
        const int j = wm * 64 + mt * 16 + quad * 4 + rr;  // Wuk index (row)
        wqkT[(size_t)hh * 16384 + (size_t)j * 128 + i] = f2bf(acc[mt][nt][rr]);
      }
    }
  const float po = __shfl_xor(bacc, 1);
  if ((tid & 1) == 0) bqabs[hh * 128 + r] = bacc + po;
}

// ---------------------------------------------------------------------------
// GEMM1 split-K: partials of h @ [W_dkv|W_dq|W_kr].
// grid (64 mtiles, 2 nhalves, 4 ksplits), block 256 (4 waves, each 64x48).
__global__ __launch_bounds__(256) void k_gemm1_sk(
    const float* __restrict__ H, const float* __restrict__ Wdkv,
    const float* __restrict__ Wdq, const float* __restrict__ Wkr,
    float* __restrict__ part) {
  __shared__ __align__(16) ushort_t As[64 * 72];
  __shared__ __align__(16) ushort_t Bs[192 * 72];
  const int tid = threadIdx.x;
  const int m0 = blockIdx.x * 64;
  const int n0 = blockIdx.y * 192;
  const int kc0 = blockIdx.z * 1280;
  const int lane = tid & 63, wid = tid >> 6;
  const int quad = lane >> 4, l15 = lane & 15;
  f32x4 acc[4][3];
#pragma unroll
  for (int a = 0; a < 4; ++a)
#pragma unroll
    for (int b = 0; b < 3; ++b) acc[a][b] = (f32x4){0.f, 0.f, 0.f, 0.f};
  const int ar = tid >> 2, ak0 = (tid & 3) * 16;
  const int bkp = tid >> 3;   // 0..31: k-pair (k = 2*bkp, 2*bkp+1)
  const int bng = tid & 7;    // n-subgroup of 8 within each 64-col group
  const float* harow = H + (size_t)(m0 + ar) * 5120 + ak0;
  for (int kb = kc0; kb < kc0 + 1280; kb += 64) {
    const float* ap = harow + kb;
    f32x4 af0 = *(const f32x4*)ap, af1 = *(const f32x4*)(ap + 4);
    f32x4 af2 = *(const f32x4*)(ap + 8), af3 = *(const f32x4*)(ap + 12);
    u32x4 apk0 = { cvt_pk_bf16(af0[0], af0[1]), cvt_pk_bf16(af0[2], af0[3]),
                   cvt_pk_bf16(af1[0], af1[1]), cvt_pk_bf16(af1[2], af1[3]) };
    u32x4 apk1 = { cvt_pk_bf16(af2[0], af2[1]), cvt_pk_bf16(af2[2], af2[3]),
                   cvt_pk_bf16(af3[0], af3[1]), cvt_pk_bf16(af3[2], af3[3]) };
    *(u32x4*)&As[ar * 72 + ak0] = apk0;
    *(u32x4*)&As[ar * 72 + ak0 + 8] = apk1;
    const int krow = kb + 2 * bkp;
    const int kd = (2 * bkp) ^ (bng << 3);   // swizzled physical k slot
#pragma unroll
    for (int g = 0; g < 3; ++g) {
      const int lcol = g * 64 + bng * 8;
      const int col = n0 + lcol;
      const float* base = (col < 128 ? Wdkv + col
                         : col < 256 ? Wdq + (col - 128)
                                     : Wkr + (col - 256)) + (size_t)krow * 128;
      f32x4 r0a = *(const f32x4*)base, r0b = *(const f32x4*)(base + 4);
      f32x4 r1a = *(const f32x4*)(base + 128), r1b = *(const f32x4*)(base + 132);
#pragma unroll
      for (int i = 0; i < 4; ++i) {
        *(unsigned*)&Bs[(lcol + i) * 72 + kd]     = cvt_pk_bf16(r0a[i], r1a[i]);
        *(unsigned*)&Bs[(lcol + 4 + i) * 72 + kd] = cvt_pk_bf16(r0b[i], r1b[i]);
      }
    }
    __syncthreads();
#pragma unroll
    for (int ks = 0; ks < 2; ++ks) {
      short8 a[4], b[3];
#pragma unroll
      for (int mt = 0; mt < 4; ++mt)
        a[mt] = *(const short8*)&As[(mt * 16 + l15) * 72 + ks * 32 + quad * 8];
#pragma unroll
      for (int nt = 0; nt < 3; ++nt) {
        const int row = wid * 48 + nt * 16 + l15;
        const int kofs = (ks * 32 + quad * 8) ^ (((row >> 3) & 7) << 3);
        b[nt] = *(const short8*)&Bs[row * 72 + kofs];
      }
#pragma unroll
      for (int mt = 0; mt < 4; ++mt)
#pragma unroll
        for (int nt = 0; nt < 3; ++nt) acc[mt][nt] = MFMA(a[mt], b[nt], acc[mt][nt]);
    }
    __syncthreads();
  }
  const size_t pb = (size_t)blockIdx.z * 4096 * 384;
#pragma unroll
  for (int mt = 0; mt < 4; ++mt)
#pragma unroll
    for (int nt = 0; nt < 3; ++nt) {
      const int col = n0 + wid * 48 + nt * 16 + l15;
#pragma unroll
      for (int r = 0; r < 4; ++r) {
        const int row = m0 + mt * 16 + quad * 4 + r;
        part[pb + (size_t)row * 384 + col] = acc[mt][nt][r];
      }
    }
}

// ---------------------------------------------------------------------------
// reduce 4 partials + bias; rope for the k_rot slice. grid 4096, block 384.
__global__ __launch_bounds__(384) void k_reduce(
    const float* __restrict__ part, const float* __restrict__ bdkv,
    const float* __restrict__ bdq, const float* __restrict__ bkr,
    ushort_t* __restrict__ ckv, ushort_t* __restrict__ cq,
    ushort_t* __restrict__ krot) {
  const int row = blockIdx.x;
  const int c = threadIdx.x;
  float v = 0.f;
#pragma unroll
  for (int ks = 0; ks < 4; ++ks)
    v += part[((size_t)ks * 4096 + row) * 384 + c];
  if (c < 128) {
    v += bdkv[c];
    ckv[(size_t)row * 128 + c] = f2bf(v);
  } else if (c < 256) {
    v += bdq[c - 128];
    cq[(size_t)row * 128 + (c - 128)] = f2bf(v);
  } else {
    v += bkr[c - 256];
    float partner = __shfl_xor(v, 4);
    const int j = (c - 256) & 15;
    const int head = (c - 256) >> 4;
    const int s = row & 2047, bb = row >> 11;
    const int j4 = j & 3;
    const float fr = (j4 == 0) ? 1.f : (j4 == 1) ? 0.1f : (j4 == 2) ? 0.01f : 0.001f;
    float sth, cth;
    __sincosf(s * 0.025f * fr, &sth, &cth);
    const float y = (j < 4) ? (v * cth - partner * sth)
                  : (j < 8) ? (v * cth + partner * sth) : v;
    krot[((size_t)((bb << 3) + head) * 2048 + s) * 16 + j] = f2bf(y);
  }
}

// ---------------------------------------------------------------------------
// ckvT[b][d][s] = ckv[b*2048+s][d].  64 blocks x 256 thr, 64 s x 128 d tiles.
__global__ __launch_bounds__(256) void k_ckvt(const ushort_t* __restrict__ ckv,
                                              ushort_t* __restrict__ ckvT) {
  __shared__ __align__(16) ushort_t T[128 * 72];
  const int tid = threadIdx.x;
  const int s0 = blockIdx.x * 64;
  const int bb = s0 >> 11, sl = s0 & 2047;
  const int sr = tid >> 2, sseg = tid & 3;
  {
    const ushort_t* kp = ckv + ((size_t)s0 + sr) * 128 + sseg * 32;
    us8 v[4];
#pragma unroll
    for (int w = 0; w < 4; ++w) v[w] = *(const us8*)(kp + w * 8);
#pragma unroll
    for (int w = 0; w < 4; ++w)
#pragma unroll
      for (int i = 0; i < 8; ++i)
        T[(sseg * 32 + w * 8 + i) * 72 + sr] = v[w][i];
  }
  __syncthreads();
  const int vrow = tid >> 1, vk0 = (tid & 1) * 32;
#pragma unroll
  for (int w = 0; w < 4; ++w) {
    us8 t = *(const us8*)&T[vrow * 72 + vk0 + w * 8];
    *(us8*)(ckvT + ((size_t)bb * 128 + vrow) * 2048 + sl + vk0 + w * 8) = t;
  }
}

// ---------------------------------------------------------------------------
// q_rot = rope(c_q @ W_qr + b_qr) * SCALE_ATT.  grid 128, block 256.
// R8(kept): Wqr head-slice (128x16 f32 = 8 KB) staged in LDS once per block
//     (all 256 threads share one head) — broadcast reads thereafter.
__global__ __launch_bounds__(256) void k_qrot(const ushort_t* __restrict__ cq,
                                              const float* __restrict__ Wqr,
                                              const float* __restrict__ bqr,
                                              ushort_t* __restrict__ qrot) {
  __shared__ float Wl[128 * 16];
  int gidx = blockIdx.x * 256 + threadIdx.x;  // 0..32767
  int s = gidx & 2047, bh = gidx >> 11;
  int hh = bh & 7, bb = bh >> 3;
  {
    int t = threadIdx.x;
    int row = t >> 1, c8 = (t & 1) * 8;
    const float* src = Wqr + (size_t)row * 128 + hh * 16 + c8;
#pragma unroll
    for (int i = 0; i < 8; ++i) Wl[row * 16 + c8 + i] = src[i];
  }
  __syncthreads();
  const ushort_t* crow = cq + ((size_t)bb * 2048 + s) * 128;
  float acc[16];
#pragma unroll
  for (int j = 0; j < 16; ++j) acc[j] = bqr[hh * 16 + j];
  for (int k0 = 0; k0 < 128; k0 += 8) {
    us8 cv8 = *(const us8*)(crow + k0);
#pragma unroll
    for (int i = 0; i < 8; ++i) {
      float cv = bf2f(cv8[i]);
      const float* wr = &Wl[(k0 + i) * 16];
#pragma unroll
      for (int j = 0; j < 16; ++j) acc[j] += cv * wr[j];
    }
  }
  float y[16];
#pragma unroll
  for (int j4 = 0; j4 < 4; ++j4) {
    float fr = (j4 == 0) ? 1.f : (j4 == 1) ? 0.1f : (j4 == 2) ? 0.01f : 0.001f;
    float sth, cth;
    __sincosf(s * 0.025f * fr, &sth, &cth);
    y[j4] = acc[j4] * cth - acc[j4 + 4] * sth;
    y[j4 + 4] = acc[j4 + 4] * cth + acc[j4] * sth;
  }
#pragma unroll
  for (int j = 8; j < 16; ++j) y[j] = acc[j];
  us8 o0, o1;
#pragma unroll
  for (int j = 0; j < 8; ++j) {
    o0[j] = f2bf(y[j] * SCALE_ATT);
    o1[j] = f2bf(y[8 + j] * SCALE_ATT);
  }
  *(us8*)(qrot + (size_t)gidx * 16) = o0;
  *(us8*)(qrot + (size_t)gidx * 16 + 8) = o1;
}

// ---------------------------------------------------------------------------
// q_abs = (c_q @ W_qk[h] + b_qabs[h]) * SCALE_ATT.  BM=128,BN=128,BK=64. grid (32, 8).
__global__ __launch_bounds__(256) void k_qabs(const ushort_t* __restrict__ cq,
                                              const ushort_t* __restrict__ wqkT,
                                              const float* __restrict__ bqabs,
                                              ushort_t* __restrict__ qabs) {
  __shared__ __align__(16) ushort_t As[128 * 72];
  __shared__ __align__(16) ushort_t Bs[128 * 72];
  const int tid = threadIdx.x;
  const int m0 = blockIdx.x * 128, hh = blockIdx.y;
  const int lane = tid & 63, wid = tid >> 6;
  const int quad = lane >> 4, l15 = lane & 15;
  const int wm = wid & 1, wn = wid >> 1;
  f32x4 acc[4][4];
#pragma unroll
  for (int a = 0; a < 4; ++a)
#pragma unroll
    for (int b = 0; b < 4; ++b) acc[a][b] = (f32x4){0.f, 0.f, 0.f, 0.f};
  const int ar = tid >> 1, as0 = (tid & 1) * 32;
  for (int kb = 0; kb < 128; kb += 64) {
    const ushort_t* ap = cq + (size_t)(m0 + ar) * 128 + kb + as0;
    const ushort_t* bp = wqkT + (size_t)hh * 16384 + (size_t)ar * 128 + kb + as0;
#pragma unroll
    for (int w = 0; w < 4; ++w) {
      *(us8*)&As[ar * 72 + as0 + w * 8] = *(const us8*)(ap + w * 8);
      *(us8*)&Bs[ar * 72 + as0 + w * 8] = *(const us8*)(bp + w * 8);
    }
    __syncthreads();
#pragma unroll
    for (int ks = 0; ks < 2; ++ks) {
      short8 a[4], b[4];
#pragma unroll
      for (int mt = 0; mt < 4; ++mt)
        a[mt] = *(const short8*)&As[(wm * 64 + mt * 16 + l15) * 72 + ks * 32 + quad * 8];
#pragma unroll
      for (int nt = 0; nt < 4; ++nt)
        b[nt] = *(const short8*)&Bs[(wn * 64 + nt * 16 + l15) * 72 + ks * 32 + quad * 8];
#pragma unroll
      for (int mt = 0; mt < 4; ++mt)
#pragma unroll
        for (int nt = 0; nt < 4; ++nt) acc[mt][nt] = MFMA(a[mt], b[nt], acc[mt][nt]);
    }
    __syncthreads();
  }
#pragma unroll
  for (int mt = 0; mt < 4; ++mt)
#pragma unroll
    for (int nt = 0; nt < 4; ++nt) {
      int col = wn * 64 + nt * 16 + l15;
      float bias = bqabs[hh * 128 + col];
#pragma unroll
      for (int r = 0; r < 4; ++r) {
        int m = m0 + wm * 64 + mt * 16 + quad * 4 + r;
        int bb = m >> 11, s = m & 2047;
        qabs[((size_t)((bb << 3) + hh) * 2048 + s) * 128 + col] =
            f2bf((acc[mt][nt][r] + bias) * SCALE_ATT);
      }
    }
}

// ---------------------------------------------------------------------------
// wcombT[n][h*128+c] = sum_d W_o[h*640+d][n] * W_uv[c][h*640+d]
// + fused bvec accumulation: bvec[n] += sum_d buv[h*640+d]*W_o[h*640+d][n]
__global__ __launch_bounds__(256) void k_comb(const float* __restrict__ Wo,
                                              const float* __restrict__ Wuv,
                                              const float* __restrict__ buv,
                                              ushort_t* __restrict__ wcombT,
                                              float* __restrict__ bvec) {
  __shared__ __align__(16) ushort_t As[128 * 72];
  __shared__ __align__(16) ushort_t Bs[128 * 72];
  const int tid = threadIdx.x;
  const int n0 = blockIdx.x * 128, hh = blockIdx.y;
  const int lane = tid & 63, wid = tid >> 6;
  const int quad = lane >> 4, l15 = lane & 15;
  const int wm = wid & 1, wn = wid >> 1;
  f32x4 acc[4][4];
#pragma unroll
  for (int a = 0; a < 4; ++a)
#pragma unroll
    for (int b = 0; b < 4; ++b) acc[a][b] = (f32x4){0.f, 0.f, 0.f, 0.f};
  const int akp = tid >> 3;   // 0..31: k-pair
  const int ang = tid & 7;    // n-group of 16
  const int kd0 = (2 * akp) ^ (((2 * ang) & 7) << 3);
  const int kd1 = (2 * akp) ^ (((2 * ang + 1) & 7) << 3);
  const int bc = tid >> 1, bd0 = (tid & 1) * 32;
  const int bvc = tid >> 1, bvh = tid & 1;
  const int bswz = ((bvc >> 3) & 7) << 3;     // bacc read-side swizzle
  const float* buvh = buv + hh * 640;
  float bacc = 0.f;
  for (int kb = 0; kb < 640; kb += 64) {
    {
      const float* ap0 = Wo + (size_t)(hh * 640 + kb + 2 * akp) * 5120 + n0 + ang * 16;
      const float* ap1 = ap0 + 5120;
      f32x4 r0[4], r1[4];
#pragma unroll
      for (int w = 0; w < 4; ++w) {
        r0[w] = *(const f32x4*)(ap0 + w * 4);
        r1[w] = *(const f32x4*)(ap1 + w * 4);
      }
#pragma unroll
      for (int w = 0; w < 2; ++w)
#pragma unroll
        for (int i = 0; i < 4; ++i)
          *(unsigned*)&As[(ang * 16 + w * 4 + i) * 72 + kd0] =
              cvt_pk_bf16(r0[w][i], r1[w][i]);
#pragma unroll
      for (int w = 2; w < 4; ++w)
#pragma unroll
        for (int i = 0; i < 4; ++i)
          *(unsigned*)&As[(ang * 16 + w * 4 + i) * 72 + kd1] =
              cvt_pk_bf16(r0[w][i], r1[w][i]);
    }
    const float* bp = Wuv + (size_t)bc * 5120 + hh * 640 + kb + bd0;
    f32x4 b0 = *(const f32x4*)bp, b1 = *(const f32x4*)(bp + 4);
    f32x4 b2 = *(const f32x4*)(bp + 8), b3 = *(const f32x4*)(bp + 12);
    f32x4 b4 = *(const f32x4*)(bp + 16), b5 = *(const f32x4*)(bp + 20);
    f32x4 b6 = *(const f32x4*)(bp + 24), b7 = *(const f32x4*)(bp + 28);
    u32x4 q0 = { cvt_pk_bf16(b0[0], b0[1]), cvt_pk_bf16(b0[2], b0[3]),
                 cvt_pk_bf16(b1[0], b1[1]), cvt_pk_bf16(b1[2], b1[3]) };
    u32x4 q1 = { cvt_pk_bf16(b2[0], b2[1]), cvt_pk_bf16(b2[2], b2[3]),
                 cvt_pk_bf16(b3[0], b3[1]), cvt_pk_bf16(b3[2], b3[3]) };
    u32x4 q2 = { cvt_pk_bf16(b4[0], b4[1]), cvt_pk_bf16(b4[2], b4[3]),
                 cvt_pk_bf16(b5[0], b5[1]), cvt_pk_bf16(b5[2], b5[3]) };
    u32x4 q3 = { cvt_pk_bf16(b6[0], b6[1]), cvt_pk_bf16(b6[2], b6[3]),
                 cvt_pk_bf16(b7[0], b7[1]), cvt_pk_bf16(b7[2], b7[3]) };
    *(u32x4*)&Bs[bc * 72 + bd0]      = q0;
    *(u32x4*)&Bs[bc * 72 + bd0 + 8]  = q1;
    *(u32x4*)&Bs[bc * 72 + bd0 + 16] = q2;
    *(u32x4*)&Bs[bc * 72 + bd0 + 24] = q3;
    __syncthreads();
    // bvec partial from the staged W_o tile (swizzle-compensated read)
#pragma unroll
    for (int d8 = 0; d8 < 4; ++d8) {
      const int k0 = bvh * 32 + d8 * 8;       // logical k base (8-aligned)
      const us8 a8 = *(const us8*)&As[bvc * 72 + (k0 ^ bswz)];
      const f32x4 b4a = *(const f32x4*)&buvh[kb + k0];
      const f32x4 b4b = *(const f32x4*)&buvh[kb + k0 + 4];
      bacc += b4a[0] * bf2f(a8[0]) + b4a[1] * bf2f(a8[1]) +
              b4a[2] * bf2f(a8[2]) + b4a[3] * bf2f(a8[3]) +
              b4b[0] * bf2f(a8[4]) + b4b[1] * bf2f(a8[5]) +
              b4b[2] * bf2f(a8[6]) + b4b[3] * bf2f(a8[7]);
    }
#pragma unroll
    for (int ks = 0; ks < 2; ++ks) {
      short8 a[4], b[4];
#pragma unroll
      for (int mt = 0; mt < 4; ++mt) {
        const int row = wm * 64 + mt * 16 + l15;
        const int kofs = (ks * 32 + quad * 8) ^ (((row >> 3) & 7) << 3);
        a[mt] = *(const short8*)&As[row * 72 + kofs];
      }
#pragma unroll
      for (int nt = 0; nt < 4; ++nt)
        b[nt] = *(const short8*)&Bs[(wn * 64 + nt * 16 + l15) * 72 + ks * 32 + quad * 8];
#pragma unroll
      for (int mt = 0; mt < 4; ++mt)
#pragma unroll
        for (int nt = 0; nt < 4; ++nt) acc[mt][nt] = MFMA(a[mt], b[nt], acc[mt][nt]);
    }
    __syncthreads();
  }
#pragma unroll
  for (int mt = 0; mt < 4; ++mt)
#pragma unroll
    for (int nt = 0; nt < 4; ++nt) {
      int col = wn * 64 + nt * 16 + l15;
#pragma unroll
      for (int r = 0; r < 4; ++r) {
        int n = n0 + wm * 64 + mt * 16 + quad * 4 + r;
        wcombT[(size_t)n * 1024 + hh * 128 + col] = f2bf(acc[mt][nt][r]);
      }
    }
  atomicAdd(&bvec[n0 + bvc], bacc);
}

// ---------------------------------------------------------------------------
// Flash attention over absorbed dims. grid (32 q-tiles, 16 bh), block 256.
// R7 version (known-pass): swapped-QK lane-local softmax, Qs in LDS.
__global__ __launch_bounds__(256) void k_attn(const ushort_t* __restrict__ qabs,
                                              const ushort_t* __restrict__ qrot,
                                              const ushort_t* __restrict__ ckv,
                                              const ushort_t* __restrict__ krot,
                                              const ushort_t* __restrict__ ckvT,
                                              ushort_t* __restrict__ ctx) {
  __shared__ __align__(16) ushort_t Qs[64 * 168];
  __shared__ __align__(16) ushort_t Ks[64 * 168];
  __shared__ __align__(16) ushort_t Vt[128 * 72];
  __shared__ __align__(16) ushort_t Ps[64 * 72];
  const int tid = threadIdx.x;
  const int bh = blockIdx.y, bb = bh >> 3, hh = bh & 7;
  const int q0 = blockIdx.x * 64;
  const int lane = tid & 63, wid = tid >> 6;
  const int quad = lane >> 4, l15 = lane & 15;
  const int sr = tid >> 2, sseg = tid & 3;
  const int vrow = tid >> 1, vk0 = (tid & 1) * 32;
  (void)hh;
  {  // Q staging (once) + static zero tails for Qs AND Ks (cols 144..159)
    const ushort_t* qa = qabs + ((size_t)bh * 2048 + q0 + sr) * 128 + sseg * 32;
#pragma unroll
    for (int w = 0; w < 4; ++w)
      *(us8*)&Qs[sr * 168 + sseg * 32 + w * 8] = *(const us8*)(qa + w * 8);
    if (sseg == 0) {
      const ushort_t* qr = qrot + ((size_t)bh * 2048 + q0 + sr) * 16;
      *(us8*)&Qs[sr * 168 + 128] = *(const us8*)qr;
      *(us8*)&Qs[sr * 168 + 136] = *(const us8*)(qr + 8);
    }
    if (sseg == 1) {
      us8 z = (us8)0;
      *(us8*)&Qs[sr * 168 + 144] = z;
      *(us8*)&Qs[sr * 168 + 152] = z;
      *(us8*)&Ks[sr * 168 + 144] = z;
      *(us8*)&Ks[sr * 168 + 152] = z;
    }
  }
  us8 kreg[4], vreg[4], krr0, krr1;
  auto loadKV = [&](int key0) {
    const ushort_t* kp = ckv + ((size_t)bb * 2048 + key0 + sr) * 128 + sseg * 32;
#pragma unroll
    for (int w = 0; w < 4; ++w) kreg[w] = *(const us8*)(kp + w * 8);
    const ushort_t* vp = ckvT + ((size_t)bb * 128 + vrow) * 2048 + key0 + vk0;
#pragma unroll
    for (int w = 0; w < 4; ++w) vreg[w] = *(const us8*)(vp + w * 8);
    if (sseg == 0) {
      const ushort_t* kr = krot + ((size_t)bh * 2048 + key0 + sr) * 16;
      krr0 = *(const us8*)kr;
      krr1 = *(const us8*)(kr + 8);
    }
  };
  loadKV(0);
  f32x4 oacc[8];
#pragma unroll
  for (int i = 0; i < 8; ++i) oacc[i] = (f32x4){0.f, 0.f, 0.f, 0.f};
  float mrow[4] = {-1e30f, -1e30f, -1e30f, -1e30f};  // PV-side (q = quad*4+r)
  float m_sm = -1e30f;                               // SM-side (q = l15)
  float lrow_l = 0.f;                                // per-lane partial sum

  for (int kt = 0; kt < 32; ++kt) {
    // write prefetched regs -> LDS
#pragma unroll
    for (int w = 0; w < 4; ++w)
      *(us8*)&Ks[sr * 168 + sseg * 32 + w * 8] = kreg[w];
    if (sseg == 0) {
      *(us8*)&Ks[sr * 168 + 128] = krr0;
      *(us8*)&Ks[sr * 168 + 136] = krr1;
    }
#pragma unroll
    for (int w = 0; w < 4; ++w)
      *(us8*)&Vt[vrow * 72 + vk0 + w * 8] = vreg[w];
    __syncthreads();
    f32x4 sacc[4];   // sacc[nt][r]: key = nt*16 + quad*4 + r, query = l15
#pragma unroll
    for (int nt = 0; nt < 4; ++nt) sacc[nt] = (f32x4){0.f, 0.f, 0.f, 0.f};
#pragma unroll
    for (int ks = 0; ks < 5; ++ks) {
      short8 aq = *(const short8*)&Qs[(wid * 16 + l15) * 168 + ks * 32 + quad * 8];
#pragma unroll
      for (int nt = 0; nt < 4; ++nt) {
        short8 bk = *(const short8*)&Ks[(nt * 16 + l15) * 168 + ks * 32 + quad * 8];
        sacc[nt] = MFMA(bk, aq, sacc[nt]);   // swapped: D[key][query]
      }
    }
    if (kt < 31) loadKV((kt + 1) * 64);   // VMEM in flight during softmax+PV
    // ---- swapped softmax: lane owns query l15, 16 keys in regs
    float mx = sacc[0][0];
#pragma unroll
    for (int nt = 0; nt < 4; ++nt)
#pragma unroll
      for (int r = 0; r < 4; ++r) mx = fmaxf(mx, sacc[nt][r]);
    mx = fmaxf(mx, __shfl_xor(mx, 16));
    mx = fmaxf(mx, __shfl_xor(mx, 32));
    const bool grew = mx > m_sm;
    if (__any(grew)) {
      if (grew) { lrow_l *= __expf(m_sm - mx); m_sm = mx; }
#pragma unroll
      for (int r = 0; r < 4; ++r) {
        float mnew = __shfl(m_sm, quad * 4 + r);
        if (mnew > mrow[r]) {
          float alpha = __expf(mrow[r] - mnew);
          mrow[r] = mnew;
#pragma unroll
          for (int t8 = 0; t8 < 8; ++t8) oacc[t8][r] *= alpha;
        }
      }
    }
    float rs = 0.f;
    const int prow = (wid * 16 + l15) * 72 + quad * 4;
#pragma unroll
    for (int nt = 0; nt < 4; ++nt) {
      float p0 = __expf(sacc[nt][0] - m_sm);
      float p1 = __expf(sacc[nt][1] - m_sm);
      float p2 = __expf(sacc[nt][2] - m_sm);
      float p3 = __expf(sacc[nt][3] - m_sm);
      rs += (p0 + p1) + (p2 + p3);
      *(unsigned*)&Ps[prow + nt * 16]     = cvt_pk_bf16(p0, p1);
      *(unsigned*)&Ps[prow + nt * 16 + 2] = cvt_pk_bf16(p2, p3);
    }
    lrow_l += rs;
    // Ps rows are wave-private: intra-wave LDS RAW ordered by lgkmcnt.
#pragma unroll
    for (int kk = 0; kk < 2; ++kk) {
      short8 pa = *(const short8*)&Ps[(wid * 16 + l15) * 72 + kk * 32 + quad * 8];
#pragma unroll
      for (int nt = 0; nt < 8; ++nt) {
        short8 vb = *(const short8*)&Vt[(nt * 16 + l15) * 72 + kk * 32 + quad * 8];
        oacc[nt] = MFMA(pa, vb, oacc[nt]);
      }
    }
    __syncthreads();
  }
  lrow_l += __shfl_xor(lrow_l, 16);
  lrow_l += __shfl_xor(lrow_l, 32);
#pragma unroll
  for (int r = 0; r < 4; ++r) {
    float rl = 1.f / __shfl(lrow_l, quad * 4 + r);
    int row = q0 + wid * 16 + quad * 4 + r;
    size_t base = ((size_t)bb * 2048 + row) * 1024 + hh * 128;
#pragma unroll
    for (int nt = 0; nt < 8; ++nt)
      ctx[base + nt * 16 + l15] = f2bf(oacc[nt][r] * rl);
  }
}

// ---------------------------------------------------------------------------
// out = ctx(4096x1024) @ wcombT^T + bvec.  BM=BN=128, BK=64, K=1024. grid (32,40)
// reg-prefetch 2-phase pipeline (loads for kb+64 fly under MFMA on kb).
__global__ __launch_bounds__(256) void k_final(const ushort_t* __restrict__ ctx,
                                               const ushort_t* __restrict__ wcombT,
                                               const float* __restrict__ bvec,
                                               float* __restrict__ out) {
  __shared__ __align__(16) ushort_t As[128 * 72];
  __shared__ __align__(16) ushort_t Bs[128 * 72];
  const int tid = threadIdx.x;
  const int m0 = blockIdx.x * 128, n0 = blockIdx.y * 128;
  const int lane = tid & 63, wid = tid >> 6;
  const int quad = lane >> 4, l15 = lane & 15;
  const int wm = wid & 1, wn = wid >> 1;
  f32x4 acc[4][4];
#pragma unroll
  for (int a = 0; a < 4; ++a)
#pragma unroll
    for (int b = 0; b < 4; ++b) acc[a][b] = (f32x4){0.f, 0.f, 0.f, 0.f};
  const int ar = tid >> 1, as0 = (tid & 1) * 32;
  const ushort_t* ap = ctx + (size_t)(m0 + ar) * 1024 + as0;
  const ushort_t* bp = wcombT + (size_t)(n0 + ar) * 1024 + as0;
  us8 ra[4], rb[4];
#pragma unroll
  for (int w = 0; w < 4; ++w) {
    ra[w] = *(const us8*)(ap + w * 8);
    rb[w] = *(const us8*)(bp + w * 8);
  }
  for (int kb = 0; kb < 1024; kb += 64) {
#pragma unroll
    for (int w = 0; w < 4; ++w) {
      *(us8*)&As[ar * 72 + as0 + w * 8] = ra[w];
      *(us8*)&Bs[ar * 72 + as0 + w * 8] = rb[w];
    }
    __syncthreads();
    if (kb < 960) {
      const ushort_t* ap2 = ap + kb + 64;
      const ushort_t* bp2 = bp + kb + 64;
#pragma unroll
      for (int w = 0; w < 4; ++w) {
        ra[w] = *(const us8*)(ap2 + w * 8);
        rb[w] = *(const us8*)(bp2 + w * 8);
      }
    }
#pragma unroll
    for (int ks = 0; ks < 2; ++ks) {
      short8 a[4], b[4];
#pragma unroll
      for (int mt = 0; mt < 4; ++mt)
        a[mt] = *(const short8*)&As[(wm * 64 + mt * 16 + l15) * 72 + ks * 32 + quad * 8];
#pragma unroll
      for (int nt = 0; nt < 4; ++nt)
        b[nt] = *(const short8*)&Bs[(wn * 64 + nt * 16 + l15) * 72 + ks * 32 + quad * 8];
#pragma unroll
      for (int mt = 0; mt < 4; ++mt)
#pragma unroll
        for (int nt = 0; nt < 4; ++nt) acc[mt][nt] = MFMA(a[mt], b[nt], acc[mt][nt]);
    }
    __syncthreads();
  }
#pragma unroll
  for (int mt = 0; mt < 4; ++mt)
#pragma unroll
    for (int nt = 0; nt < 4; ++nt) {
      int col = wn * 64 + nt * 16 + l15;
      float bias = bvec[n0 + col];
#pragma unroll
      for (int r = 0; r < 4; ++r) {
        int row = m0 + wm * 64 + mt * 16 + quad * 4 + r;
        out[(size_t)row * 5120 + n0 + col] = acc[mt][nt][r] + bias;
      }
    }
}

// ---------------------------------------------------------------------------
extern "C" void kernel_launch(void* const* d_in, const int* in_sizes, int n_in,
                              void* d_out, int out_size, void* d_ws, size_t ws_size,
                              hipStream_t stream) {
  const float* H    = (const float*)d_in[0];
  const float* Wdkv = (const float*)d_in[1];
  const float* bdkv = (const float*)d_in[2];
  const float* Wdq  = (const float*)d_in[3];
  const float* bdq  = (const float*)d_in[4];
  const float* Wuk  = (const float*)d_in[5];
  // d_in[6] = b_uk : softmax-invariant -> unused
  const float* Wuv  = (const float*)d_in[7];
  const float* buv  = (const float*)d_in[8];
  const float* Wuq  = (const float*)d_in[9];
  const float* buq  = (const float*)d_in[10];
  const float* Wqr  = (const float*)d_in[11];
  const float* bqr  = (const float*)d_in[12];
  const float* Wkr  = (const float*)d_in[13];
  const float* bkr  = (const float*)d_in[14];
  const float* Wo   = (const float*)d_in[15];
  const float* bo   = (const float*)d_in[16];
  float* out = (float*)d_out;

  char* ws = (char*)d_ws;
  size_t off = 0;
  auto alloc = [&](size_t bytes) -> void* {
    void* p = ws + off;
    off += (bytes + 255) & ~(size_t)255;
    return p;
  };
  // --- region A (persistent) ~5.5 MB
  ushort_t* ckv    = (ushort_t*)alloc((size_t)4096 * 128 * 2);
  ushort_t* cq     = (ushort_t*)alloc((size_t)4096 * 128 * 2);
  ushort_t* ckvT   = (ushort_t*)alloc((size_t)2 * 128 * 2048 * 2);
  ushort_t* krot   = (ushort_t*)alloc((size_t)16 * 2048 * 16 * 2);
  ushort_t* qrot   = (ushort_t*)alloc((size_t)16 * 2048 * 16 * 2);
  ushort_t* wqkT   = (ushort_t*)alloc((size_t)8 * 128 * 128 * 2);
  float*    bqabs  = (float*)alloc((size_t)8 * 128 * 4);
  float*    bvec   = (float*)alloc((size_t)5120 * 4);
  // --- region B: split-K partials (25.2 MB), lifetime: gemm1_sk -> reduce
  size_t mark = off;
  float*    part   = (float*)alloc((size_t)4 * 4096 * 384 * 4);
  size_t endB = off;
  // --- region C aliases B (stream-ordered: all uses launch after k_reduce)
  off = mark;
  ushort_t* qabs   = (ushort_t*)alloc((size_t)16 * 2048 * 128 * 2);
  ushort_t* wcombT = (ushort_t*)alloc((size_t)5120 * 1024 * 2);
  ushort_t* ctx    = (ushort_t*)alloc((size_t)4096 * 1024 * 2);
  if (off < endB) off = endB;
  (void)ws_size; (void)in_sizes; (void)n_in; (void)out_size;

  hipLaunchKernelGGL(k_bvec_init, dim3(20), dim3(256), 0, stream, bo, bvec);
  hipLaunchKernelGGL(k_wqk, dim3(8), dim3(256), 0, stream, Wuq, Wuk, buq, wqkT, bqabs);
  hipLaunchKernelGGL(k_gemm1_sk, dim3(64, 2, 4), dim3(256), 0, stream,
                     H, Wdkv, Wdq, Wkr, part);
  hipLaunchKernelGGL(k_reduce, dim3(4096), dim3(384), 0, stream,
                     part, bdkv, bdq, bkr, ckv, cq, krot);
  hipLaunchKernelGGL(k_ckvt, dim3(64), dim3(256), 0, stream, ckv, ckvT);
  hipLaunchKernelGGL(k_comb, dim3(40, 8), dim3(256), 0, stream, Wo, Wuv, buv, wcombT, bvec);
  hipLaunchKernelGGL(k_qrot, dim3(128), dim3(256), 0, stream, cq, Wqr, bqr, qrot);
  hipLaunchKernelGGL(k_qabs, dim3(32, 8), dim3(256), 0, stream, cq, wqkT, bqabs, qabs);
  hipLaunchKernelGGL(k_attn, dim3(32, 16), dim3(256), 0, stream,
                     qabs, qrot, ckv, krot, ckvT, ctx);
  hipLaunchKernelGGL(k_final, dim3(32, 40), dim3(256), 0, stream, ctx, wcombT, bvec, out);
}